// Round 1
// baseline (783.826 us; speedup 1.0000x reference)
//
#include <hip/hip_runtime.h>
#include <math.h>

#define B_ 4
#define H_ 8
#define L_ 1024
#define E_ 64
#define NTOP 35
#define SCALE_ 0.04419417382415922f  /* 1/sqrt(512) */

// ---------------------------------------------------------------------------
// Kernel 1: partial circular cross-correlation amplitude^2.
// amp2_part[(bh*8+chunk)*1024 + tau] = sum_{e in chunk(8)} ( sum_t q[(t+tau)%1024]*k[t] )^2
// ---------------------------------------------------------------------------
__global__ __launch_bounds__(256) void k_corr(const float* __restrict__ q_g,
                                              const float* __restrict__ k_g,
                                              float* __restrict__ amp2_part) {
  __shared__ __align__(16) float q_s[8][1024];
  __shared__ __align__(16) float k_s[8][1024];
  const int chunk = blockIdx.x & 7;
  const int bh = blockIdx.x >> 3;
  const int b = bh >> 3, h = bh & 7;
  const int e0 = chunk * 8;
  const int tid = threadIdx.x;

  for (int idx = tid; idx < 8 * 1024; idx += 256) {
    int e = idx & 7, t = idx >> 3;
    size_t g = ((size_t)(b * L_ + t) * H_ + h) * E_ + e0 + e;
    q_s[e][t] = q_g[g];
    k_s[e][t] = k_g[g];
  }
  __syncthreads();

  const int w = tid >> 6, lane = tid & 63;
  const int tau = w * 256 + lane * 4;  // this thread owns tau..tau+3
  float a0 = 0.f, a1 = 0.f, a2 = 0.f, a3 = 0.f;

  for (int e = 0; e < 8; ++e) {
    const float4* q4 = reinterpret_cast<const float4*>(q_s[e]);
    const float4* k4 = reinterpret_cast<const float4*>(k_s[e]);
    float c0 = 0.f, c1 = 0.f, c2 = 0.f, c3 = 0.f;
    const int base = tau >> 2;
    float4 wa = q4[base & 255];
#pragma unroll 4
    for (int t4 = 0; t4 < 256; ++t4) {
      float4 wb = q4[(base + t4 + 1) & 255];
      float4 kv = k4[t4];
      c0 = fmaf(wa.x, kv.x, c0); c1 = fmaf(wa.y, kv.x, c1); c2 = fmaf(wa.z, kv.x, c2); c3 = fmaf(wa.w, kv.x, c3);
      c0 = fmaf(wa.y, kv.y, c0); c1 = fmaf(wa.z, kv.y, c1); c2 = fmaf(wa.w, kv.y, c2); c3 = fmaf(wb.x, kv.y, c3);
      c0 = fmaf(wa.z, kv.z, c0); c1 = fmaf(wa.w, kv.z, c1); c2 = fmaf(wb.x, kv.z, c2); c3 = fmaf(wb.y, kv.z, c3);
      c0 = fmaf(wa.w, kv.w, c0); c1 = fmaf(wb.x, kv.w, c1); c2 = fmaf(wb.y, kv.w, c2); c3 = fmaf(wb.z, kv.w, c3);
      wa = wb;
    }
    a0 = fmaf(c0, c0, a0); a1 = fmaf(c1, c1, a1);
    a2 = fmaf(c2, c2, a2); a3 = fmaf(c3, c3, a3);
  }
  float4 outv = make_float4(a0, a1, a2, a3);
  *reinterpret_cast<float4*>(&amp2_part[(size_t)blockIdx.x * 1024 + tau]) = outv;
}

// ---------------------------------------------------------------------------
// Kernel 2: top-35 selection per (b,h,src). src0: correlation amp^2 (sum of 8
// partials). src1: ||tf_q row||^2. Lowest-index tie-break (lax.top_k set).
// ---------------------------------------------------------------------------
__global__ __launch_bounds__(256) void k_topk(const float* __restrict__ amp2_part,
                                              const float* __restrict__ tfq,
                                              int* __restrict__ sel_ws) {
  __shared__ float amp[1024];
  __shared__ float rv[256];
  __shared__ int ri[256];
  const int src = blockIdx.x & 1;
  const int bh = blockIdx.x >> 1;
  const int b = bh >> 3, h = bh & 7;
  const int tid = threadIdx.x;

  if (src == 0) {
    for (int t = tid; t < 1024; t += 256) {
      float s = 0.f;
      for (int c = 0; c < 8; ++c) s += amp2_part[(size_t)(bh * 8 + c) * 1024 + t];
      amp[t] = s;
    }
  } else {
    for (int l = tid; l < 1024; l += 256) {
      const float4* p4 = reinterpret_cast<const float4*>(
          &tfq[((size_t)(b * L_ + l) * H_ + h) * E_]);
      float s = 0.f;
#pragma unroll
      for (int e4 = 0; e4 < 16; ++e4) {
        float4 v = p4[e4];
        s += v.x * v.x + v.y * v.y + v.z * v.z + v.w * v.w;
      }
      amp[l] = s;
    }
  }
  __syncthreads();

  for (int it = 0; it < NTOP; ++it) {
    float bv = -1.f; int bi = 0;
    for (int t = tid; t < 1024; t += 256) {
      float v = amp[t];
      if (v > bv) { bv = v; bi = t; }   // ascending t scan: first occurrence kept
    }
    rv[tid] = bv; ri[tid] = bi;
    __syncthreads();
    for (int s = 128; s > 0; s >>= 1) {
      if (tid < s) {
        float ov = rv[tid + s]; int oi = ri[tid + s];
        if (ov > rv[tid] || (ov == rv[tid] && oi < ri[tid])) { rv[tid] = ov; ri[tid] = oi; }
      }
      __syncthreads();
    }
    if (tid == 0) {
      sel_ws[(bh * 2 + src) * 64 + it] = ri[0];
      amp[ri[0]] = -1.f;
    }
    __syncthreads();
  }
}

// ---------------------------------------------------------------------------
// Kernel 3: scores over selected rows -> two softmaxes -> fuse -> times V.
// Writes 0.5*attn directly into d_out at [(bh*64+d)*1024 + a].
// ---------------------------------------------------------------------------
__global__ __launch_bounds__(256) void k_attn(const float* __restrict__ q_g,
                                              const float* __restrict__ tfq,
                                              const float* __restrict__ k_g,
                                              const float* __restrict__ v_g,
                                              const float* __restrict__ wfuse,
                                              const int* __restrict__ sel_ws,
                                              float* __restrict__ out) {
  __shared__ float qselt[NTOP][64];
  __shared__ float qseltf[NTOP][64];
  __shared__ float vselt[NTOP][64];
  __shared__ float vseltf[NTOP][64];
  __shared__ float ks[256][65];
  const int aq = blockIdx.x & 3;
  const int bh = blockIdx.x >> 2;
  const int b = bh >> 3, h = bh & 7;
  const int a0 = aq * 256;
  const int tid = threadIdx.x;

  for (int idx = tid; idx < NTOP * 64; idx += 256) {
    int i = idx >> 6, e = idx & 63;
    int st = sel_ws[(bh * 2 + 0) * 64 + i];
    int sf = sel_ws[(bh * 2 + 1) * 64 + i];
    qselt[i][e]  = q_g[((size_t)(b * L_ + st) * H_ + h) * E_ + e];
    qseltf[i][e] = tfq[((size_t)(b * L_ + sf) * H_ + h) * E_ + e];
    vselt[i][e]  = v_g[((size_t)(b * L_ + st) * H_ + h) * E_ + e];
    vseltf[i][e] = v_g[((size_t)(b * L_ + sf) * H_ + h) * E_ + e];
  }
  for (int idx = tid; idx < 256 * 64; idx += 256) {
    int r = idx >> 6, e = idx & 63;
    ks[r][e] = k_g[((size_t)(b * L_ + a0 + r) * H_ + h) * E_ + e];
  }
  __syncthreads();

  const int a = a0 + tid;
  float wf0 = wfuse[(h * L_ + a) * 2 + 0];
  float wf1 = wfuse[(h * L_ + a) * 2 + 1];
  float wm = fmaxf(wf0, wf1);
  float ew0 = expf(wf0 - wm), ew1 = expf(wf1 - wm);
  float nw0 = ew0 / (ew0 + ew1), nw1 = ew1 / (ew0 + ew1);

  float ct[NTOP], ctf[NTOP];
  // pass: attn_t
  {
#pragma unroll
    for (int i = 0; i < NTOP; ++i) ct[i] = 0.f;
    for (int e = 0; e < 64; ++e) {
      float kv = ks[tid][e];
#pragma unroll
      for (int i = 0; i < NTOP; ++i) ct[i] = fmaf(qselt[i][e], kv, ct[i]);
    }
    float m = -1e30f;
#pragma unroll
    for (int i = 0; i < NTOP; ++i) { ct[i] *= SCALE_; m = fmaxf(m, ct[i]); }
    float sum = 0.f;
#pragma unroll
    for (int i = 0; i < NTOP; ++i) { ct[i] = expf(ct[i] - m); sum += ct[i]; }
    float c = 0.5f * nw0 / sum;   // fold 0.5 output scale here
#pragma unroll
    for (int i = 0; i < NTOP; ++i) ct[i] *= c;
  }
  // pass: attn_tf
  {
#pragma unroll
    for (int i = 0; i < NTOP; ++i) ctf[i] = 0.f;
    for (int e = 0; e < 64; ++e) {
      float kv = ks[tid][e];
#pragma unroll
      for (int i = 0; i < NTOP; ++i) ctf[i] = fmaf(qseltf[i][e], kv, ctf[i]);
    }
    float m = -1e30f;
#pragma unroll
    for (int i = 0; i < NTOP; ++i) { ctf[i] *= SCALE_; m = fmaxf(m, ctf[i]); }
    float sum = 0.f;
#pragma unroll
    for (int i = 0; i < NTOP; ++i) { ctf[i] = expf(ctf[i] - m); sum += ctf[i]; }
    float c = 0.5f * nw1 / sum;
#pragma unroll
    for (int i = 0; i < NTOP; ++i) ctf[i] *= c;
  }
  // out row (this thread's a): 0.5*(nw0*attn_t + nw1*attn_tf) @ V  -> ks[tid][d]
  for (int d = 0; d < 64; ++d) {
    float acc = 0.f;
#pragma unroll
    for (int i = 0; i < NTOP; ++i) acc = fmaf(ct[i], vselt[i][d], acc);
#pragma unroll
    for (int i = 0; i < NTOP; ++i) acc = fmaf(ctf[i], vseltf[i][d], acc);
    ks[tid][d] = acc;
  }
  __syncthreads();
  // transposed, coalesced store: out[(bh*64+d)*1024 + a0 + r]
  for (int idx = tid; idx < 256 * 64; idx += 256) {
    int d = idx >> 8, r = idx & 255;
    out[((size_t)(bh * 64 + d)) * 1024 + a0 + r] = ks[r][d];
  }
}

// ---------------------------------------------------------------------------
// Kernel 4: first 64 rfft modes of q / k along time (table-driven DFT).
// ft[((bh*64+e)*64+m)*2 + {0,1}] = Re/Im of sum_t x[t] e^{-2pi i m t/1024}
// ---------------------------------------------------------------------------
__global__ __launch_bounds__(256) void k_dft(const float* __restrict__ q_g,
                                             const float* __restrict__ k_g,
                                             float* __restrict__ qft,
                                             float* __restrict__ kft) {
  __shared__ float xs[16][1024];
  __shared__ float ctab[1024], stab[1024];
  const int src = blockIdx.x & 1;
  const int ec = (blockIdx.x >> 1) & 3;
  const int bh = blockIdx.x >> 3;
  const int b = bh >> 3, h = bh & 7;
  const int e0 = ec * 16;
  const int tid = threadIdx.x;
  const float* xg = src ? k_g : q_g;
  float* oft = src ? kft : qft;

  const float TWO_PI = 6.283185307179586f;
  for (int j = tid; j < 1024; j += 256) {
    float ang = TWO_PI * (float)j * (1.0f / 1024.0f);
    ctab[j] = cosf(ang); stab[j] = sinf(ang);
  }
  for (int idx = tid; idx < 16 * 1024; idx += 256) {
    int e = idx & 15, t = idx >> 4;
    xs[e][t] = xg[((size_t)(b * L_ + t) * H_ + h) * E_ + e0 + e];
  }
  __syncthreads();

  const int m = tid & 63, w = tid >> 6;
  const int ea = w, eb = w + 4, ec2 = w + 8, ed = w + 12;
  float r0 = 0.f, i0 = 0.f, r1 = 0.f, i1 = 0.f, r2 = 0.f, i2 = 0.f, r3 = 0.f, i3 = 0.f;
  for (int t = 0; t < 1024; ++t) {
    int j = (m * t) & 1023;
    float c = ctab[j], s = stab[j];
    float xa = xs[ea][t], xb = xs[eb][t], xc = xs[ec2][t], xd = xs[ed][t];
    r0 = fmaf(xa, c, r0); i0 = fmaf(xa, s, i0);
    r1 = fmaf(xb, c, r1); i1 = fmaf(xb, s, i1);
    r2 = fmaf(xc, c, r2); i2 = fmaf(xc, s, i2);
    r3 = fmaf(xd, c, r3); i3 = fmaf(xd, s, i3);
  }
  size_t o;
  o = ((size_t)(bh * 64 + e0 + ea) * 64 + m) * 2;  oft[o] = r0; oft[o + 1] = -i0;
  o = ((size_t)(bh * 64 + e0 + eb) * 64 + m) * 2;  oft[o] = r1; oft[o + 1] = -i1;
  o = ((size_t)(bh * 64 + e0 + ec2) * 64 + m) * 2; oft[o] = r2; oft[o + 1] = -i2;
  o = ((size_t)(bh * 64 + e0 + ed) * 64 + m) * 2;  oft[o] = r3; oft[o + 1] = -i3;
}

// ---------------------------------------------------------------------------
// Kernel 5: xqk = ctanh(q_ft^T k_ft); xqkv = xqk @ k_ft^T; xqkvw = w1-einsum.
// One block per (b,h).
// ---------------------------------------------------------------------------
__global__ __launch_bounds__(256) void k_specmix(const float* __restrict__ qft,
                                                 const float* __restrict__ kft,
                                                 const float* __restrict__ w1re,
                                                 const float* __restrict__ w1im,
                                                 float* __restrict__ xw) {
  __shared__ float qre[64][65], qim[64][65];
  __shared__ float kre[64][65], kim[64][65];
  __shared__ float tre[64][65], tim[64][65];
  const int bh = blockIdx.x;
  const int h = bh & 7;
  const int tid = threadIdx.x;

  for (int idx = tid; idx < 4096; idx += 256) {
    int e = idx >> 6, x = idx & 63;
    size_t o = ((size_t)(bh * 64 + e) * 64 + x) * 2;
    qre[e][x] = qft[o]; qim[e][x] = qft[o + 1];
    kre[e][x] = kft[o]; kim[e][x] = kft[o + 1];
  }
  __syncthreads();

  const int x = tid & 63, g = tid >> 6;
  // xqk[x][y] = tanh( sum_e q[e,x]*k[e,y] )   (complex)
  for (int yy = 0; yy < 16; ++yy) {
    int y = g * 16 + yy;
    float ar = 0.f, ai = 0.f;
    for (int e = 0; e < 64; ++e) {
      float a = qre[e][x], bq = qim[e][x];
      float c = kre[e][y], d = kim[e][y];
      ar = fmaf(a, c, fmaf(-bq, d, ar));
      ai = fmaf(a, d, fmaf(bq, c, ai));
    }
    float trv, tiv;
    float x2 = 2.f * ar, y2 = 2.f * ai;
    if (fabsf(x2) > 30.f) {
      trv = copysignf(1.f, ar); tiv = 0.f;
    } else {
      float sh = sinhf(x2), ch = coshf(x2);
      float sn = sinf(y2), cs = cosf(y2);
      float dd = ch + cs;
      trv = sh / dd; tiv = sn / dd;
    }
    tre[x][y] = trv; tim[x][y] = tiv;
  }
  __syncthreads();
  // xqkv[e][x] = sum_y xqk[x][y]*k[e][y]  -> overwrite qre/qim
  for (int ee = 0; ee < 16; ++ee) {
    int e = g * 16 + ee;
    float ar = 0.f, ai = 0.f;
    for (int y = 0; y < 64; ++y) {
      float a = tre[x][y], bq = tim[x][y];
      float c = kre[e][y], d = kim[e][y];
      ar = fmaf(a, c, fmaf(-bq, d, ar));
      ai = fmaf(a, d, fmaf(bq, c, ai));
    }
    qre[e][x] = ar; qim[e][x] = ai;
  }
  __syncthreads();
  // xqkvw[o][x] = sum_e xqkv[e][x]*w1[h,e,o,x], scaled by 1/(512*512)
  const float INV = 1.0f / (512.0f * 512.0f);
  for (int oo = 0; oo < 16; ++oo) {
    int o = g * 16 + oo;
    float ar = 0.f, ai = 0.f;
    for (int e = 0; e < 64; ++e) {
      float a = qre[e][x], bq = qim[e][x];
      size_t wi = (((size_t)h * 64 + e) * 64 + o) * 64 + x;
      float c = w1re[wi], d = w1im[wi];
      ar = fmaf(a, c, fmaf(-bq, d, ar));
      ai = fmaf(a, d, fmaf(bq, c, ai));
    }
    size_t oidx = ((size_t)(bh * 64 + o) * 64 + x) * 2;
    xw[oidx] = ar * INV; xw[oidx + 1] = ai * INV;
  }
}

// ---------------------------------------------------------------------------
// Kernel 6: 64-mode irfft, add 0.5*spec into d_out (which holds 0.5*attn).
// out[t] += 0.5*(ReX0 + 2*sum_{m=1..63}(ReXm cos - ImXm sin)) / 1024
// ---------------------------------------------------------------------------
__global__ __launch_bounds__(256) void k_final(const float* __restrict__ xw,
                                               float* __restrict__ out) {
  __shared__ float Xre[8][64], Xim[8][64];
  __shared__ float ctab[1024], stab[1024];
  const int oc = blockIdx.x & 7;
  const int bh = blockIdx.x >> 3;
  const int o0 = oc * 8;
  const int tid = threadIdx.x;
  const float TWO_PI = 6.283185307179586f;

  for (int j = tid; j < 1024; j += 256) {
    float ang = TWO_PI * (float)j * (1.0f / 1024.0f);
    ctab[j] = cosf(ang); stab[j] = sinf(ang);
  }
  for (int idx = tid; idx < 512; idx += 256) {
    int o = idx >> 6, m = idx & 63;
    size_t s = ((size_t)(bh * 64 + o0 + o) * 64 + m) * 2;
    Xre[o][m] = xw[s]; Xim[o][m] = xw[s + 1];
  }
  __syncthreads();

  const int ts = tid & 31, ol = tid >> 5;
  const float HALF_INVN = 0.5f / 1024.0f;
  for (int k = 0; k < 32; ++k) {
    int t = ts + k * 32;
    float acc = Xre[ol][0];
#pragma unroll 7
    for (int m = 1; m < 64; ++m) {
      int j = (m * t) & 1023;
      acc += 2.f * (Xre[ol][m] * ctab[j] - Xim[ol][m] * stab[j]);
    }
    size_t oi = ((size_t)(bh * 64 + o0 + ol)) * 1024 + t;
    out[oi] = fmaf(acc, HALF_INVN, out[oi]);
  }
}

// ---------------------------------------------------------------------------
extern "C" void kernel_launch(void* const* d_in, const int* in_sizes, int n_in,
                              void* d_out, int out_size, void* d_ws, size_t ws_size,
                              hipStream_t stream) {
  const float* tfq   = (const float*)d_in[0];
  const float* q     = (const float*)d_in[1];
  const float* k     = (const float*)d_in[2];
  const float* v     = (const float*)d_in[3];
  const float* wfuse = (const float*)d_in[5];
  const float* w1re  = (const float*)d_in[6];
  const float* w1im  = (const float*)d_in[7];
  float* out = (float*)d_out;
  float* ws  = (float*)d_ws;

  // ws layout (floats): amp2[262144] | sel(int)[4096] | qft[262144] | kft[262144] | xw[262144]
  float* amp2 = ws;
  int*   sel  = (int*)(ws + 262144);
  float* qft  = ws + 266240;
  float* kft  = ws + 528384;
  float* xw   = ws + 790528;

  k_corr<<<256, 256, 0, stream>>>(q, k, amp2);
  k_topk<<<64, 256, 0, stream>>>(amp2, tfq, sel);
  k_attn<<<128, 256, 0, stream>>>(q, tfq, k, v, wfuse, sel, out);
  k_dft<<<256, 256, 0, stream>>>(q, k, qft, kft);
  k_specmix<<<32, 256, 0, stream>>>(qft, kft, w1re, w1im, xw);
  k_final<<<256, 256, 0, stream>>>(xw, out);
}

// Round 2
// 626.905 us; speedup vs baseline: 1.2503x; 1.2503x over previous
//
#include <hip/hip_runtime.h>
#include <math.h>

#define B_ 4
#define H_ 8
#define L_ 1024
#define E_ 64
#define NTOP 35
#define SCALE_ 0.04419417382415922f  /* 1/sqrt(512) */

// ---------------------------------------------------------------------------
// Kernel 1: partial circular cross-correlation amplitude^2.
// amp2_part[(bh*8+chunk)*1024 + tau] = sum_{e in chunk(8)} ( sum_t q[(t+tau)%1024]*k[t] )^2
// ---------------------------------------------------------------------------
__global__ __launch_bounds__(256) void k_corr(const float* __restrict__ q_g,
                                              const float* __restrict__ k_g,
                                              float* __restrict__ amp2_part) {
  __shared__ __align__(16) float q_s[8][1024];
  __shared__ __align__(16) float k_s[8][1024];
  const int chunk = blockIdx.x & 7;
  const int bh = blockIdx.x >> 3;
  const int b = bh >> 3, h = bh & 7;
  const int e0 = chunk * 8;
  const int tid = threadIdx.x;

  for (int idx = tid; idx < 8 * 1024; idx += 256) {
    int e = idx & 7, t = idx >> 3;
    size_t g = ((size_t)(b * L_ + t) * H_ + h) * E_ + e0 + e;
    q_s[e][t] = q_g[g];
    k_s[e][t] = k_g[g];
  }
  __syncthreads();

  const int w = tid >> 6, lane = tid & 63;
  const int tau = w * 256 + lane * 4;  // this thread owns tau..tau+3
  float a0 = 0.f, a1 = 0.f, a2 = 0.f, a3 = 0.f;

  for (int e = 0; e < 8; ++e) {
    const float4* q4 = reinterpret_cast<const float4*>(q_s[e]);
    const float4* k4 = reinterpret_cast<const float4*>(k_s[e]);
    float c0 = 0.f, c1 = 0.f, c2 = 0.f, c3 = 0.f;
    const int base = tau >> 2;
    float4 wa = q4[base & 255];
#pragma unroll 4
    for (int t4 = 0; t4 < 256; ++t4) {
      float4 wb = q4[(base + t4 + 1) & 255];
      float4 kv = k4[t4];
      c0 = fmaf(wa.x, kv.x, c0); c1 = fmaf(wa.y, kv.x, c1); c2 = fmaf(wa.z, kv.x, c2); c3 = fmaf(wa.w, kv.x, c3);
      c0 = fmaf(wa.y, kv.y, c0); c1 = fmaf(wa.z, kv.y, c1); c2 = fmaf(wa.w, kv.y, c2); c3 = fmaf(wb.x, kv.y, c3);
      c0 = fmaf(wa.z, kv.z, c0); c1 = fmaf(wa.w, kv.z, c1); c2 = fmaf(wb.x, kv.z, c2); c3 = fmaf(wb.y, kv.z, c3);
      c0 = fmaf(wa.w, kv.w, c0); c1 = fmaf(wb.x, kv.w, c1); c2 = fmaf(wb.y, kv.w, c2); c3 = fmaf(wb.z, kv.w, c3);
      wa = wb;
    }
    a0 = fmaf(c0, c0, a0); a1 = fmaf(c1, c1, a1);
    a2 = fmaf(c2, c2, a2); a3 = fmaf(c3, c3, a3);
  }
  float4 outv = make_float4(a0, a1, a2, a3);
  *reinterpret_cast<float4*>(&amp2_part[(size_t)blockIdx.x * 1024 + tau]) = outv;
}

// ---------------------------------------------------------------------------
// Kernel 2: top-35 selection per (b,h,src). src0: correlation amp^2 (sum of 8
// partials). src1: ||tf_q row||^2. Lowest-index tie-break (lax.top_k set).
// ---------------------------------------------------------------------------
__global__ __launch_bounds__(256) void k_topk(const float* __restrict__ amp2_part,
                                              const float* __restrict__ tfq,
                                              int* __restrict__ sel_ws) {
  __shared__ float amp[1024];
  __shared__ float rv[256];
  __shared__ int ri[256];
  const int src = blockIdx.x & 1;
  const int bh = blockIdx.x >> 1;
  const int b = bh >> 3, h = bh & 7;
  const int tid = threadIdx.x;

  if (src == 0) {
    for (int t = tid; t < 1024; t += 256) {
      float s = 0.f;
      for (int c = 0; c < 8; ++c) s += amp2_part[(size_t)(bh * 8 + c) * 1024 + t];
      amp[t] = s;
    }
  } else {
    for (int l = tid; l < 1024; l += 256) {
      const float4* p4 = reinterpret_cast<const float4*>(
          &tfq[((size_t)(b * L_ + l) * H_ + h) * E_]);
      float s = 0.f;
#pragma unroll
      for (int e4 = 0; e4 < 16; ++e4) {
        float4 v = p4[e4];
        s += v.x * v.x + v.y * v.y + v.z * v.z + v.w * v.w;
      }
      amp[l] = s;
    }
  }
  __syncthreads();

  for (int it = 0; it < NTOP; ++it) {
    float bv = -1.f; int bi = 0;
    for (int t = tid; t < 1024; t += 256) {
      float v = amp[t];
      if (v > bv) { bv = v; bi = t; }   // ascending t scan: first occurrence kept
    }
    rv[tid] = bv; ri[tid] = bi;
    __syncthreads();
    for (int s = 128; s > 0; s >>= 1) {
      if (tid < s) {
        float ov = rv[tid + s]; int oi = ri[tid + s];
        if (ov > rv[tid] || (ov == rv[tid] && oi < ri[tid])) { rv[tid] = ov; ri[tid] = oi; }
      }
      __syncthreads();
    }
    if (tid == 0) {
      sel_ws[(bh * 2 + src) * 64 + it] = ri[0];
      amp[ri[0]] = -1.f;
    }
    __syncthreads();
  }
}

// ---------------------------------------------------------------------------
// Kernel 3: scores over selected rows -> two softmaxes -> fuse -> times V.
// Writes 0.5*attn directly into d_out at [(bh*64+d)*1024 + a].
// ---------------------------------------------------------------------------
__global__ __launch_bounds__(256) void k_attn(const float* __restrict__ q_g,
                                              const float* __restrict__ tfq,
                                              const float* __restrict__ k_g,
                                              const float* __restrict__ v_g,
                                              const float* __restrict__ wfuse,
                                              const int* __restrict__ sel_ws,
                                              float* __restrict__ out) {
  __shared__ float qselt[NTOP][64];
  __shared__ float qseltf[NTOP][64];
  __shared__ float vselt[NTOP][64];
  __shared__ float vseltf[NTOP][64];
  __shared__ float ks[256][65];
  const int aq = blockIdx.x & 3;
  const int bh = blockIdx.x >> 2;
  const int b = bh >> 3, h = bh & 7;
  const int a0 = aq * 256;
  const int tid = threadIdx.x;

  for (int idx = tid; idx < NTOP * 64; idx += 256) {
    int i = idx >> 6, e = idx & 63;
    int st = sel_ws[(bh * 2 + 0) * 64 + i];
    int sf = sel_ws[(bh * 2 + 1) * 64 + i];
    qselt[i][e]  = q_g[((size_t)(b * L_ + st) * H_ + h) * E_ + e];
    qseltf[i][e] = tfq[((size_t)(b * L_ + sf) * H_ + h) * E_ + e];
    vselt[i][e]  = v_g[((size_t)(b * L_ + st) * H_ + h) * E_ + e];
    vseltf[i][e] = v_g[((size_t)(b * L_ + sf) * H_ + h) * E_ + e];
  }
  for (int idx = tid; idx < 256 * 64; idx += 256) {
    int r = idx >> 6, e = idx & 63;
    ks[r][e] = k_g[((size_t)(b * L_ + a0 + r) * H_ + h) * E_ + e];
  }
  __syncthreads();

  const int a = a0 + tid;
  float wf0 = wfuse[(h * L_ + a) * 2 + 0];
  float wf1 = wfuse[(h * L_ + a) * 2 + 1];
  float wm = fmaxf(wf0, wf1);
  float ew0 = expf(wf0 - wm), ew1 = expf(wf1 - wm);
  float nw0 = ew0 / (ew0 + ew1), nw1 = ew1 / (ew0 + ew1);

  float ct[NTOP], ctf[NTOP];
  // pass: attn_t
  {
#pragma unroll
    for (int i = 0; i < NTOP; ++i) ct[i] = 0.f;
    for (int e = 0; e < 64; ++e) {
      float kv = ks[tid][e];
#pragma unroll
      for (int i = 0; i < NTOP; ++i) ct[i] = fmaf(qselt[i][e], kv, ct[i]);
    }
    float m = -1e30f;
#pragma unroll
    for (int i = 0; i < NTOP; ++i) { ct[i] *= SCALE_; m = fmaxf(m, ct[i]); }
    float sum = 0.f;
#pragma unroll
    for (int i = 0; i < NTOP; ++i) { ct[i] = expf(ct[i] - m); sum += ct[i]; }
    float c = 0.5f * nw0 / sum;   // fold 0.5 output scale here
#pragma unroll
    for (int i = 0; i < NTOP; ++i) ct[i] *= c;
  }
  // pass: attn_tf
  {
#pragma unroll
    for (int i = 0; i < NTOP; ++i) ctf[i] = 0.f;
    for (int e = 0; e < 64; ++e) {
      float kv = ks[tid][e];
#pragma unroll
      for (int i = 0; i < NTOP; ++i) ctf[i] = fmaf(qseltf[i][e], kv, ctf[i]);
    }
    float m = -1e30f;
#pragma unroll
    for (int i = 0; i < NTOP; ++i) { ctf[i] *= SCALE_; m = fmaxf(m, ctf[i]); }
    float sum = 0.f;
#pragma unroll
    for (int i = 0; i < NTOP; ++i) { ctf[i] = expf(ctf[i] - m); sum += ctf[i]; }
    float c = 0.5f * nw1 / sum;
#pragma unroll
    for (int i = 0; i < NTOP; ++i) ctf[i] *= c;
  }
  // out row (this thread's a): 0.5*(nw0*attn_t + nw1*attn_tf) @ V  -> ks[tid][d]
  for (int d = 0; d < 64; ++d) {
    float acc = 0.f;
#pragma unroll
    for (int i = 0; i < NTOP; ++i) acc = fmaf(ct[i], vselt[i][d], acc);
#pragma unroll
    for (int i = 0; i < NTOP; ++i) acc = fmaf(ctf[i], vseltf[i][d], acc);
    ks[tid][d] = acc;
  }
  __syncthreads();
  // transposed, coalesced store: out[(bh*64+d)*1024 + a0 + r]
  for (int idx = tid; idx < 256 * 64; idx += 256) {
    int d = idx >> 8, r = idx & 255;
    out[((size_t)(bh * 64 + d)) * 1024 + a0 + r] = ks[r][d];
  }
}

// ---------------------------------------------------------------------------
// Kernel 4: first 64 rfft modes of q / k along time (table-driven DFT).
// ft[((bh*64+e)*64+m)*2 + {0,1}] = Re/Im of sum_t x[t] e^{-2pi i m t/1024}
// ---------------------------------------------------------------------------
__global__ __launch_bounds__(256) void k_dft(const float* __restrict__ q_g,
                                             const float* __restrict__ k_g,
                                             float* __restrict__ qft,
                                             float* __restrict__ kft) {
  __shared__ float xs[16][1024];
  __shared__ float ctab[1024], stab[1024];
  const int src = blockIdx.x & 1;
  const int ec = (blockIdx.x >> 1) & 3;
  const int bh = blockIdx.x >> 3;
  const int b = bh >> 3, h = bh & 7;
  const int e0 = ec * 16;
  const int tid = threadIdx.x;
  const float* xg = src ? k_g : q_g;
  float* oft = src ? kft : qft;

  const float TWO_PI = 6.283185307179586f;
  for (int j = tid; j < 1024; j += 256) {
    float ang = TWO_PI * (float)j * (1.0f / 1024.0f);
    ctab[j] = cosf(ang); stab[j] = sinf(ang);
  }
  for (int idx = tid; idx < 16 * 1024; idx += 256) {
    int e = idx & 15, t = idx >> 4;
    xs[e][t] = xg[((size_t)(b * L_ + t) * H_ + h) * E_ + e0 + e];
  }
  __syncthreads();

  const int m = tid & 63, w = tid >> 6;
  const int ea = w, eb = w + 4, ec2 = w + 8, ed = w + 12;
  float r0 = 0.f, i0 = 0.f, r1 = 0.f, i1 = 0.f, r2 = 0.f, i2 = 0.f, r3 = 0.f, i3 = 0.f;
  for (int t = 0; t < 1024; ++t) {
    int j = (m * t) & 1023;
    float c = ctab[j], s = stab[j];
    float xa = xs[ea][t], xb = xs[eb][t], xc = xs[ec2][t], xd = xs[ed][t];
    r0 = fmaf(xa, c, r0); i0 = fmaf(xa, s, i0);
    r1 = fmaf(xb, c, r1); i1 = fmaf(xb, s, i1);
    r2 = fmaf(xc, c, r2); i2 = fmaf(xc, s, i2);
    r3 = fmaf(xd, c, r3); i3 = fmaf(xd, s, i3);
  }
  size_t o;
  o = ((size_t)(bh * 64 + e0 + ea) * 64 + m) * 2;  oft[o] = r0; oft[o + 1] = -i0;
  o = ((size_t)(bh * 64 + e0 + eb) * 64 + m) * 2;  oft[o] = r1; oft[o + 1] = -i1;
  o = ((size_t)(bh * 64 + e0 + ec2) * 64 + m) * 2; oft[o] = r2; oft[o + 1] = -i2;
  o = ((size_t)(bh * 64 + e0 + ed) * 64 + m) * 2;  oft[o] = r3; oft[o + 1] = -i3;
}

// ---------------------------------------------------------------------------
// Kernel 5a: xqk = ctanh(q_ft^T k_ft); xqkv = xqk @ k_ft^T  (per b,h).
// 1024 threads: lane x = tid&63, group g = tid>>6 (16 groups of 4 y / 4 e).
// Writes xqkv as two planes: xre_g/xim_g [bh*4096 + e*64 + x].
// ---------------------------------------------------------------------------
__global__ __launch_bounds__(1024) void k_spec12(const float* __restrict__ qft,
                                                 const float* __restrict__ kft,
                                                 float* __restrict__ xre_g,
                                                 float* __restrict__ xim_g) {
  __shared__ float qre[64][65], qim[64][65];
  __shared__ float kre[64][65], kim[64][65];
  __shared__ float tre[64][65], tim[64][65];
  const int bh = blockIdx.x;
  const int tid = threadIdx.x;

  for (int idx = tid; idx < 4096; idx += 1024) {
    int e = idx >> 6, x = idx & 63;
    size_t o = ((size_t)(bh * 64 + e) * 64 + x) * 2;
    qre[e][x] = qft[o]; qim[e][x] = qft[o + 1];
    kre[e][x] = kft[o]; kim[e][x] = kft[o + 1];
  }
  __syncthreads();

  const int x = tid & 63, g = tid >> 6;
  // xqk[x][y] = ctanh( sum_e q[e,x]*k[e,y] )
#pragma unroll
  for (int yy = 0; yy < 4; ++yy) {
    int y = g * 4 + yy;
    float ar = 0.f, ai = 0.f;
    for (int e = 0; e < 64; ++e) {
      float a = qre[e][x], b = qim[e][x];
      float c = kre[e][y], d = kim[e][y];
      ar = fmaf(a, c, fmaf(-b, d, ar));
      ai = fmaf(a, d, fmaf(b, c, ai));
    }
    float trv, tiv;
    float x2 = 2.f * ar, y2 = 2.f * ai;
    if (fabsf(x2) > 30.f) {
      trv = copysignf(1.f, ar); tiv = 0.f;
    } else {
      float sh = sinhf(x2), ch = coshf(x2);
      float sn = sinf(y2), cs = cosf(y2);
      float dd = ch + cs;
      trv = sh / dd; tiv = sn / dd;
    }
    tre[x][y] = trv; tim[x][y] = tiv;
  }
  __syncthreads();
  // xqkv[e][x] = sum_y xqk[x][y]*k[e][y]
#pragma unroll
  for (int ee = 0; ee < 4; ++ee) {
    int e = g * 4 + ee;
    float ar = 0.f, ai = 0.f;
    for (int y = 0; y < 64; ++y) {
      float a = tre[x][y], b = tim[x][y];
      float c = kre[e][y], d = kim[e][y];
      ar = fmaf(a, c, fmaf(-b, d, ar));
      ai = fmaf(a, d, fmaf(b, c, ai));
    }
    xre_g[(size_t)bh * 4096 + e * 64 + x] = ar;
    xim_g[(size_t)bh * 4096 + e * 64 + x] = ai;
  }
}

// ---------------------------------------------------------------------------
// Kernel 5b: xqkvw[o][x] = (sum_e xqkv[e][x]*w1[h,e,o,x]) / 512^2.
// Grid: (bh, o-chunk of 8) = 256 blocks. Threads: x = tid&63, g = tid>>6,
// group g covers e in [g*16, g*16+16). w1 loads coalesced over lanes (x).
// ---------------------------------------------------------------------------
__global__ __launch_bounds__(256) void k_w1(const float* __restrict__ xre_g,
                                            const float* __restrict__ xim_g,
                                            const float* __restrict__ w1re,
                                            const float* __restrict__ w1im,
                                            float* __restrict__ xw) {
  __shared__ float xre[64][65], xim[64][65];
  __shared__ float redr[4][512], redi[4][512];
  const int oc = blockIdx.x & 7;
  const int bh = blockIdx.x >> 3;
  const int h = bh & 7;
  const int tid = threadIdx.x;

  for (int idx = tid; idx < 4096; idx += 256) {
    int e = idx >> 6, x = idx & 63;
    xre[e][x] = xre_g[(size_t)bh * 4096 + idx];
    xim[e][x] = xim_g[(size_t)bh * 4096 + idx];
  }
  __syncthreads();

  const int x = tid & 63, g = tid >> 6;
  float accr[8], acci[8];
#pragma unroll
  for (int oo = 0; oo < 8; ++oo) { accr[oo] = 0.f; acci[oo] = 0.f; }

  for (int ee = 0; ee < 16; ++ee) {
    int e = g * 16 + ee;
    float a = xre[e][x], b = xim[e][x];
    size_t wbase = (((size_t)h * 64 + e) * 64 + oc * 8) * 64 + x;
#pragma unroll
    for (int oo = 0; oo < 8; ++oo) {
      float c = w1re[wbase + (size_t)oo * 64];
      float d = w1im[wbase + (size_t)oo * 64];
      accr[oo] = fmaf(a, c, fmaf(-b, d, accr[oo]));
      acci[oo] = fmaf(a, d, fmaf(b, c, acci[oo]));
    }
  }
#pragma unroll
  for (int oo = 0; oo < 8; ++oo) {
    redr[g][oo * 64 + x] = accr[oo];
    redi[g][oo * 64 + x] = acci[oo];
  }
  __syncthreads();

  const float INV = 1.0f / (512.0f * 512.0f);
  for (int idx = tid; idx < 512; idx += 256) {
    int oo = idx >> 6, x2 = idx & 63;
    float r = redr[0][idx] + redr[1][idx] + redr[2][idx] + redr[3][idx];
    float i = redi[0][idx] + redi[1][idx] + redi[2][idx] + redi[3][idx];
    size_t oidx = ((size_t)(bh * 64 + oc * 8 + oo) * 64 + x2) * 2;
    xw[oidx] = r * INV;
    xw[oidx + 1] = i * INV;
  }
}

// ---------------------------------------------------------------------------
// Kernel 6: 64-mode irfft, add 0.5*spec into d_out (which holds 0.5*attn).
// out[t] += 0.5*(ReX0 + 2*sum_{m=1..63}(ReXm cos - ImXm sin)) / 1024
// ---------------------------------------------------------------------------
__global__ __launch_bounds__(256) void k_final(const float* __restrict__ xw,
                                               float* __restrict__ out) {
  __shared__ float Xre[8][64], Xim[8][64];
  __shared__ float ctab[1024], stab[1024];
  const int oc = blockIdx.x & 7;
  const int bh = blockIdx.x >> 3;
  const int o0 = oc * 8;
  const int tid = threadIdx.x;
  const float TWO_PI = 6.283185307179586f;

  for (int j = tid; j < 1024; j += 256) {
    float ang = TWO_PI * (float)j * (1.0f / 1024.0f);
    ctab[j] = cosf(ang); stab[j] = sinf(ang);
  }
  for (int idx = tid; idx < 512; idx += 256) {
    int o = idx >> 6, m = idx & 63;
    size_t s = ((size_t)(bh * 64 + o0 + o) * 64 + m) * 2;
    Xre[o][m] = xw[s]; Xim[o][m] = xw[s + 1];
  }
  __syncthreads();

  const int ts = tid & 31, ol = tid >> 5;
  const float HALF_INVN = 0.5f / 1024.0f;
  for (int k = 0; k < 32; ++k) {
    int t = ts + k * 32;
    float acc = Xre[ol][0];
#pragma unroll 7
    for (int m = 1; m < 64; ++m) {
      int j = (m * t) & 1023;
      acc += 2.f * (Xre[ol][m] * ctab[j] - Xim[ol][m] * stab[j]);
    }
    size_t oi = ((size_t)(bh * 64 + o0 + ol)) * 1024 + t;
    out[oi] = fmaf(acc, HALF_INVN, out[oi]);
  }
}

// ---------------------------------------------------------------------------
extern "C" void kernel_launch(void* const* d_in, const int* in_sizes, int n_in,
                              void* d_out, int out_size, void* d_ws, size_t ws_size,
                              hipStream_t stream) {
  const float* tfq   = (const float*)d_in[0];
  const float* q     = (const float*)d_in[1];
  const float* k     = (const float*)d_in[2];
  const float* v     = (const float*)d_in[3];
  const float* wfuse = (const float*)d_in[5];
  const float* w1re  = (const float*)d_in[6];
  const float* w1im  = (const float*)d_in[7];
  float* out = (float*)d_out;
  float* ws  = (float*)d_ws;

  // ws layout (floats):
  //   amp2[262144]  (reused after k_topk as xqkv_re[131072] | xqkv_im[131072])
  //   sel(int)[4096] | qft[262144] | kft[262144] | xw[262144]
  float* amp2   = ws;
  float* xre_g  = ws;             // aliases amp2 (dead after k_topk)
  float* xim_g  = ws + 131072;
  int*   sel    = (int*)(ws + 262144);
  float* qft    = ws + 266240;
  float* kft    = ws + 528384;
  float* xw     = ws + 790528;

  k_corr<<<256, 256, 0, stream>>>(q, k, amp2);
  k_topk<<<64, 256, 0, stream>>>(amp2, tfq, sel);
  k_attn<<<128, 256, 0, stream>>>(q, tfq, k, v, wfuse, sel, out);
  k_dft<<<256, 256, 0, stream>>>(q, k, qft, kft);
  k_spec12<<<32, 1024, 0, stream>>>(qft, kft, xre_g, xim_g);
  k_w1<<<256, 256, 0, stream>>>(xre_g, xim_g, w1re, w1im, xw);
  k_final<<<256, 256, 0, stream>>>(xw, out);
}

// Round 3
// 419.279 us; speedup vs baseline: 1.8695x; 1.4952x over previous
//
#include <hip/hip_runtime.h>
#include <math.h>

#define B_ 4
#define H_ 8
#define L_ 1024
#define E_ 64
#define NTOP 35
#define SCALE_ 0.04419417382415922f  /* 1/sqrt(512) */

// ---------------------------------------------------------------------------
// Kernel 1: partial circular cross-correlation amplitude^2.
// amp2_part[(bh*8+chunk)*1024 + tau] = sum_{e in chunk(8)} ( sum_t q[(t+tau)%1024]*k[t] )^2
// ---------------------------------------------------------------------------
__global__ __launch_bounds__(256) void k_corr(const float* __restrict__ q_g,
                                              const float* __restrict__ k_g,
                                              float* __restrict__ amp2_part) {
  __shared__ __align__(16) float q_s[8][1024];
  __shared__ __align__(16) float k_s[8][1024];
  const int chunk = blockIdx.x & 7;
  const int bh = blockIdx.x >> 3;
  const int b = bh >> 3, h = bh & 7;
  const int e0 = chunk * 8;
  const int tid = threadIdx.x;

  for (int idx = tid; idx < 8 * 1024; idx += 256) {
    int e = idx & 7, t = idx >> 3;
    size_t g = ((size_t)(b * L_ + t) * H_ + h) * E_ + e0 + e;
    q_s[e][t] = q_g[g];
    k_s[e][t] = k_g[g];
  }
  __syncthreads();

  const int w = tid >> 6, lane = tid & 63;
  const int tau = w * 256 + lane * 4;  // this thread owns tau..tau+3
  float a0 = 0.f, a1 = 0.f, a2 = 0.f, a3 = 0.f;

  for (int e = 0; e < 8; ++e) {
    const float4* q4 = reinterpret_cast<const float4*>(q_s[e]);
    const float4* k4 = reinterpret_cast<const float4*>(k_s[e]);
    float c0 = 0.f, c1 = 0.f, c2 = 0.f, c3 = 0.f;
    const int base = tau >> 2;
    float4 wa = q4[base & 255];
#pragma unroll 4
    for (int t4 = 0; t4 < 256; ++t4) {
      float4 wb = q4[(base + t4 + 1) & 255];
      float4 kv = k4[t4];
      c0 = fmaf(wa.x, kv.x, c0); c1 = fmaf(wa.y, kv.x, c1); c2 = fmaf(wa.z, kv.x, c2); c3 = fmaf(wa.w, kv.x, c3);
      c0 = fmaf(wa.y, kv.y, c0); c1 = fmaf(wa.z, kv.y, c1); c2 = fmaf(wa.w, kv.y, c2); c3 = fmaf(wb.x, kv.y, c3);
      c0 = fmaf(wa.z, kv.z, c0); c1 = fmaf(wa.w, kv.z, c1); c2 = fmaf(wb.x, kv.z, c2); c3 = fmaf(wb.y, kv.z, c3);
      c0 = fmaf(wa.w, kv.w, c0); c1 = fmaf(wb.x, kv.w, c1); c2 = fmaf(wb.y, kv.w, c2); c3 = fmaf(wb.z, kv.w, c3);
      wa = wb;
    }
    a0 = fmaf(c0, c0, a0); a1 = fmaf(c1, c1, a1);
    a2 = fmaf(c2, c2, a2); a3 = fmaf(c3, c3, a3);
  }
  float4 outv = make_float4(a0, a1, a2, a3);
  *reinterpret_cast<float4*>(&amp2_part[(size_t)blockIdx.x * 1024 + tau]) = outv;
}

// ---------------------------------------------------------------------------
// Kernel 2: top-35 selection per (b,h,src). Wave-shuffle argmax per round;
// only the owner thread rescans after removal. Lowest-index tie-break.
// ---------------------------------------------------------------------------
__global__ __launch_bounds__(256) void k_topk(const float* __restrict__ amp2_part,
                                              const float* __restrict__ tfq,
                                              int* __restrict__ sel_ws) {
  __shared__ float amp[1024];
  __shared__ float wv_s[4];
  __shared__ int wi_s[4];
  __shared__ int winner_s;
  const int src = blockIdx.x & 1;
  const int bh = blockIdx.x >> 1;
  const int b = bh >> 3, h = bh & 7;
  const int tid = threadIdx.x;

  if (src == 0) {
    for (int t = tid; t < 1024; t += 256) {
      float s = 0.f;
      for (int c = 0; c < 8; ++c) s += amp2_part[(size_t)(bh * 8 + c) * 1024 + t];
      amp[t] = s;
    }
  } else {
    for (int l = tid; l < 1024; l += 256) {
      const float4* p4 = reinterpret_cast<const float4*>(
          &tfq[((size_t)(b * L_ + l) * H_ + h) * E_]);
      float s = 0.f;
#pragma unroll
      for (int e4 = 0; e4 < 16; ++e4) {
        float4 v = p4[e4];
        s += v.x * v.x + v.y * v.y + v.z * v.z + v.w * v.w;
      }
      amp[l] = s;
    }
  }
  __syncthreads();

  // local max over the 4 owned slots (t = tid + 256k), ascending scan
  float bv = -1.f; int bi = tid;
#pragma unroll
  for (int kk = 0; kk < 4; ++kk) {
    int t = tid + kk * 256;
    float v = amp[t];
    if (v > bv) { bv = v; bi = t; }
  }
  const int lane = tid & 63, w = tid >> 6;

  for (int it = 0; it < NTOP; ++it) {
    float v = bv; int i = bi;
#pragma unroll
    for (int d = 1; d < 64; d <<= 1) {
      float ov = __shfl_xor(v, d);
      int oi = __shfl_xor(i, d);
      if (ov > v || (ov == v && oi < i)) { v = ov; i = oi; }
    }
    if (lane == 0) { wv_s[w] = v; wi_s[w] = i; }
    __syncthreads();
    if (tid == 0) {
      float fv = wv_s[0]; int fi = wi_s[0];
#pragma unroll
      for (int j = 1; j < 4; ++j) {
        if (wv_s[j] > fv || (wv_s[j] == fv && wi_s[j] < fi)) { fv = wv_s[j]; fi = wi_s[j]; }
      }
      winner_s = fi;
      sel_ws[(bh * 2 + src) * 64 + it] = fi;
    }
    __syncthreads();
    int fi = winner_s;
    if ((fi & 255) == tid) {
      amp[fi] = -1.f;
      bv = -1.f; bi = tid;
#pragma unroll
      for (int kk = 0; kk < 4; ++kk) {
        int t = tid + kk * 256;
        float vv = amp[t];
        if (vv > bv) { bv = vv; bi = t; }
      }
    }
  }
}

// ---------------------------------------------------------------------------
// Kernel 3: scores over selected rows -> two softmaxes -> fuse -> times V.
// Writes 0.5*attn directly into d_out at [(bh*64+d)*1024 + a].
// ---------------------------------------------------------------------------
__global__ __launch_bounds__(256) void k_attn(const float* __restrict__ q_g,
                                              const float* __restrict__ tfq,
                                              const float* __restrict__ k_g,
                                              const float* __restrict__ v_g,
                                              const float* __restrict__ wfuse,
                                              const int* __restrict__ sel_ws,
                                              float* __restrict__ out) {
  __shared__ float qselt[NTOP][64];
  __shared__ float qseltf[NTOP][64];
  __shared__ float vselt[NTOP][64];
  __shared__ float vseltf[NTOP][64];
  __shared__ float ks[256][65];
  const int aq = blockIdx.x & 3;
  const int bh = blockIdx.x >> 2;
  const int b = bh >> 3, h = bh & 7;
  const int a0 = aq * 256;
  const int tid = threadIdx.x;

  for (int idx = tid; idx < NTOP * 64; idx += 256) {
    int i = idx >> 6, e = idx & 63;
    int st = sel_ws[(bh * 2 + 0) * 64 + i];
    int sf = sel_ws[(bh * 2 + 1) * 64 + i];
    qselt[i][e]  = q_g[((size_t)(b * L_ + st) * H_ + h) * E_ + e];
    qseltf[i][e] = tfq[((size_t)(b * L_ + sf) * H_ + h) * E_ + e];
    vselt[i][e]  = v_g[((size_t)(b * L_ + st) * H_ + h) * E_ + e];
    vseltf[i][e] = v_g[((size_t)(b * L_ + sf) * H_ + h) * E_ + e];
  }
  for (int idx = tid; idx < 256 * 64; idx += 256) {
    int r = idx >> 6, e = idx & 63;
    ks[r][e] = k_g[((size_t)(b * L_ + a0 + r) * H_ + h) * E_ + e];
  }
  __syncthreads();

  const int a = a0 + tid;
  float wf0 = wfuse[(h * L_ + a) * 2 + 0];
  float wf1 = wfuse[(h * L_ + a) * 2 + 1];
  float wm = fmaxf(wf0, wf1);
  float ew0 = expf(wf0 - wm), ew1 = expf(wf1 - wm);
  float nw0 = ew0 / (ew0 + ew1), nw1 = ew1 / (ew0 + ew1);

  float ct[NTOP], ctf[NTOP];
  // pass: attn_t
  {
#pragma unroll
    for (int i = 0; i < NTOP; ++i) ct[i] = 0.f;
    for (int e = 0; e < 64; ++e) {
      float kv = ks[tid][e];
#pragma unroll
      for (int i = 0; i < NTOP; ++i) ct[i] = fmaf(qselt[i][e], kv, ct[i]);
    }
    float m = -1e30f;
#pragma unroll
    for (int i = 0; i < NTOP; ++i) { ct[i] *= SCALE_; m = fmaxf(m, ct[i]); }
    float sum = 0.f;
#pragma unroll
    for (int i = 0; i < NTOP; ++i) { ct[i] = expf(ct[i] - m); sum += ct[i]; }
    float c = 0.5f * nw0 / sum;   // fold 0.5 output scale here
#pragma unroll
    for (int i = 0; i < NTOP; ++i) ct[i] *= c;
  }
  // pass: attn_tf
  {
#pragma unroll
    for (int i = 0; i < NTOP; ++i) ctf[i] = 0.f;
    for (int e = 0; e < 64; ++e) {
      float kv = ks[tid][e];
#pragma unroll
      for (int i = 0; i < NTOP; ++i) ctf[i] = fmaf(qseltf[i][e], kv, ctf[i]);
    }
    float m = -1e30f;
#pragma unroll
    for (int i = 0; i < NTOP; ++i) { ctf[i] *= SCALE_; m = fmaxf(m, ctf[i]); }
    float sum = 0.f;
#pragma unroll
    for (int i = 0; i < NTOP; ++i) { ctf[i] = expf(ctf[i] - m); sum += ctf[i]; }
    float c = 0.5f * nw1 / sum;
#pragma unroll
    for (int i = 0; i < NTOP; ++i) ctf[i] *= c;
  }
  // out row (this thread's a): 0.5*(nw0*attn_t + nw1*attn_tf) @ V  -> ks[tid][d]
  for (int d = 0; d < 64; ++d) {
    float acc = 0.f;
#pragma unroll
    for (int i = 0; i < NTOP; ++i) acc = fmaf(ct[i], vselt[i][d], acc);
#pragma unroll
    for (int i = 0; i < NTOP; ++i) acc = fmaf(ctf[i], vseltf[i][d], acc);
    ks[tid][d] = acc;
  }
  __syncthreads();
  // transposed, coalesced store: out[(bh*64+d)*1024 + a0 + r]
  for (int idx = tid; idx < 256 * 64; idx += 256) {
    int d = idx >> 8, r = idx & 255;
    out[((size_t)(bh * 64 + d)) * 1024 + a0 + r] = ks[r][d];
  }
}

// ---------------------------------------------------------------------------
// Kernel 4: first 64 rfft modes of q / k along time (table-driven DFT).
// ft[((bh*64+e)*64+m)*2 + {0,1}] = Re/Im of sum_t x[t] e^{-2pi i m t/1024}
// ---------------------------------------------------------------------------
__global__ __launch_bounds__(256) void k_dft(const float* __restrict__ q_g,
                                             const float* __restrict__ k_g,
                                             float* __restrict__ qft,
                                             float* __restrict__ kft) {
  __shared__ float xs[16][1024];
  __shared__ float ctab[1024], stab[1024];
  const int src = blockIdx.x & 1;
  const int ec = (blockIdx.x >> 1) & 3;
  const int bh = blockIdx.x >> 3;
  const int b = bh >> 3, h = bh & 7;
  const int e0 = ec * 16;
  const int tid = threadIdx.x;
  const float* xg = src ? k_g : q_g;
  float* oft = src ? kft : qft;

  const float TWO_PI = 6.283185307179586f;
  for (int j = tid; j < 1024; j += 256) {
    float ang = TWO_PI * (float)j * (1.0f / 1024.0f);
    ctab[j] = cosf(ang); stab[j] = sinf(ang);
  }
  for (int idx = tid; idx < 16 * 1024; idx += 256) {
    int e = idx & 15, t = idx >> 4;
    xs[e][t] = xg[((size_t)(b * L_ + t) * H_ + h) * E_ + e0 + e];
  }
  __syncthreads();

  const int m = tid & 63, w = tid >> 6;
  const int ea = w, eb = w + 4, ec2 = w + 8, ed = w + 12;
  float r0 = 0.f, i0 = 0.f, r1 = 0.f, i1 = 0.f, r2 = 0.f, i2 = 0.f, r3 = 0.f, i3 = 0.f;
  for (int t = 0; t < 1024; ++t) {
    int j = (m * t) & 1023;
    float c = ctab[j], s = stab[j];
    float xa = xs[ea][t], xb = xs[eb][t], xc = xs[ec2][t], xd = xs[ed][t];
    r0 = fmaf(xa, c, r0); i0 = fmaf(xa, s, i0);
    r1 = fmaf(xb, c, r1); i1 = fmaf(xb, s, i1);
    r2 = fmaf(xc, c, r2); i2 = fmaf(xc, s, i2);
    r3 = fmaf(xd, c, r3); i3 = fmaf(xd, s, i3);
  }
  size_t o;
  o = ((size_t)(bh * 64 + e0 + ea) * 64 + m) * 2;  oft[o] = r0; oft[o + 1] = -i0;
  o = ((size_t)(bh * 64 + e0 + eb) * 64 + m) * 2;  oft[o] = r1; oft[o + 1] = -i1;
  o = ((size_t)(bh * 64 + e0 + ec2) * 64 + m) * 2; oft[o] = r2; oft[o + 1] = -i2;
  o = ((size_t)(bh * 64 + e0 + ed) * 64 + m) * 2;  oft[o] = r3; oft[o + 1] = -i3;
}

// ---------------------------------------------------------------------------
// Kernel 5a: xqk = ctanh(q_ft^T k_ft); xqkv = xqk @ k_ft^T.
// Grid: (bh, x-chunk of 8) = 256 blocks, 256 threads.
// Stores xqkv x-major: xre_g[bh*4096 + x*64 + e] (lane-coalesced).
// ---------------------------------------------------------------------------
__global__ __launch_bounds__(256) void k_spec12(const float* __restrict__ qft,
                                                 const float* __restrict__ kft,
                                                 float* __restrict__ xre_g,
                                                 float* __restrict__ xim_g) {
  __shared__ float kre[64][65], kim[64][65];
  __shared__ float qre[64][8], qim[64][8];
  __shared__ float tre[8][64], tim[8][64];
  const int xc = blockIdx.x & 7;
  const int bh = blockIdx.x >> 3;
  const int tid = threadIdx.x;

  for (int idx = tid; idx < 4096; idx += 256) {
    int e = idx >> 6, y = idx & 63;
    size_t o = ((size_t)(bh * 64 + e) * 64 + y) * 2;
    kre[e][y] = kft[o]; kim[e][y] = kft[o + 1];
  }
  for (int idx = tid; idx < 512; idx += 256) {
    int e = idx >> 3, xl = idx & 7;
    size_t o = ((size_t)(bh * 64 + e) * 64 + xc * 8 + xl) * 2;
    qre[e][xl] = qft[o]; qim[e][xl] = qft[o + 1];
  }
  __syncthreads();

  const int y = tid & 63, xg = tid >> 6;
  // xqk[x][y] = ctanh( sum_e conj-free complex dot )
#pragma unroll
  for (int xi = 0; xi < 2; ++xi) {
    int xl = xg + xi * 4;
    float ar = 0.f, ai = 0.f;
    for (int e = 0; e < 64; ++e) {
      float a = qre[e][xl], b = qim[e][xl];
      float c = kre[e][y], d = kim[e][y];
      ar = fmaf(a, c, fmaf(-b, d, ar));
      ai = fmaf(a, d, fmaf(b, c, ai));
    }
    float trv, tiv;
    float x2 = 2.f * ar, y2 = 2.f * ai;
    if (fabsf(x2) > 30.f) {
      trv = copysignf(1.f, ar); tiv = 0.f;
    } else {
      float sh = sinhf(x2), ch = coshf(x2);
      float sn = sinf(y2), cs = cosf(y2);
      float dd = ch + cs;
      trv = sh / dd; tiv = sn / dd;
    }
    tre[xl][y] = trv; tim[xl][y] = tiv;
  }
  __syncthreads();

  const int e2 = tid & 63, xg2 = tid >> 6;
  // xqkv[e][x] = sum_y xqk[x][y]*k[e][y]
#pragma unroll
  for (int xi = 0; xi < 2; ++xi) {
    int xl = xg2 + xi * 4;
    float ar = 0.f, ai = 0.f;
    for (int yy = 0; yy < 64; ++yy) {
      float a = tre[xl][yy], b = tim[xl][yy];
      float c = kre[e2][yy], d = kim[e2][yy];
      ar = fmaf(a, c, fmaf(-b, d, ar));
      ai = fmaf(a, d, fmaf(b, c, ai));
    }
    xre_g[(size_t)bh * 4096 + (xc * 8 + xl) * 64 + e2] = ar;
    xim_g[(size_t)bh * 4096 + (xc * 8 + xl) * 64 + e2] = ai;
  }
}

// ---------------------------------------------------------------------------
// Kernel 5b: xqkvw[o][x] = (sum_e xqkv[e][x]*w1[h,e,o,x]) / 512^2.
// xqkv planes are x-major: xre_g[bh*4096 + x*64 + e].
// ---------------------------------------------------------------------------
__global__ __launch_bounds__(256) void k_w1(const float* __restrict__ xre_g,
                                            const float* __restrict__ xim_g,
                                            const float* __restrict__ w1re,
                                            const float* __restrict__ w1im,
                                            float* __restrict__ xw) {
  __shared__ float xre[64][65], xim[64][65];
  __shared__ float redr[4][512], redi[4][512];
  const int oc = blockIdx.x & 7;
  const int bh = blockIdx.x >> 3;
  const int h = bh & 7;
  const int tid = threadIdx.x;

  for (int idx = tid; idx < 4096; idx += 256) {
    int x = idx >> 6, e = idx & 63;   // x-major global layout
    xre[e][x] = xre_g[(size_t)bh * 4096 + idx];
    xim[e][x] = xim_g[(size_t)bh * 4096 + idx];
  }
  __syncthreads();

  const int x = tid & 63, g = tid >> 6;
  float accr[8], acci[8];
#pragma unroll
  for (int oo = 0; oo < 8; ++oo) { accr[oo] = 0.f; acci[oo] = 0.f; }

  for (int ee = 0; ee < 16; ++ee) {
    int e = g * 16 + ee;
    float a = xre[e][x], b = xim[e][x];
    size_t wbase = (((size_t)h * 64 + e) * 64 + oc * 8) * 64 + x;
#pragma unroll
    for (int oo = 0; oo < 8; ++oo) {
      float c = w1re[wbase + (size_t)oo * 64];
      float d = w1im[wbase + (size_t)oo * 64];
      accr[oo] = fmaf(a, c, fmaf(-b, d, accr[oo]));
      acci[oo] = fmaf(a, d, fmaf(b, c, acci[oo]));
    }
  }
#pragma unroll
  for (int oo = 0; oo < 8; ++oo) {
    redr[g][oo * 64 + x] = accr[oo];
    redi[g][oo * 64 + x] = acci[oo];
  }
  __syncthreads();

  const float INV = 1.0f / (512.0f * 512.0f);
  for (int idx = tid; idx < 512; idx += 256) {
    int oo = idx >> 6, x2 = idx & 63;
    float r = redr[0][idx] + redr[1][idx] + redr[2][idx] + redr[3][idx];
    float i = redi[0][idx] + redi[1][idx] + redi[2][idx] + redi[3][idx];
    size_t oidx = ((size_t)(bh * 64 + oc * 8 + oo) * 64 + x2) * 2;
    xw[oidx] = r * INV;
    xw[oidx + 1] = i * INV;
  }
}

// ---------------------------------------------------------------------------
// Kernel 6: 64-mode irfft via per-thread rotation (no LDS tables, no bank
// conflicts), add 0.5*spec into d_out (which holds 0.5*attn).
// ---------------------------------------------------------------------------
__global__ __launch_bounds__(256) void k_final(const float* __restrict__ xw,
                                               float* __restrict__ out) {
  __shared__ float Xre[8][64], Xim[8][64];   // pre-scaled by 2
  const int oc = blockIdx.x & 7;
  const int bh = blockIdx.x >> 3;
  const int o0 = oc * 8;
  const int tid = threadIdx.x;

  for (int idx = tid; idx < 512; idx += 256) {
    int o = idx >> 6, m = idx & 63;
    size_t s = ((size_t)(bh * 64 + o0 + o) * 64 + m) * 2;
    Xre[o][m] = 2.f * xw[s]; Xim[o][m] = 2.f * xw[s + 1];
  }
  __syncthreads();

  const int ts = tid & 31, ol = tid >> 5;
  const float HALF_INVN = 0.5f / 1024.0f;
  const float TWO_PI = 6.283185307179586f;
  for (int k = 0; k < 32; ++k) {
    int t = ts + k * 32;
    float th = TWO_PI * (float)t * (1.0f / 1024.0f);
    float s1, c1;
    __sincosf(th, &s1, &c1);
    float cm = c1, sm = s1;
    float acc = 0.5f * Xre[ol][0];
#pragma unroll 9
    for (int m = 1; m < 64; ++m) {
      acc = fmaf(Xre[ol][m], cm, acc);
      acc = fmaf(-Xim[ol][m], sm, acc);
      float cn = fmaf(cm, c1, -sm * s1);
      float sn = fmaf(sm, c1, cm * s1);
      cm = cn; sm = sn;
    }
    size_t oi = ((size_t)(bh * 64 + o0 + ol)) * 1024 + t;
    out[oi] = fmaf(acc, HALF_INVN, out[oi]);
  }
}

// ---------------------------------------------------------------------------
extern "C" void kernel_launch(void* const* d_in, const int* in_sizes, int n_in,
                              void* d_out, int out_size, void* d_ws, size_t ws_size,
                              hipStream_t stream) {
  const float* tfq   = (const float*)d_in[0];
  const float* q     = (const float*)d_in[1];
  const float* k     = (const float*)d_in[2];
  const float* v     = (const float*)d_in[3];
  const float* wfuse = (const float*)d_in[5];
  const float* w1re  = (const float*)d_in[6];
  const float* w1im  = (const float*)d_in[7];
  float* out = (float*)d_out;
  float* ws  = (float*)d_ws;

  // ws layout (floats):
  //   amp2[262144]  (reused after k_topk as xqkv_re[131072] | xqkv_im[131072])
  //   sel(int)[4096] | qft[262144] | kft[262144] | xw[262144]
  float* amp2   = ws;
  float* xre_g  = ws;             // aliases amp2 (dead after k_topk)
  float* xim_g  = ws + 131072;
  int*   sel    = (int*)(ws + 262144);
  float* qft    = ws + 266240;
  float* kft    = ws + 528384;
  float* xw     = ws + 790528;

  k_corr<<<256, 256, 0, stream>>>(q, k, amp2);
  k_topk<<<64, 256, 0, stream>>>(amp2, tfq, sel);
  k_attn<<<128, 256, 0, stream>>>(q, tfq, k, v, wfuse, sel, out);
  k_dft<<<256, 256, 0, stream>>>(q, k, qft, kft);
  k_spec12<<<256, 256, 0, stream>>>(qft, kft, xre_g, xim_g);
  k_w1<<<256, 256, 0, stream>>>(xre_g, xim_g, w1re, w1im, xw);
  k_final<<<256, 256, 0, stream>>>(xw, out);
}

// Round 4
// 346.396 us; speedup vs baseline: 2.2628x; 1.2104x over previous
//
#include <hip/hip_runtime.h>
#include <math.h>

#define B_ 4
#define H_ 8
#define L_ 1024
#define E_ 64
#define NTOP 35
#define SCALE_ 0.04419417382415922f  /* 1/sqrt(512) */

// ---------------------------------------------------------------------------
// Kernel 1: partial circular cross-correlation amplitude^2.
// Grid: (bh, e-chunk of 8) = 256 blocks. Thread owns 8 tau x 4 e (half of the
// chunk); 3-float4 sliding window -> 32 FMA per per-lane LDS read.
// amp2_part[(bh*8+chunk)*1024 + tau] = sum_{e in chunk} corr_e(tau)^2
// ---------------------------------------------------------------------------
__global__ __launch_bounds__(256) void k_corr(const float* __restrict__ q_g,
                                              const float* __restrict__ k_g,
                                              float* __restrict__ amp2_part) {
  __shared__ __align__(16) float q_s[8][1024];
  __shared__ __align__(16) float k_s[8][1024];
  __shared__ float red[128][9];
  const int chunk = blockIdx.x & 7;
  const int bh = blockIdx.x >> 3;
  const int b = bh >> 3, h = bh & 7;
  const int e0 = chunk * 8;
  const int tid = threadIdx.x;

  // float4 staging: item = (t, f); f selects e-quad. LDS writes are t-major
  // scalar per e-row: 2-way bank conflict only (free).
  for (int idx = tid; idx < 2048; idx += 256) {
    int t = idx >> 1, f = idx & 1;
    size_t g4 = (((size_t)(b * L_ + t) * H_ + h) * E_ + e0 + f * 4) >> 2;
    float4 qv = reinterpret_cast<const float4*>(q_g)[g4];
    float4 kv = reinterpret_cast<const float4*>(k_g)[g4];
    q_s[f * 4 + 0][t] = qv.x; q_s[f * 4 + 1][t] = qv.y;
    q_s[f * 4 + 2][t] = qv.z; q_s[f * 4 + 3][t] = qv.w;
    k_s[f * 4 + 0][t] = kv.x; k_s[f * 4 + 1][t] = kv.y;
    k_s[f * 4 + 2][t] = kv.z; k_s[f * 4 + 3][t] = kv.w;
  }
  __syncthreads();

  const int eh = tid >> 7;      // e-half: 0 -> e 0..3, 1 -> e 4..7
  const int ti = tid & 127;     // tau group
  const int tb4 = ti * 2;       // tau base in float4 units (tau = ti*8)

  float a0 = 0.f, a1 = 0.f, a2 = 0.f, a3 = 0.f;
  float a4 = 0.f, a5 = 0.f, a6 = 0.f, a7 = 0.f;

  for (int ei = 0; ei < 4; ++ei) {
    const int e = eh * 4 + ei;
    const float4* q4 = reinterpret_cast<const float4*>(q_s[e]);
    const float4* k4 = reinterpret_cast<const float4*>(k_s[e]);
    float c0 = 0.f, c1 = 0.f, c2 = 0.f, c3 = 0.f;
    float c4 = 0.f, c5 = 0.f, c6 = 0.f, c7 = 0.f;
    float4 wa = q4[tb4];
    float4 wb = q4[(tb4 + 1) & 255];
#pragma unroll 4
    for (int t4 = 0; t4 < 256; ++t4) {
      float4 wc = q4[(tb4 + t4 + 2) & 255];
      float4 kv = k4[t4];
      c0 = fmaf(wa.x, kv.x, c0); c0 = fmaf(wa.y, kv.y, c0); c0 = fmaf(wa.z, kv.z, c0); c0 = fmaf(wa.w, kv.w, c0);
      c1 = fmaf(wa.y, kv.x, c1); c1 = fmaf(wa.z, kv.y, c1); c1 = fmaf(wa.w, kv.z, c1); c1 = fmaf(wb.x, kv.w, c1);
      c2 = fmaf(wa.z, kv.x, c2); c2 = fmaf(wa.w, kv.y, c2); c2 = fmaf(wb.x, kv.z, c2); c2 = fmaf(wb.y, kv.w, c2);
      c3 = fmaf(wa.w, kv.x, c3); c3 = fmaf(wb.x, kv.y, c3); c3 = fmaf(wb.y, kv.z, c3); c3 = fmaf(wb.z, kv.w, c3);
      c4 = fmaf(wb.x, kv.x, c4); c4 = fmaf(wb.y, kv.y, c4); c4 = fmaf(wb.z, kv.z, c4); c4 = fmaf(wb.w, kv.w, c4);
      c5 = fmaf(wb.y, kv.x, c5); c5 = fmaf(wb.z, kv.y, c5); c5 = fmaf(wb.w, kv.z, c5); c5 = fmaf(wc.x, kv.w, c5);
      c6 = fmaf(wb.z, kv.x, c6); c6 = fmaf(wb.w, kv.y, c6); c6 = fmaf(wc.x, kv.z, c6); c6 = fmaf(wc.y, kv.w, c6);
      c7 = fmaf(wb.w, kv.x, c7); c7 = fmaf(wc.x, kv.y, c7); c7 = fmaf(wc.y, kv.z, c7); c7 = fmaf(wc.z, kv.w, c7);
      wa = wb; wb = wc;
    }
    a0 = fmaf(c0, c0, a0); a1 = fmaf(c1, c1, a1); a2 = fmaf(c2, c2, a2); a3 = fmaf(c3, c3, a3);
    a4 = fmaf(c4, c4, a4); a5 = fmaf(c5, c5, a5); a6 = fmaf(c6, c6, a6); a7 = fmaf(c7, c7, a7);
  }

  if (eh == 1) {
    red[ti][0] = a0; red[ti][1] = a1; red[ti][2] = a2; red[ti][3] = a3;
    red[ti][4] = a4; red[ti][5] = a5; red[ti][6] = a6; red[ti][7] = a7;
  }
  __syncthreads();
  if (eh == 0) {
    float4 o0 = make_float4(a0 + red[ti][0], a1 + red[ti][1],
                            a2 + red[ti][2], a3 + red[ti][3]);
    float4 o1 = make_float4(a4 + red[ti][4], a5 + red[ti][5],
                            a6 + red[ti][6], a7 + red[ti][7]);
    float* dst = &amp2_part[(size_t)blockIdx.x * 1024 + ti * 8];
    reinterpret_cast<float4*>(dst)[0] = o0;
    reinterpret_cast<float4*>(dst)[1] = o1;
  }
}

// ---------------------------------------------------------------------------
// Kernel 2: top-35 selection per (b,h,src). Wave-shuffle argmax per round;
// only the owner thread rescans after removal. Lowest-index tie-break.
// ---------------------------------------------------------------------------
__global__ __launch_bounds__(256) void k_topk(const float* __restrict__ amp2_part,
                                              const float* __restrict__ tfq,
                                              int* __restrict__ sel_ws) {
  __shared__ float amp[1024];
  __shared__ float wv_s[4];
  __shared__ int wi_s[4];
  __shared__ int winner_s;
  const int src = blockIdx.x & 1;
  const int bh = blockIdx.x >> 1;
  const int b = bh >> 3, h = bh & 7;
  const int tid = threadIdx.x;

  if (src == 0) {
    for (int t = tid; t < 1024; t += 256) {
      float s = 0.f;
      for (int c = 0; c < 8; ++c) s += amp2_part[(size_t)(bh * 8 + c) * 1024 + t];
      amp[t] = s;
    }
  } else {
    for (int l = tid; l < 1024; l += 256) {
      const float4* p4 = reinterpret_cast<const float4*>(
          &tfq[((size_t)(b * L_ + l) * H_ + h) * E_]);
      float s = 0.f;
#pragma unroll
      for (int e4 = 0; e4 < 16; ++e4) {
        float4 v = p4[e4];
        s += v.x * v.x + v.y * v.y + v.z * v.z + v.w * v.w;
      }
      amp[l] = s;
    }
  }
  __syncthreads();

  // local max over the 4 owned slots (t = tid + 256k), ascending scan
  float bv = -1.f; int bi = tid;
#pragma unroll
  for (int kk = 0; kk < 4; ++kk) {
    int t = tid + kk * 256;
    float v = amp[t];
    if (v > bv) { bv = v; bi = t; }
  }
  const int lane = tid & 63, w = tid >> 6;

  for (int it = 0; it < NTOP; ++it) {
    float v = bv; int i = bi;
#pragma unroll
    for (int d = 1; d < 64; d <<= 1) {
      float ov = __shfl_xor(v, d);
      int oi = __shfl_xor(i, d);
      if (ov > v || (ov == v && oi < i)) { v = ov; i = oi; }
    }
    if (lane == 0) { wv_s[w] = v; wi_s[w] = i; }
    __syncthreads();
    if (tid == 0) {
      float fv = wv_s[0]; int fi = wi_s[0];
#pragma unroll
      for (int j = 1; j < 4; ++j) {
        if (wv_s[j] > fv || (wv_s[j] == fv && wi_s[j] < fi)) { fv = wv_s[j]; fi = wi_s[j]; }
      }
      winner_s = fi;
      sel_ws[(bh * 2 + src) * 64 + it] = fi;
    }
    __syncthreads();
    int fi = winner_s;
    if ((fi & 255) == tid) {
      amp[fi] = -1.f;
      bv = -1.f; bi = tid;
#pragma unroll
      for (int kk = 0; kk < 4; ++kk) {
        int t = tid + kk * 256;
        float vv = amp[t];
        if (vv > bv) { bv = vv; bi = t; }
      }
    }
  }
}

// ---------------------------------------------------------------------------
// Kernel 3: scores over selected rows -> two softmaxes -> fuse -> times V.
// Writes 0.5*attn directly into d_out at [(bh*64+d)*1024 + a].
// ---------------------------------------------------------------------------
__global__ __launch_bounds__(256) void k_attn(const float* __restrict__ q_g,
                                              const float* __restrict__ tfq,
                                              const float* __restrict__ k_g,
                                              const float* __restrict__ v_g,
                                              const float* __restrict__ wfuse,
                                              const int* __restrict__ sel_ws,
                                              float* __restrict__ out) {
  __shared__ float qselt[NTOP][64];
  __shared__ float qseltf[NTOP][64];
  __shared__ float vselt[NTOP][64];
  __shared__ float vseltf[NTOP][64];
  __shared__ float ks[256][65];
  const int aq = blockIdx.x & 3;
  const int bh = blockIdx.x >> 2;
  const int b = bh >> 3, h = bh & 7;
  const int a0 = aq * 256;
  const int tid = threadIdx.x;

  for (int idx = tid; idx < NTOP * 64; idx += 256) {
    int i = idx >> 6, e = idx & 63;
    int st = sel_ws[(bh * 2 + 0) * 64 + i];
    int sf = sel_ws[(bh * 2 + 1) * 64 + i];
    qselt[i][e]  = q_g[((size_t)(b * L_ + st) * H_ + h) * E_ + e];
    qseltf[i][e] = tfq[((size_t)(b * L_ + sf) * H_ + h) * E_ + e];
    vselt[i][e]  = v_g[((size_t)(b * L_ + st) * H_ + h) * E_ + e];
    vseltf[i][e] = v_g[((size_t)(b * L_ + sf) * H_ + h) * E_ + e];
  }
  for (int idx = tid; idx < 256 * 64; idx += 256) {
    int r = idx >> 6, e = idx & 63;
    ks[r][e] = k_g[((size_t)(b * L_ + a0 + r) * H_ + h) * E_ + e];
  }
  __syncthreads();

  const int a = a0 + tid;
  float wf0 = wfuse[(h * L_ + a) * 2 + 0];
  float wf1 = wfuse[(h * L_ + a) * 2 + 1];
  float wm = fmaxf(wf0, wf1);
  float ew0 = expf(wf0 - wm), ew1 = expf(wf1 - wm);
  float nw0 = ew0 / (ew0 + ew1), nw1 = ew1 / (ew0 + ew1);

  float ct[NTOP], ctf[NTOP];
  // pass: attn_t
  {
#pragma unroll
    for (int i = 0; i < NTOP; ++i) ct[i] = 0.f;
    for (int e = 0; e < 64; ++e) {
      float kv = ks[tid][e];
#pragma unroll
      for (int i = 0; i < NTOP; ++i) ct[i] = fmaf(qselt[i][e], kv, ct[i]);
    }
    float m = -1e30f;
#pragma unroll
    for (int i = 0; i < NTOP; ++i) { ct[i] *= SCALE_; m = fmaxf(m, ct[i]); }
    float sum = 0.f;
#pragma unroll
    for (int i = 0; i < NTOP; ++i) { ct[i] = expf(ct[i] - m); sum += ct[i]; }
    float c = 0.5f * nw0 / sum;   // fold 0.5 output scale here
#pragma unroll
    for (int i = 0; i < NTOP; ++i) ct[i] *= c;
  }
  // pass: attn_tf
  {
#pragma unroll
    for (int i = 0; i < NTOP; ++i) ctf[i] = 0.f;
    for (int e = 0; e < 64; ++e) {
      float kv = ks[tid][e];
#pragma unroll
      for (int i = 0; i < NTOP; ++i) ctf[i] = fmaf(qseltf[i][e], kv, ctf[i]);
    }
    float m = -1e30f;
#pragma unroll
    for (int i = 0; i < NTOP; ++i) { ctf[i] *= SCALE_; m = fmaxf(m, ctf[i]); }
    float sum = 0.f;
#pragma unroll
    for (int i = 0; i < NTOP; ++i) { ctf[i] = expf(ctf[i] - m); sum += ctf[i]; }
    float c = 0.5f * nw1 / sum;
#pragma unroll
    for (int i = 0; i < NTOP; ++i) ctf[i] *= c;
  }
  // out row (this thread's a): 0.5*(nw0*attn_t + nw1*attn_tf) @ V  -> ks[tid][d]
  for (int d = 0; d < 64; ++d) {
    float acc = 0.f;
#pragma unroll
    for (int i = 0; i < NTOP; ++i) acc = fmaf(ct[i], vselt[i][d], acc);
#pragma unroll
    for (int i = 0; i < NTOP; ++i) acc = fmaf(ctf[i], vseltf[i][d], acc);
    ks[tid][d] = acc;
  }
  __syncthreads();
  // transposed, coalesced store: out[(bh*64+d)*1024 + a0 + r]
  for (int idx = tid; idx < 256 * 64; idx += 256) {
    int d = idx >> 8, r = idx & 255;
    out[((size_t)(bh * 64 + d)) * 1024 + a0 + r] = ks[r][d];
  }
}

// ---------------------------------------------------------------------------
// Kernel 4: first 64 rfft modes via per-thread rotation recurrence.
// Grid: (bh, src, e-chunk of 8) = 512 blocks. Thread: m = tid&63, 2 e's.
// All LDS reads are wave-broadcast (no conflicts); stores coalesced float2.
// ---------------------------------------------------------------------------
__global__ __launch_bounds__(256) void k_dft(const float* __restrict__ q_g,
                                             const float* __restrict__ k_g,
                                             float* __restrict__ qft,
                                             float* __restrict__ kft) {
  __shared__ float xs[8][1024];
  const int src = blockIdx.x & 1;
  const int ec = (blockIdx.x >> 1) & 7;
  const int bh = blockIdx.x >> 4;
  const int b = bh >> 3, h = bh & 7;
  const int e0 = ec * 8;
  const int tid = threadIdx.x;
  const float* xg = src ? k_g : q_g;
  float* oft = src ? kft : qft;

  for (int idx = tid; idx < 2048; idx += 256) {
    int t = idx >> 1, f = idx & 1;
    size_t g4 = (((size_t)(b * L_ + t) * H_ + h) * E_ + e0 + f * 4) >> 2;
    float4 xv = reinterpret_cast<const float4*>(xg)[g4];
    xs[f * 4 + 0][t] = xv.x; xs[f * 4 + 1][t] = xv.y;
    xs[f * 4 + 2][t] = xv.z; xs[f * 4 + 3][t] = xv.w;
  }
  __syncthreads();

  const int m = tid & 63, eg = tid >> 6;
  const int ea = eg * 2, eb = eg * 2 + 1;
  const float TWO_PI = 6.283185307179586f;
  float c1, s1;
  sincosf(TWO_PI * (float)m * (1.0f / 1024.0f), &s1, &c1);
  float cm = 1.f, sm = 0.f;
  float r0 = 0.f, i0 = 0.f, r1 = 0.f, i1 = 0.f;
#pragma unroll 4
  for (int t = 0; t < 1024; ++t) {
    float xa = xs[ea][t], xb = xs[eb][t];
    r0 = fmaf(xa, cm, r0); i0 = fmaf(xa, sm, i0);
    r1 = fmaf(xb, cm, r1); i1 = fmaf(xb, sm, i1);
    float cn = fmaf(cm, c1, -sm * s1);
    float sn = fmaf(sm, c1, cm * s1);
    cm = cn; sm = sn;
  }
  float2 o0 = make_float2(r0, -i0);
  float2 o1 = make_float2(r1, -i1);
  reinterpret_cast<float2*>(oft)[(size_t)(bh * 64 + e0 + ea) * 64 + m] = o0;
  reinterpret_cast<float2*>(oft)[(size_t)(bh * 64 + e0 + eb) * 64 + m] = o1;
}

// ---------------------------------------------------------------------------
// Kernel 5a: xqk = ctanh(q_ft^T k_ft); xqkv = xqk @ k_ft^T.
// Grid: (bh, x-chunk of 8) = 256 blocks, 256 threads.
// Stores xqkv x-major: xre_g[bh*4096 + x*64 + e] (lane-coalesced).
// ---------------------------------------------------------------------------
__global__ __launch_bounds__(256) void k_spec12(const float* __restrict__ qft,
                                                 const float* __restrict__ kft,
                                                 float* __restrict__ xre_g,
                                                 float* __restrict__ xim_g) {
  __shared__ float kre[64][65], kim[64][65];
  __shared__ float qre[64][8], qim[64][8];
  __shared__ float tre[8][64], tim[8][64];
  const int xc = blockIdx.x & 7;
  const int bh = blockIdx.x >> 3;
  const int tid = threadIdx.x;

  for (int idx = tid; idx < 4096; idx += 256) {
    int e = idx >> 6, y = idx & 63;
    size_t o = ((size_t)(bh * 64 + e) * 64 + y) * 2;
    kre[e][y] = kft[o]; kim[e][y] = kft[o + 1];
  }
  for (int idx = tid; idx < 512; idx += 256) {
    int e = idx >> 3, xl = idx & 7;
    size_t o = ((size_t)(bh * 64 + e) * 64 + xc * 8 + xl) * 2;
    qre[e][xl] = qft[o]; qim[e][xl] = qft[o + 1];
  }
  __syncthreads();

  const int y = tid & 63, xg = tid >> 6;
  // xqk[x][y] = ctanh( sum_e conj-free complex dot )
#pragma unroll
  for (int xi = 0; xi < 2; ++xi) {
    int xl = xg + xi * 4;
    float ar = 0.f, ai = 0.f;
    for (int e = 0; e < 64; ++e) {
      float a = qre[e][xl], b = qim[e][xl];
      float c = kre[e][y], d = kim[e][y];
      ar = fmaf(a, c, fmaf(-b, d, ar));
      ai = fmaf(a, d, fmaf(b, c, ai));
    }
    float trv, tiv;
    float x2 = 2.f * ar, y2 = 2.f * ai;
    if (fabsf(x2) > 30.f) {
      trv = copysignf(1.f, ar); tiv = 0.f;
    } else {
      float sh = sinhf(x2), ch = coshf(x2);
      float sn = sinf(y2), cs = cosf(y2);
      float dd = ch + cs;
      trv = sh / dd; tiv = sn / dd;
    }
    tre[xl][y] = trv; tim[xl][y] = tiv;
  }
  __syncthreads();

  const int e2 = tid & 63, xg2 = tid >> 6;
  // xqkv[e][x] = sum_y xqk[x][y]*k[e][y]
#pragma unroll
  for (int xi = 0; xi < 2; ++xi) {
    int xl = xg2 + xi * 4;
    float ar = 0.f, ai = 0.f;
    for (int yy = 0; yy < 64; ++yy) {
      float a = tre[xl][yy], b = tim[xl][yy];
      float c = kre[e2][yy], d = kim[e2][yy];
      ar = fmaf(a, c, fmaf(-b, d, ar));
      ai = fmaf(a, d, fmaf(b, c, ai));
    }
    xre_g[(size_t)bh * 4096 + (xc * 8 + xl) * 64 + e2] = ar;
    xim_g[(size_t)bh * 4096 + (xc * 8 + xl) * 64 + e2] = ai;
  }
}

// ---------------------------------------------------------------------------
// Kernel 5b: xqkvw[o][x] = (sum_e xqkv[e][x]*w1[h,e,o,x]) / 512^2.
// xqkv planes are x-major: xre_g[bh*4096 + x*64 + e].
// ---------------------------------------------------------------------------
__global__ __launch_bounds__(256) void k_w1(const float* __restrict__ xre_g,
                                            const float* __restrict__ xim_g,
                                            const float* __restrict__ w1re,
                                            const float* __restrict__ w1im,
                                            float* __restrict__ xw) {
  __shared__ float xre[64][65], xim[64][65];
  __shared__ float redr[4][512], redi[4][512];
  const int oc = blockIdx.x & 7;
  const int bh = blockIdx.x >> 3;
  const int h = bh & 7;
  const int tid = threadIdx.x;

  for (int idx = tid; idx < 4096; idx += 256) {
    int x = idx >> 6, e = idx & 63;   // x-major global layout
    xre[e][x] = xre_g[(size_t)bh * 4096 + idx];
    xim[e][x] = xim_g[(size_t)bh * 4096 + idx];
  }
  __syncthreads();

  const int x = tid & 63, g = tid >> 6;
  float accr[8], acci[8];
#pragma unroll
  for (int oo = 0; oo < 8; ++oo) { accr[oo] = 0.f; acci[oo] = 0.f; }

  for (int ee = 0; ee < 16; ++ee) {
    int e = g * 16 + ee;
    float a = xre[e][x], b = xim[e][x];
    size_t wbase = (((size_t)h * 64 + e) * 64 + oc * 8) * 64 + x;
#pragma unroll
    for (int oo = 0; oo < 8; ++oo) {
      float c = w1re[wbase + (size_t)oo * 64];
      float d = w1im[wbase + (size_t)oo * 64];
      accr[oo] = fmaf(a, c, fmaf(-b, d, accr[oo]));
      acci[oo] = fmaf(a, d, fmaf(b, c, acci[oo]));
    }
  }
#pragma unroll
  for (int oo = 0; oo < 8; ++oo) {
    redr[g][oo * 64 + x] = accr[oo];
    redi[g][oo * 64 + x] = acci[oo];
  }
  __syncthreads();

  const float INV = 1.0f / (512.0f * 512.0f);
  for (int idx = tid; idx < 512; idx += 256) {
    int oo = idx >> 6, x2 = idx & 63;
    float r = redr[0][idx] + redr[1][idx] + redr[2][idx] + redr[3][idx];
    float i = redi[0][idx] + redi[1][idx] + redi[2][idx] + redi[3][idx];
    size_t oidx = ((size_t)(bh * 64 + oc * 8 + oo) * 64 + x2) * 2;
    xw[oidx] = r * INV;
    xw[oidx + 1] = i * INV;
  }
}

// ---------------------------------------------------------------------------
// Kernel 6: 64-mode irfft via per-thread rotation (no LDS tables, no bank
// conflicts), add 0.5*spec into d_out (which holds 0.5*attn).
// ---------------------------------------------------------------------------
__global__ __launch_bounds__(256) void k_final(const float* __restrict__ xw,
                                               float* __restrict__ out) {
  __shared__ float Xre[8][64], Xim[8][64];   // pre-scaled by 2
  const int oc = blockIdx.x & 7;
  const int bh = blockIdx.x >> 3;
  const int o0 = oc * 8;
  const int tid = threadIdx.x;

  for (int idx = tid; idx < 512; idx += 256) {
    int o = idx >> 6, m = idx & 63;
    size_t s = ((size_t)(bh * 64 + o0 + o) * 64 + m) * 2;
    Xre[o][m] = 2.f * xw[s]; Xim[o][m] = 2.f * xw[s + 1];
  }
  __syncthreads();

  const int ts = tid & 31, ol = tid >> 5;
  const float HALF_INVN = 0.5f / 1024.0f;
  const float TWO_PI = 6.283185307179586f;
  for (int k = 0; k < 32; ++k) {
    int t = ts + k * 32;
    float th = TWO_PI * (float)t * (1.0f / 1024.0f);
    float s1, c1;
    __sincosf(th, &s1, &c1);
    float cm = c1, sm = s1;
    float acc = 0.5f * Xre[ol][0];
#pragma unroll 9
    for (int m = 1; m < 64; ++m) {
      acc = fmaf(Xre[ol][m], cm, acc);
      acc = fmaf(-Xim[ol][m], sm, acc);
      float cn = fmaf(cm, c1, -sm * s1);
      float sn = fmaf(sm, c1, cm * s1);
      cm = cn; sm = sn;
    }
    size_t oi = ((size_t)(bh * 64 + o0 + ol)) * 1024 + t;
    out[oi] = fmaf(acc, HALF_INVN, out[oi]);
  }
}

// ---------------------------------------------------------------------------
extern "C" void kernel_launch(void* const* d_in, const int* in_sizes, int n_in,
                              void* d_out, int out_size, void* d_ws, size_t ws_size,
                              hipStream_t stream) {
  const float* tfq   = (const float*)d_in[0];
  const float* q     = (const float*)d_in[1];
  const float* k     = (const float*)d_in[2];
  const float* v     = (const float*)d_in[3];
  const float* wfuse = (const float*)d_in[5];
  const float* w1re  = (const float*)d_in[6];
  const float* w1im  = (const float*)d_in[7];
  float* out = (float*)d_out;
  float* ws  = (float*)d_ws;

  // ws layout (floats):
  //   amp2[262144]  (reused after k_topk as xqkv_re[131072] | xqkv_im[131072])
  //   sel(int)[4096] | qft[262144] | kft[262144] | xw[262144]
  float* amp2   = ws;
  float* xre_g  = ws;             // aliases amp2 (dead after k_topk)
  float* xim_g  = ws + 131072;
  int*   sel    = (int*)(ws + 262144);
  float* qft    = ws + 266240;
  float* kft    = ws + 528384;
  float* xw     = ws + 790528;

  k_corr<<<256, 256, 0, stream>>>(q, k, amp2);
  k_topk<<<64, 256, 0, stream>>>(amp2, tfq, sel);
  k_attn<<<128, 256, 0, stream>>>(q, tfq, k, v, wfuse, sel, out);
  k_dft<<<512, 256, 0, stream>>>(q, k, qft, kft);
  k_spec12<<<256, 256, 0, stream>>>(qft, kft, xre_g, xim_g);
  k_w1<<<256, 256, 0, stream>>>(xre_g, xim_g, w1re, w1im, xw);
  k_final<<<256, 256, 0, stream>>>(xw, out);
}

// Round 5
// 319.899 us; speedup vs baseline: 2.4502x; 1.0828x over previous
//
#include <hip/hip_runtime.h>
#include <math.h>

#define B_ 4
#define H_ 8
#define L_ 1024
#define E_ 64
#define NTOP 35
#define SCALE_ 0.04419417382415922f  /* 1/sqrt(512) */

// ---------------------------------------------------------------------------
// Kernel 1: partial circular cross-correlation amplitude^2.
// Grid: (bh, e-chunk of 8) = 256 blocks x 512 threads.
// Thread: eq = tid>>7 owns 2 e's; ti = tid&127 owns 8 taus as TWO 4-tau
// windows (tau = w*512+lane*4 and +256) -> all LDS reads lane-consecutive
// (conflict-free); 32 FMA per per-lane float4 read.
// amp2_part[(bh*8+chunk)*1024 + tau] = sum_{e in chunk} corr_e(tau)^2
// ---------------------------------------------------------------------------
__global__ __launch_bounds__(512) void k_corr(const float* __restrict__ q_g,
                                              const float* __restrict__ k_g,
                                              float* __restrict__ amp2_part) {
  __shared__ __align__(16) float4 q_s4[8][256];
  __shared__ __align__(16) float4 k_s4[8][256];
  __shared__ float red[3][128][9];
  const int chunk = blockIdx.x & 7;
  const int bh = blockIdx.x >> 3;
  const int b = bh >> 3, h = bh & 7;
  const int e0 = chunk * 8;
  const int tid = threadIdx.x;

  float* q_sf = reinterpret_cast<float*>(q_s4);
  float* k_sf = reinterpret_cast<float*>(k_s4);
  // staging: item = (t, f); f selects e-quad. Transposed scalar writes are
  // 2-way bank conflicts only (free).
  for (int idx = tid; idx < 2048; idx += 512) {
    int t = idx >> 1, f = idx & 1;
    size_t g4 = (((size_t)(b * L_ + t) * H_ + h) * E_ + e0 + f * 4) >> 2;
    float4 qv = reinterpret_cast<const float4*>(q_g)[g4];
    float4 kv = reinterpret_cast<const float4*>(k_g)[g4];
    q_sf[(f * 4 + 0) * 1024 + t] = qv.x; q_sf[(f * 4 + 1) * 1024 + t] = qv.y;
    q_sf[(f * 4 + 2) * 1024 + t] = qv.z; q_sf[(f * 4 + 3) * 1024 + t] = qv.w;
    k_sf[(f * 4 + 0) * 1024 + t] = kv.x; k_sf[(f * 4 + 1) * 1024 + t] = kv.y;
    k_sf[(f * 4 + 2) * 1024 + t] = kv.z; k_sf[(f * 4 + 3) * 1024 + t] = kv.w;
  }
  __syncthreads();

  const int eq = tid >> 7;       // e-quarter: 2 e's
  const int ti = tid & 127;
  const int w = ti >> 6, lane = ti & 63;
  const int base4 = w * 128 + lane;   // window a base (float4 units)

  float a0 = 0.f, a1 = 0.f, a2 = 0.f, a3 = 0.f;
  float a4 = 0.f, a5 = 0.f, a6 = 0.f, a7 = 0.f;

  for (int ei = 0; ei < 2; ++ei) {
    const int e = eq * 2 + ei;
    const float4* q4 = &q_s4[e][0];
    const float4* k4 = &k_s4[e][0];
    float c0 = 0.f, c1 = 0.f, c2 = 0.f, c3 = 0.f;
    float c4 = 0.f, c5 = 0.f, c6 = 0.f, c7 = 0.f;
    float4 A0 = q4[base4 & 255];
    float4 B0 = q4[(base4 + 64) & 255];
#pragma unroll 4
    for (int t4 = 0; t4 < 256; ++t4) {
      float4 A1 = q4[(base4 + t4 + 1) & 255];
      float4 B1 = q4[(base4 + t4 + 65) & 255];
      float4 kv = k4[t4];
      c0 = fmaf(A0.x, kv.x, c0); c0 = fmaf(A0.y, kv.y, c0); c0 = fmaf(A0.z, kv.z, c0); c0 = fmaf(A0.w, kv.w, c0);
      c1 = fmaf(A0.y, kv.x, c1); c1 = fmaf(A0.z, kv.y, c1); c1 = fmaf(A0.w, kv.z, c1); c1 = fmaf(A1.x, kv.w, c1);
      c2 = fmaf(A0.z, kv.x, c2); c2 = fmaf(A0.w, kv.y, c2); c2 = fmaf(A1.x, kv.z, c2); c2 = fmaf(A1.y, kv.w, c2);
      c3 = fmaf(A0.w, kv.x, c3); c3 = fmaf(A1.x, kv.y, c3); c3 = fmaf(A1.y, kv.z, c3); c3 = fmaf(A1.z, kv.w, c3);
      c4 = fmaf(B0.x, kv.x, c4); c4 = fmaf(B0.y, kv.y, c4); c4 = fmaf(B0.z, kv.z, c4); c4 = fmaf(B0.w, kv.w, c4);
      c5 = fmaf(B0.y, kv.x, c5); c5 = fmaf(B0.z, kv.y, c5); c5 = fmaf(B0.w, kv.z, c5); c5 = fmaf(B1.x, kv.w, c5);
      c6 = fmaf(B0.z, kv.x, c6); c6 = fmaf(B0.w, kv.y, c6); c6 = fmaf(B1.x, kv.z, c6); c6 = fmaf(B1.y, kv.w, c6);
      c7 = fmaf(B0.w, kv.x, c7); c7 = fmaf(B1.x, kv.y, c7); c7 = fmaf(B1.y, kv.z, c7); c7 = fmaf(B1.z, kv.w, c7);
      A0 = A1; B0 = B1;
    }
    a0 = fmaf(c0, c0, a0); a1 = fmaf(c1, c1, a1); a2 = fmaf(c2, c2, a2); a3 = fmaf(c3, c3, a3);
    a4 = fmaf(c4, c4, a4); a5 = fmaf(c5, c5, a5); a6 = fmaf(c6, c6, a6); a7 = fmaf(c7, c7, a7);
  }

  if (eq > 0) {
    float* rr = red[eq - 1][ti];
    rr[0] = a0; rr[1] = a1; rr[2] = a2; rr[3] = a3;
    rr[4] = a4; rr[5] = a5; rr[6] = a6; rr[7] = a7;
  }
  __syncthreads();
  if (eq == 0) {
#pragma unroll
    for (int g = 0; g < 3; ++g) {
      const float* rr = red[g][ti];
      a0 += rr[0]; a1 += rr[1]; a2 += rr[2]; a3 += rr[3];
      a4 += rr[4]; a5 += rr[5]; a6 += rr[6]; a7 += rr[7];
    }
    float* dst = &amp2_part[(size_t)blockIdx.x * 1024 + w * 512 + lane * 4];
    *reinterpret_cast<float4*>(dst) = make_float4(a0, a1, a2, a3);
    *reinterpret_cast<float4*>(dst + 256) = make_float4(a4, a5, a6, a7);
  }
}

// ---------------------------------------------------------------------------
// Kernel 2: top-35 selection per (b,h,src). Wave-shuffle argmax per round;
// only the owner thread rescans after removal. Lowest-index tie-break.
// ---------------------------------------------------------------------------
__global__ __launch_bounds__(256) void k_topk(const float* __restrict__ amp2_part,
                                              const float* __restrict__ tfq,
                                              int* __restrict__ sel_ws) {
  __shared__ float amp[1024];
  __shared__ float wv_s[4];
  __shared__ int wi_s[4];
  __shared__ int winner_s;
  const int src = blockIdx.x & 1;
  const int bh = blockIdx.x >> 1;
  const int b = bh >> 3, h = bh & 7;
  const int tid = threadIdx.x;

  if (src == 0) {
    for (int t = tid; t < 1024; t += 256) {
      float s = 0.f;
      for (int c = 0; c < 8; ++c) s += amp2_part[(size_t)(bh * 8 + c) * 1024 + t];
      amp[t] = s;
    }
  } else {
    for (int l = tid; l < 1024; l += 256) {
      const float4* p4 = reinterpret_cast<const float4*>(
          &tfq[((size_t)(b * L_ + l) * H_ + h) * E_]);
      float s = 0.f;
#pragma unroll
      for (int e4 = 0; e4 < 16; ++e4) {
        float4 v = p4[e4];
        s += v.x * v.x + v.y * v.y + v.z * v.z + v.w * v.w;
      }
      amp[l] = s;
    }
  }
  __syncthreads();

  // local max over the 4 owned slots (t = tid + 256k), ascending scan
  float bv = -1.f; int bi = tid;
#pragma unroll
  for (int kk = 0; kk < 4; ++kk) {
    int t = tid + kk * 256;
    float v = amp[t];
    if (v > bv) { bv = v; bi = t; }
  }
  const int lane = tid & 63, w = tid >> 6;

  for (int it = 0; it < NTOP; ++it) {
    float v = bv; int i = bi;
#pragma unroll
    for (int d = 1; d < 64; d <<= 1) {
      float ov = __shfl_xor(v, d);
      int oi = __shfl_xor(i, d);
      if (ov > v || (ov == v && oi < i)) { v = ov; i = oi; }
    }
    if (lane == 0) { wv_s[w] = v; wi_s[w] = i; }
    __syncthreads();
    if (tid == 0) {
      float fv = wv_s[0]; int fi = wi_s[0];
#pragma unroll
      for (int j = 1; j < 4; ++j) {
        if (wv_s[j] > fv || (wv_s[j] == fv && wi_s[j] < fi)) { fv = wv_s[j]; fi = wi_s[j]; }
      }
      winner_s = fi;
      sel_ws[(bh * 2 + src) * 64 + it] = fi;
    }
    __syncthreads();
    int fi = winner_s;
    if ((fi & 255) == tid) {
      amp[fi] = -1.f;
      bv = -1.f; bi = tid;
#pragma unroll
      for (int kk = 0; kk < 4; ++kk) {
        int t = tid + kk * 256;
        float vv = amp[t];
        if (vv > bv) { bv = vv; bi = t; }
      }
    }
  }
}

// ---------------------------------------------------------------------------
// Kernel 3: scores over selected rows -> two softmaxes -> fuse -> times V.
// Grid: (bh, a-chunk of 64) = 512 blocks x 256 threads.
// Thread = (row r = tid>>2, quarter qd = tid&3): qd splits the e-sum for
// scores (shfl_xor combine within wave) and the d-range for the output.
// Writes 0.5*attn directly into d_out at [(bh*64+d)*1024 + a].
// ---------------------------------------------------------------------------
__global__ __launch_bounds__(256) void k_attn(const float* __restrict__ q_g,
                                              const float* __restrict__ tfq,
                                              const float* __restrict__ k_g,
                                              const float* __restrict__ v_g,
                                              const float* __restrict__ wfuse,
                                              const int* __restrict__ sel_ws,
                                              float* __restrict__ out) {
  __shared__ float qselt[NTOP][64];
  __shared__ float qseltf[NTOP][64];
  __shared__ float vselt[NTOP][64];
  __shared__ float vseltf[NTOP][64];
  __shared__ float ks[64][65];
  const int ac = blockIdx.x & 15;
  const int bh = blockIdx.x >> 4;
  const int b = bh >> 3, h = bh & 7;
  const int a0 = ac * 64;
  const int tid = threadIdx.x;

  for (int idx = tid; idx < NTOP * 64; idx += 256) {
    int i = idx >> 6, e = idx & 63;
    int st = sel_ws[(bh * 2 + 0) * 64 + i];
    int sf = sel_ws[(bh * 2 + 1) * 64 + i];
    qselt[i][e]  = q_g[((size_t)(b * L_ + st) * H_ + h) * E_ + e];
    qseltf[i][e] = tfq[((size_t)(b * L_ + sf) * H_ + h) * E_ + e];
    vselt[i][e]  = v_g[((size_t)(b * L_ + st) * H_ + h) * E_ + e];
    vseltf[i][e] = v_g[((size_t)(b * L_ + sf) * H_ + h) * E_ + e];
  }
  for (int idx = tid; idx < 64 * 64; idx += 256) {
    int r = idx >> 6, e = idx & 63;
    ks[r][e] = k_g[((size_t)(b * L_ + a0 + r) * H_ + h) * E_ + e];
  }
  __syncthreads();

  const int qd = tid & 3, r = tid >> 2;
  const int a = a0 + r;
  const int eb = qd * 16;

  float ct[NTOP], ctf[NTOP];
#pragma unroll
  for (int i = 0; i < NTOP; ++i) { ct[i] = 0.f; ctf[i] = 0.f; }
  // partial scores over this quarter's 16 e's
  for (int j = 0; j < 16; ++j) {
    float kv = ks[r][eb + j];
#pragma unroll
    for (int i = 0; i < NTOP; ++i) {
      ct[i]  = fmaf(qselt[i][eb + j], kv, ct[i]);
      ctf[i] = fmaf(qseltf[i][eb + j], kv, ctf[i]);
    }
  }
  // combine quarters (lanes 4r..4r+3 are in the same wave)
#pragma unroll
  for (int i = 0; i < NTOP; ++i) {
    ct[i] += __shfl_xor(ct[i], 1);  ct[i] += __shfl_xor(ct[i], 2);
    ctf[i] += __shfl_xor(ctf[i], 1); ctf[i] += __shfl_xor(ctf[i], 2);
  }

  float wf0 = wfuse[(h * L_ + a) * 2 + 0];
  float wf1 = wfuse[(h * L_ + a) * 2 + 1];
  float wm = fmaxf(wf0, wf1);
  float ew0 = expf(wf0 - wm), ew1 = expf(wf1 - wm);
  float nw0 = ew0 / (ew0 + ew1), nw1 = ew1 / (ew0 + ew1);

  // softmaxes (replicated across the 4 lanes of the row)
  {
    float m = -1e30f;
#pragma unroll
    for (int i = 0; i < NTOP; ++i) { ct[i] *= SCALE_; m = fmaxf(m, ct[i]); }
    float sum = 0.f;
#pragma unroll
    for (int i = 0; i < NTOP; ++i) { ct[i] = expf(ct[i] - m); sum += ct[i]; }
    float c = 0.5f * nw0 / sum;
#pragma unroll
    for (int i = 0; i < NTOP; ++i) ct[i] *= c;
  }
  {
    float m = -1e30f;
#pragma unroll
    for (int i = 0; i < NTOP; ++i) { ctf[i] *= SCALE_; m = fmaxf(m, ctf[i]); }
    float sum = 0.f;
#pragma unroll
    for (int i = 0; i < NTOP; ++i) { ctf[i] = expf(ctf[i] - m); sum += ctf[i]; }
    float c = 0.5f * nw1 / sum;
#pragma unroll
    for (int i = 0; i < NTOP; ++i) ctf[i] *= c;
  }
  // output: this thread covers d = qd*16 .. qd*16+15 for its row
  for (int j = 0; j < 16; ++j) {
    int d = eb + j;
    float acc = 0.f;
#pragma unroll
    for (int i = 0; i < NTOP; ++i) acc = fmaf(ct[i], vselt[i][d], acc);
#pragma unroll
    for (int i = 0; i < NTOP; ++i) acc = fmaf(ctf[i], vseltf[i][d], acc);
    out[((size_t)(bh * 64 + d)) * 1024 + a] = acc;
  }
}

// ---------------------------------------------------------------------------
// Kernel 4: first 64 rfft modes via per-thread rotation recurrence.
// Grid: (bh, src, e-chunk of 8) = 512 blocks. Thread: m = tid&63, 2 e's.
// All LDS reads are wave-broadcast (no conflicts); stores coalesced float2.
// ---------------------------------------------------------------------------
__global__ __launch_bounds__(256) void k_dft(const float* __restrict__ q_g,
                                             const float* __restrict__ k_g,
                                             float* __restrict__ qft,
                                             float* __restrict__ kft) {
  __shared__ float xs[8][1024];
  const int src = blockIdx.x & 1;
  const int ec = (blockIdx.x >> 1) & 7;
  const int bh = blockIdx.x >> 4;
  const int b = bh >> 3, h = bh & 7;
  const int e0 = ec * 8;
  const int tid = threadIdx.x;
  const float* xg = src ? k_g : q_g;
  float* oft = src ? kft : qft;

  for (int idx = tid; idx < 2048; idx += 256) {
    int t = idx >> 1, f = idx & 1;
    size_t g4 = (((size_t)(b * L_ + t) * H_ + h) * E_ + e0 + f * 4) >> 2;
    float4 xv = reinterpret_cast<const float4*>(xg)[g4];
    xs[f * 4 + 0][t] = xv.x; xs[f * 4 + 1][t] = xv.y;
    xs[f * 4 + 2][t] = xv.z; xs[f * 4 + 3][t] = xv.w;
  }
  __syncthreads();

  const int m = tid & 63, eg = tid >> 6;
  const int ea = eg * 2, eb = eg * 2 + 1;
  const float TWO_PI = 6.283185307179586f;
  float c1, s1;
  sincosf(TWO_PI * (float)m * (1.0f / 1024.0f), &s1, &c1);
  float cm = 1.f, sm = 0.f;
  float r0 = 0.f, i0 = 0.f, r1 = 0.f, i1 = 0.f;
#pragma unroll 4
  for (int t = 0; t < 1024; ++t) {
    float xa = xs[ea][t], xb = xs[eb][t];
    r0 = fmaf(xa, cm, r0); i0 = fmaf(xa, sm, i0);
    r1 = fmaf(xb, cm, r1); i1 = fmaf(xb, sm, i1);
    float cn = fmaf(cm, c1, -sm * s1);
    float sn = fmaf(sm, c1, cm * s1);
    cm = cn; sm = sn;
  }
  float2 o0 = make_float2(r0, -i0);
  float2 o1 = make_float2(r1, -i1);
  reinterpret_cast<float2*>(oft)[(size_t)(bh * 64 + e0 + ea) * 64 + m] = o0;
  reinterpret_cast<float2*>(oft)[(size_t)(bh * 64 + e0 + eb) * 64 + m] = o1;
}

// ---------------------------------------------------------------------------
// Kernel 5a: xqk = ctanh(q_ft^T k_ft); xqkv = xqk @ k_ft^T.
// Grid: (bh, x-chunk of 8) = 256 blocks, 256 threads.
// Stores xqkv x-major: xre_g[bh*4096 + x*64 + e] (lane-coalesced).
// ---------------------------------------------------------------------------
__global__ __launch_bounds__(256) void k_spec12(const float* __restrict__ qft,
                                                 const float* __restrict__ kft,
                                                 float* __restrict__ xre_g,
                                                 float* __restrict__ xim_g) {
  __shared__ float kre[64][65], kim[64][65];
  __shared__ float qre[64][8], qim[64][8];
  __shared__ float tre[8][64], tim[8][64];
  const int xc = blockIdx.x & 7;
  const int bh = blockIdx.x >> 3;
  const int tid = threadIdx.x;

  for (int idx = tid; idx < 4096; idx += 256) {
    int e = idx >> 6, y = idx & 63;
    size_t o = ((size_t)(bh * 64 + e) * 64 + y) * 2;
    kre[e][y] = kft[o]; kim[e][y] = kft[o + 1];
  }
  for (int idx = tid; idx < 512; idx += 256) {
    int e = idx >> 3, xl = idx & 7;
    size_t o = ((size_t)(bh * 64 + e) * 64 + xc * 8 + xl) * 2;
    qre[e][xl] = qft[o]; qim[e][xl] = qft[o + 1];
  }
  __syncthreads();

  const int y = tid & 63, xg = tid >> 6;
  // xqk[x][y] = ctanh( sum_e conj-free complex dot )
#pragma unroll
  for (int xi = 0; xi < 2; ++xi) {
    int xl = xg + xi * 4;
    float ar = 0.f, ai = 0.f;
    for (int e = 0; e < 64; ++e) {
      float a = qre[e][xl], b = qim[e][xl];
      float c = kre[e][y], d = kim[e][y];
      ar = fmaf(a, c, fmaf(-b, d, ar));
      ai = fmaf(a, d, fmaf(b, c, ai));
    }
    float trv, tiv;
    float x2 = 2.f * ar, y2 = 2.f * ai;
    if (fabsf(x2) > 30.f) {
      trv = copysignf(1.f, ar); tiv = 0.f;
    } else {
      float sh = sinhf(x2), ch = coshf(x2);
      float sn = sinf(y2), cs = cosf(y2);
      float dd = ch + cs;
      trv = sh / dd; tiv = sn / dd;
    }
    tre[xl][y] = trv; tim[xl][y] = tiv;
  }
  __syncthreads();

  const int e2 = tid & 63, xg2 = tid >> 6;
  // xqkv[e][x] = sum_y xqk[x][y]*k[e][y]
#pragma unroll
  for (int xi = 0; xi < 2; ++xi) {
    int xl = xg2 + xi * 4;
    float ar = 0.f, ai = 0.f;
    for (int yy = 0; yy < 64; ++yy) {
      float a = tre[xl][yy], b = tim[xl][yy];
      float c = kre[e2][yy], d = kim[e2][yy];
      ar = fmaf(a, c, fmaf(-b, d, ar));
      ai = fmaf(a, d, fmaf(b, c, ai));
    }
    xre_g[(size_t)bh * 4096 + (xc * 8 + xl) * 64 + e2] = ar;
    xim_g[(size_t)bh * 4096 + (xc * 8 + xl) * 64 + e2] = ai;
  }
}

// ---------------------------------------------------------------------------
// Kernel 5b: xqkvw[o][x] = (sum_e xqkv[e][x]*w1[h,e,o,x]) / 512^2.
// xqkv planes are x-major: xre_g[bh*4096 + x*64 + e].
// ---------------------------------------------------------------------------
__global__ __launch_bounds__(256) void k_w1(const float* __restrict__ xre_g,
                                            const float* __restrict__ xim_g,
                                            const float* __restrict__ w1re,
                                            const float* __restrict__ w1im,
                                            float* __restrict__ xw) {
  __shared__ float xre[64][65], xim[64][65];
  __shared__ float redr[4][512], redi[4][512];
  const int oc = blockIdx.x & 7;
  const int bh = blockIdx.x >> 3;
  const int h = bh & 7;
  const int tid = threadIdx.x;

  for (int idx = tid; idx < 4096; idx += 256) {
    int x = idx >> 6, e = idx & 63;   // x-major global layout
    xre[e][x] = xre_g[(size_t)bh * 4096 + idx];
    xim[e][x] = xim_g[(size_t)bh * 4096 + idx];
  }
  __syncthreads();

  const int x = tid & 63, g = tid >> 6;
  float accr[8], acci[8];
#pragma unroll
  for (int oo = 0; oo < 8; ++oo) { accr[oo] = 0.f; acci[oo] = 0.f; }

  for (int ee = 0; ee < 16; ++ee) {
    int e = g * 16 + ee;
    float a = xre[e][x], b = xim[e][x];
    size_t wbase = (((size_t)h * 64 + e) * 64 + oc * 8) * 64 + x;
#pragma unroll
    for (int oo = 0; oo < 8; ++oo) {
      float c = w1re[wbase + (size_t)oo * 64];
      float d = w1im[wbase + (size_t)oo * 64];
      accr[oo] = fmaf(a, c, fmaf(-b, d, accr[oo]));
      acci[oo] = fmaf(a, d, fmaf(b, c, acci[oo]));
    }
  }
#pragma unroll
  for (int oo = 0; oo < 8; ++oo) {
    redr[g][oo * 64 + x] = accr[oo];
    redi[g][oo * 64 + x] = acci[oo];
  }
  __syncthreads();

  const float INV = 1.0f / (512.0f * 512.0f);
  for (int idx = tid; idx < 512; idx += 256) {
    int oo = idx >> 6, x2 = idx & 63;
    float r = redr[0][idx] + redr[1][idx] + redr[2][idx] + redr[3][idx];
    float i = redi[0][idx] + redi[1][idx] + redi[2][idx] + redi[3][idx];
    size_t oidx = ((size_t)(bh * 64 + oc * 8 + oo) * 64 + x2) * 2;
    xw[oidx] = r * INV;
    xw[oidx + 1] = i * INV;
  }
}

// ---------------------------------------------------------------------------
// Kernel 6: 64-mode irfft via per-thread rotation (no LDS tables, no bank
// conflicts), add 0.5*spec into d_out (which holds 0.5*attn).
// ---------------------------------------------------------------------------
__global__ __launch_bounds__(256) void k_final(const float* __restrict__ xw,
                                               float* __restrict__ out) {
  __shared__ float Xre[8][64], Xim[8][64];   // pre-scaled by 2
  const int oc = blockIdx.x & 7;
  const int bh = blockIdx.x >> 3;
  const int o0 = oc * 8;
  const int tid = threadIdx.x;

  for (int idx = tid; idx < 512; idx += 256) {
    int o = idx >> 6, m = idx & 63;
    size_t s = ((size_t)(bh * 64 + o0 + o) * 64 + m) * 2;
    Xre[o][m] = 2.f * xw[s]; Xim[o][m] = 2.f * xw[s + 1];
  }
  __syncthreads();

  const int ts = tid & 31, ol = tid >> 5;
  const float HALF_INVN = 0.5f / 1024.0f;
  const float TWO_PI = 6.283185307179586f;
  for (int k = 0; k < 32; ++k) {
    int t = ts + k * 32;
    float th = TWO_PI * (float)t * (1.0f / 1024.0f);
    float s1, c1;
    __sincosf(th, &s1, &c1);
    float cm = c1, sm = s1;
    float acc = 0.5f * Xre[ol][0];
#pragma unroll 9
    for (int m = 1; m < 64; ++m) {
      acc = fmaf(Xre[ol][m], cm, acc);
      acc = fmaf(-Xim[ol][m], sm, acc);
      float cn = fmaf(cm, c1, -sm * s1);
      float sn = fmaf(sm, c1, cm * s1);
      cm = cn; sm = sn;
    }
    size_t oi = ((size_t)(bh * 64 + o0 + ol)) * 1024 + t;
    out[oi] = fmaf(acc, HALF_INVN, out[oi]);
  }
}

// ---------------------------------------------------------------------------
extern "C" void kernel_launch(void* const* d_in, const int* in_sizes, int n_in,
                              void* d_out, int out_size, void* d_ws, size_t ws_size,
                              hipStream_t stream) {
  const float* tfq   = (const float*)d_in[0];
  const float* q     = (const float*)d_in[1];
  const float* k     = (const float*)d_in[2];
  const float* v     = (const float*)d_in[3];
  const float* wfuse = (const float*)d_in[5];
  const float* w1re  = (const float*)d_in[6];
  const float* w1im  = (const float*)d_in[7];
  float* out = (float*)d_out;
  float* ws  = (float*)d_ws;

  // ws layout (floats):
  //   amp2[262144]  (reused after k_topk as xqkv_re[131072] | xqkv_im[131072])
  //   sel(int)[4096] | qft[262144] | kft[262144] | xw[262144]
  float* amp2   = ws;
  float* xre_g  = ws;             // aliases amp2 (dead after k_topk)
  float* xim_g  = ws + 131072;
  int*   sel    = (int*)(ws + 262144);
  float* qft    = ws + 266240;
  float* kft    = ws + 528384;
  float* xw     = ws + 790528;

  k_corr<<<256, 512, 0, stream>>>(q, k, amp2);
  k_topk<<<64, 256, 0, stream>>>(amp2, tfq, sel);
  k_attn<<<512, 256, 0, stream>>>(q, tfq, k, v, wfuse, sel, out);
  k_dft<<<512, 256, 0, stream>>>(q, k, qft, kft);
  k_spec12<<<256, 256, 0, stream>>>(qft, kft, xre_g, xim_g);
  k_w1<<<256, 256, 0, stream>>>(xre_g, xim_g, w1re, w1im, xw);
  k_final<<<256, 256, 0, stream>>>(xw, out);
}

// Round 6
// 272.085 us; speedup vs baseline: 2.8808x; 1.1757x over previous
//
#include <hip/hip_runtime.h>
#include <math.h>

#define B_ 4
#define H_ 8
#define L_ 1024
#define E_ 64
#define NTOP 35
#define SCALE_ 0.04419417382415922f  /* 1/sqrt(512) */
#define SWZ(i) ((i) ^ (((i) >> 3) & 7))

// ---------------------------------------------------------------------------
// Kernel 1: partial circular cross-correlation amplitude^2.
// Grid: (bh, e-chunk of 4) = 512 blocks x 512 threads.
// Thread: eq = tid>>7 owns 1 e; ti = tid&127 owns 8 CONSECUTIVE taus
// (tau = 8*ti..8*ti+7) via a 3-float4 rotating window -> 32 FMA per 16B
// LDS read. Slot swizzle SWZ keeps lane-stride-2 reads bank-uniform.
// amp2_part[(bh*16+chunk)*1024 + tau] = sum_{e in chunk} corr_e(tau)^2
// ---------------------------------------------------------------------------
__global__ __launch_bounds__(512) void k_corr(const float* __restrict__ q_g,
                                              const float* __restrict__ k_g,
                                              float* __restrict__ amp2_part) {
  __shared__ __align__(16) float4 q_s4[4][256];
  __shared__ __align__(16) float4 k_s4[4][256];
  __shared__ float red[3][128][9];
  const int chunk = blockIdx.x & 15;
  const int bh = blockIdx.x >> 4;
  const int b = bh >> 3, h = bh & 7;
  const int e0 = chunk * 4;
  const int tid = threadIdx.x;

  float* q_sf = reinterpret_cast<float*>(q_s4);
  float* k_sf = reinterpret_cast<float*>(k_s4);
  // one float4 per t covers the block's 4 e's; swizzled scalar writes (2-way)
  for (int t = tid; t < 1024; t += 512) {
    size_t g4 = ((size_t)(b * L_ + t) * H_ + h) * 16 + chunk;
    float4 qv = reinterpret_cast<const float4*>(q_g)[g4];
    float4 kv = reinterpret_cast<const float4*>(k_g)[g4];
    int sa = SWZ(t >> 2) * 4 + (t & 3);
    q_sf[0 * 1024 + sa] = qv.x; q_sf[1 * 1024 + sa] = qv.y;
    q_sf[2 * 1024 + sa] = qv.z; q_sf[3 * 1024 + sa] = qv.w;
    k_sf[0 * 1024 + sa] = kv.x; k_sf[1 * 1024 + sa] = kv.y;
    k_sf[2 * 1024 + sa] = kv.z; k_sf[3 * 1024 + sa] = kv.w;
  }
  __syncthreads();

  const int eq = tid >> 7;      // e row (one per quarter)
  const int ti = tid & 127;     // tau block: tau = 8*ti .. 8*ti+7
  const float4* q4 = &q_s4[eq][0];
  const float4* k4 = &k_s4[eq][0];

  float c0 = 0.f, c1 = 0.f, c2 = 0.f, c3 = 0.f;
  float c4 = 0.f, c5 = 0.f, c6 = 0.f, c7 = 0.f;
  float4 w0 = q4[SWZ(2 * ti)];
  float4 w1 = q4[SWZ((2 * ti + 1) & 255)];
#pragma unroll 8
  for (int t4 = 0; t4 < 256; ++t4) {
    float4 w2 = q4[SWZ((2 * ti + t4 + 2) & 255)];
    float4 kv = k4[SWZ(t4)];
    c0 = fmaf(w0.x, kv.x, c0); c0 = fmaf(w0.y, kv.y, c0); c0 = fmaf(w0.z, kv.z, c0); c0 = fmaf(w0.w, kv.w, c0);
    c1 = fmaf(w0.y, kv.x, c1); c1 = fmaf(w0.z, kv.y, c1); c1 = fmaf(w0.w, kv.z, c1); c1 = fmaf(w1.x, kv.w, c1);
    c2 = fmaf(w0.z, kv.x, c2); c2 = fmaf(w0.w, kv.y, c2); c2 = fmaf(w1.x, kv.z, c2); c2 = fmaf(w1.y, kv.w, c2);
    c3 = fmaf(w0.w, kv.x, c3); c3 = fmaf(w1.x, kv.y, c3); c3 = fmaf(w1.y, kv.z, c3); c3 = fmaf(w1.z, kv.w, c3);
    c4 = fmaf(w1.x, kv.x, c4); c4 = fmaf(w1.y, kv.y, c4); c4 = fmaf(w1.z, kv.z, c4); c4 = fmaf(w1.w, kv.w, c4);
    c5 = fmaf(w1.y, kv.x, c5); c5 = fmaf(w1.z, kv.y, c5); c5 = fmaf(w1.w, kv.z, c5); c5 = fmaf(w2.x, kv.w, c5);
    c6 = fmaf(w1.z, kv.x, c6); c6 = fmaf(w1.w, kv.y, c6); c6 = fmaf(w2.x, kv.z, c6); c6 = fmaf(w2.y, kv.w, c6);
    c7 = fmaf(w1.w, kv.x, c7); c7 = fmaf(w2.x, kv.y, c7); c7 = fmaf(w2.y, kv.z, c7); c7 = fmaf(w2.z, kv.w, c7);
    w0 = w1; w1 = w2;
  }
  float a0 = c0 * c0, a1 = c1 * c1, a2 = c2 * c2, a3 = c3 * c3;
  float a4 = c4 * c4, a5 = c5 * c5, a6 = c6 * c6, a7 = c7 * c7;

  if (eq > 0) {
    float* rr = red[eq - 1][ti];
    rr[0] = a0; rr[1] = a1; rr[2] = a2; rr[3] = a3;
    rr[4] = a4; rr[5] = a5; rr[6] = a6; rr[7] = a7;
  }
  __syncthreads();
  if (eq == 0) {
#pragma unroll
    for (int g = 0; g < 3; ++g) {
      const float* rr = red[g][ti];
      a0 += rr[0]; a1 += rr[1]; a2 += rr[2]; a3 += rr[3];
      a4 += rr[4]; a5 += rr[5]; a6 += rr[6]; a7 += rr[7];
    }
    float* dst = &amp2_part[(size_t)blockIdx.x * 1024 + ti * 8];
    reinterpret_cast<float4*>(dst)[0] = make_float4(a0, a1, a2, a3);
    reinterpret_cast<float4*>(dst)[1] = make_float4(a4, a5, a6, a7);
  }
}

// ---------------------------------------------------------------------------
// Kernel 2: top-35 selection per (b,h,src). Wave-shuffle argmax per round;
// only the owner thread rescans after removal. Lowest-index tie-break.
// ---------------------------------------------------------------------------
__global__ __launch_bounds__(256) void k_topk(const float* __restrict__ amp2_part,
                                              const float* __restrict__ tfq,
                                              int* __restrict__ sel_ws) {
  __shared__ float amp[1024];
  __shared__ float wv_s[4];
  __shared__ int wi_s[4];
  __shared__ int winner_s;
  const int src = blockIdx.x & 1;
  const int bh = blockIdx.x >> 1;
  const int b = bh >> 3, h = bh & 7;
  const int tid = threadIdx.x;

  if (src == 0) {
    for (int t = tid; t < 1024; t += 256) {
      float s = 0.f;
#pragma unroll
      for (int c = 0; c < 16; ++c) s += amp2_part[(size_t)(bh * 16 + c) * 1024 + t];
      amp[t] = s;
    }
  } else {
    for (int l = tid; l < 1024; l += 256) {
      const float4* p4 = reinterpret_cast<const float4*>(
          &tfq[((size_t)(b * L_ + l) * H_ + h) * E_]);
      float s = 0.f;
#pragma unroll
      for (int e4 = 0; e4 < 16; ++e4) {
        float4 v = p4[e4];
        s += v.x * v.x + v.y * v.y + v.z * v.z + v.w * v.w;
      }
      amp[l] = s;
    }
  }
  __syncthreads();

  // local max over the 4 owned slots (t = tid + 256k), ascending scan
  float bv = -1.f; int bi = tid;
#pragma unroll
  for (int kk = 0; kk < 4; ++kk) {
    int t = tid + kk * 256;
    float v = amp[t];
    if (v > bv) { bv = v; bi = t; }
  }
  const int lane = tid & 63, w = tid >> 6;

  for (int it = 0; it < NTOP; ++it) {
    float v = bv; int i = bi;
#pragma unroll
    for (int d = 1; d < 64; d <<= 1) {
      float ov = __shfl_xor(v, d);
      int oi = __shfl_xor(i, d);
      if (ov > v || (ov == v && oi < i)) { v = ov; i = oi; }
    }
    if (lane == 0) { wv_s[w] = v; wi_s[w] = i; }
    __syncthreads();
    if (tid == 0) {
      float fv = wv_s[0]; int fi = wi_s[0];
#pragma unroll
      for (int j = 1; j < 4; ++j) {
        if (wv_s[j] > fv || (wv_s[j] == fv && wi_s[j] < fi)) { fv = wv_s[j]; fi = wi_s[j]; }
      }
      winner_s = fi;
      sel_ws[(bh * 2 + src) * 64 + it] = fi;
    }
    __syncthreads();
    int fi = winner_s;
    if ((fi & 255) == tid) {
      amp[fi] = -1.f;
      bv = -1.f; bi = tid;
#pragma unroll
      for (int kk = 0; kk < 4; ++kk) {
        int t = tid + kk * 256;
        float vv = amp[t];
        if (vv > bv) { bv = vv; bi = t; }
      }
    }
  }
}

// ---------------------------------------------------------------------------
// Kernel 3: scores over selected rows -> two softmaxes -> fuse -> times V.
// Grid: (bh, a-chunk of 64) = 512 blocks x 256 threads.
// Thread = (row r = tid>>2, quarter qd = tid&3): qd splits the e-sum for
// scores (shfl_xor combine within wave) and the d-range for the output.
// Writes 0.5*attn directly into d_out at [(bh*64+d)*1024 + a].
// ---------------------------------------------------------------------------
__global__ __launch_bounds__(256) void k_attn(const float* __restrict__ q_g,
                                              const float* __restrict__ tfq,
                                              const float* __restrict__ k_g,
                                              const float* __restrict__ v_g,
                                              const float* __restrict__ wfuse,
                                              const int* __restrict__ sel_ws,
                                              float* __restrict__ out) {
  __shared__ float qselt[NTOP][64];
  __shared__ float qseltf[NTOP][64];
  __shared__ float vselt[NTOP][64];
  __shared__ float vseltf[NTOP][64];
  __shared__ float ks[64][65];
  const int ac = blockIdx.x & 15;
  const int bh = blockIdx.x >> 4;
  const int b = bh >> 3, h = bh & 7;
  const int a0 = ac * 64;
  const int tid = threadIdx.x;

  for (int idx = tid; idx < NTOP * 64; idx += 256) {
    int i = idx >> 6, e = idx & 63;
    int st = sel_ws[(bh * 2 + 0) * 64 + i];
    int sf = sel_ws[(bh * 2 + 1) * 64 + i];
    qselt[i][e]  = q_g[((size_t)(b * L_ + st) * H_ + h) * E_ + e];
    qseltf[i][e] = tfq[((size_t)(b * L_ + sf) * H_ + h) * E_ + e];
    vselt[i][e]  = v_g[((size_t)(b * L_ + st) * H_ + h) * E_ + e];
    vseltf[i][e] = v_g[((size_t)(b * L_ + sf) * H_ + h) * E_ + e];
  }
  for (int idx = tid; idx < 64 * 64; idx += 256) {
    int r = idx >> 6, e = idx & 63;
    ks[r][e] = k_g[((size_t)(b * L_ + a0 + r) * H_ + h) * E_ + e];
  }
  __syncthreads();

  const int qd = tid & 3, r = tid >> 2;
  const int a = a0 + r;
  const int eb = qd * 16;

  float ct[NTOP], ctf[NTOP];
#pragma unroll
  for (int i = 0; i < NTOP; ++i) { ct[i] = 0.f; ctf[i] = 0.f; }
  // partial scores over this quarter's 16 e's
  for (int j = 0; j < 16; ++j) {
    float kv = ks[r][eb + j];
#pragma unroll
    for (int i = 0; i < NTOP; ++i) {
      ct[i]  = fmaf(qselt[i][eb + j], kv, ct[i]);
      ctf[i] = fmaf(qseltf[i][eb + j], kv, ctf[i]);
    }
  }
  // combine quarters (lanes 4r..4r+3 are in the same wave)
#pragma unroll
  for (int i = 0; i < NTOP; ++i) {
    ct[i] += __shfl_xor(ct[i], 1);  ct[i] += __shfl_xor(ct[i], 2);
    ctf[i] += __shfl_xor(ctf[i], 1); ctf[i] += __shfl_xor(ctf[i], 2);
  }

  float wf0 = wfuse[(h * L_ + a) * 2 + 0];
  float wf1 = wfuse[(h * L_ + a) * 2 + 1];
  float wm = fmaxf(wf0, wf1);
  float ew0 = expf(wf0 - wm), ew1 = expf(wf1 - wm);
  float nw0 = ew0 / (ew0 + ew1), nw1 = ew1 / (ew0 + ew1);

  // softmaxes (replicated across the 4 lanes of the row)
  {
    float m = -1e30f;
#pragma unroll
    for (int i = 0; i < NTOP; ++i) { ct[i] *= SCALE_; m = fmaxf(m, ct[i]); }
    float sum = 0.f;
#pragma unroll
    for (int i = 0; i < NTOP; ++i) { ct[i] = expf(ct[i] - m); sum += ct[i]; }
    float c = 0.5f * nw0 / sum;
#pragma unroll
    for (int i = 0; i < NTOP; ++i) ct[i] *= c;
  }
  {
    float m = -1e30f;
#pragma unroll
    for (int i = 0; i < NTOP; ++i) { ctf[i] *= SCALE_; m = fmaxf(m, ctf[i]); }
    float sum = 0.f;
#pragma unroll
    for (int i = 0; i < NTOP; ++i) { ctf[i] = expf(ctf[i] - m); sum += ctf[i]; }
    float c = 0.5f * nw1 / sum;
#pragma unroll
    for (int i = 0; i < NTOP; ++i) ctf[i] *= c;
  }
  // output: this thread covers d = qd*16 .. qd*16+15 for its row
  for (int j = 0; j < 16; ++j) {
    int d = eb + j;
    float acc = 0.f;
#pragma unroll
    for (int i = 0; i < NTOP; ++i) acc = fmaf(ct[i], vselt[i][d], acc);
#pragma unroll
    for (int i = 0; i < NTOP; ++i) acc = fmaf(ctf[i], vseltf[i][d], acc);
    out[((size_t)(bh * 64 + d)) * 1024 + a] = acc;
  }
}

// ---------------------------------------------------------------------------
// Kernel 4: first 64 rfft modes via stride-4 rotation recurrence (chain /4,
// high ILP). Grid: (bh, src, e-chunk of 8) = 512 blocks. Thread: m = tid&63,
// 2 e's. LDS reads are wave-broadcast float4; stores coalesced float2.
// ---------------------------------------------------------------------------
__global__ __launch_bounds__(256) void k_dft(const float* __restrict__ q_g,
                                             const float* __restrict__ k_g,
                                             float* __restrict__ qft,
                                             float* __restrict__ kft) {
  __shared__ float xs[8][1024];
  const int src = blockIdx.x & 1;
  const int ec = (blockIdx.x >> 1) & 7;
  const int bh = blockIdx.x >> 4;
  const int b = bh >> 3, h = bh & 7;
  const int e0 = ec * 8;
  const int tid = threadIdx.x;
  const float* xg = src ? k_g : q_g;
  float* oft = src ? kft : qft;

  for (int idx = tid; idx < 2048; idx += 256) {
    int t = idx >> 1, f = idx & 1;
    size_t g4 = ((size_t)(b * L_ + t) * H_ + h) * 16 + ec * 2 + f;
    float4 xv = reinterpret_cast<const float4*>(xg)[g4];
    xs[f * 4 + 0][t] = xv.x; xs[f * 4 + 1][t] = xv.y;
    xs[f * 4 + 2][t] = xv.z; xs[f * 4 + 3][t] = xv.w;
  }
  __syncthreads();

  const int m = tid & 63, eg = tid >> 6;
  const float4* xa4 = reinterpret_cast<const float4*>(xs[eg * 2]);
  const float4* xb4 = reinterpret_cast<const float4*>(xs[eg * 2 + 1]);
  const float TWO_PI = 6.283185307179586f;
  float c1o, s1o;
  sincosf(TWO_PI * (float)m * (1.0f / 1024.0f), &s1o, &c1o);
  float c2o = c1o * c1o - s1o * s1o, s2o = 2.f * s1o * c1o;
  float c3o = c2o * c1o - s2o * s1o, s3o = s2o * c1o + c2o * s1o;
  float c4o = c2o * c2o - s2o * s2o, s4o = 2.f * s2o * c2o;

  float cm = 1.f, sm = 0.f;
  float r0 = 0.f, i0 = 0.f, r1 = 0.f, i1 = 0.f;
#pragma unroll 4
  for (int t4 = 0; t4 < 256; ++t4) {
    float4 xa = xa4[t4];
    float4 xb = xb4[t4];
    float ct1 = fmaf(cm, c1o, -sm * s1o), st1 = fmaf(sm, c1o, cm * s1o);
    float ct2 = fmaf(cm, c2o, -sm * s2o), st2 = fmaf(sm, c2o, cm * s2o);
    float ct3 = fmaf(cm, c3o, -sm * s3o), st3 = fmaf(sm, c3o, cm * s3o);
    r0 = fmaf(xa.x, cm, r0);  i0 = fmaf(xa.x, sm, i0);
    r0 = fmaf(xa.y, ct1, r0); i0 = fmaf(xa.y, st1, i0);
    r0 = fmaf(xa.z, ct2, r0); i0 = fmaf(xa.z, st2, i0);
    r0 = fmaf(xa.w, ct3, r0); i0 = fmaf(xa.w, st3, i0);
    r1 = fmaf(xb.x, cm, r1);  i1 = fmaf(xb.x, sm, i1);
    r1 = fmaf(xb.y, ct1, r1); i1 = fmaf(xb.y, st1, i1);
    r1 = fmaf(xb.z, ct2, r1); i1 = fmaf(xb.z, st2, i1);
    r1 = fmaf(xb.w, ct3, r1); i1 = fmaf(xb.w, st3, i1);
    float cn = fmaf(cm, c4o, -sm * s4o);
    float sn = fmaf(sm, c4o, cm * s4o);
    cm = cn; sm = sn;
  }
  float2 o0 = make_float2(r0, -i0);
  float2 o1 = make_float2(r1, -i1);
  reinterpret_cast<float2*>(oft)[(size_t)(bh * 64 + e0 + eg * 2) * 64 + m] = o0;
  reinterpret_cast<float2*>(oft)[(size_t)(bh * 64 + e0 + eg * 2 + 1) * 64 + m] = o1;
}

// ---------------------------------------------------------------------------
// Kernel 5a: xqk = ctanh(q_ft^T k_ft); xqkv = xqk @ k_ft^T.
// Grid: (bh, x-chunk of 8) = 256 blocks, 256 threads.
// Stores xqkv x-major: xre_g[bh*4096 + x*64 + e] (lane-coalesced).
// ---------------------------------------------------------------------------
__global__ __launch_bounds__(256) void k_spec12(const float* __restrict__ qft,
                                                 const float* __restrict__ kft,
                                                 float* __restrict__ xre_g,
                                                 float* __restrict__ xim_g) {
  __shared__ float kre[64][65], kim[64][65];
  __shared__ float qre[64][8], qim[64][8];
  __shared__ float tre[8][64], tim[8][64];
  const int xc = blockIdx.x & 7;
  const int bh = blockIdx.x >> 3;
  const int tid = threadIdx.x;

  for (int idx = tid; idx < 4096; idx += 256) {
    int e = idx >> 6, y = idx & 63;
    size_t o = ((size_t)(bh * 64 + e) * 64 + y) * 2;
    kre[e][y] = kft[o]; kim[e][y] = kft[o + 1];
  }
  for (int idx = tid; idx < 512; idx += 256) {
    int e = idx >> 3, xl = idx & 7;
    size_t o = ((size_t)(bh * 64 + e) * 64 + xc * 8 + xl) * 2;
    qre[e][xl] = qft[o]; qim[e][xl] = qft[o + 1];
  }
  __syncthreads();

  const int y = tid & 63, xg = tid >> 6;
  // xqk[x][y] = ctanh( sum_e conj-free complex dot )
#pragma unroll
  for (int xi = 0; xi < 2; ++xi) {
    int xl = xg + xi * 4;
    float ar = 0.f, ai = 0.f;
    for (int e = 0; e < 64; ++e) {
      float a = qre[e][xl], b = qim[e][xl];
      float c = kre[e][y], d = kim[e][y];
      ar = fmaf(a, c, fmaf(-b, d, ar));
      ai = fmaf(a, d, fmaf(b, c, ai));
    }
    float trv, tiv;
    float x2 = 2.f * ar, y2 = 2.f * ai;
    if (fabsf(x2) > 30.f) {
      trv = copysignf(1.f, ar); tiv = 0.f;
    } else {
      float sh = sinhf(x2), ch = coshf(x2);
      float sn = sinf(y2), cs = cosf(y2);
      float dd = ch + cs;
      trv = sh / dd; tiv = sn / dd;
    }
    tre[xl][y] = trv; tim[xl][y] = tiv;
  }
  __syncthreads();

  const int e2 = tid & 63, xg2 = tid >> 6;
  // xqkv[e][x] = sum_y xqk[x][y]*k[e][y]
#pragma unroll
  for (int xi = 0; xi < 2; ++xi) {
    int xl = xg2 + xi * 4;
    float ar = 0.f, ai = 0.f;
    for (int yy = 0; yy < 64; ++yy) {
      float a = tre[xl][yy], b = tim[xl][yy];
      float c = kre[e2][yy], d = kim[e2][yy];
      ar = fmaf(a, c, fmaf(-b, d, ar));
      ai = fmaf(a, d, fmaf(b, c, ai));
    }
    xre_g[(size_t)bh * 4096 + (xc * 8 + xl) * 64 + e2] = ar;
    xim_g[(size_t)bh * 4096 + (xc * 8 + xl) * 64 + e2] = ai;
  }
}

// ---------------------------------------------------------------------------
// Kernel 5b: xqkvw[o][x] = (sum_e xqkv[e][x]*w1[h,e,o,x]) / 512^2.
// xqkv planes are x-major: xre_g[bh*4096 + x*64 + e].
// ---------------------------------------------------------------------------
__global__ __launch_bounds__(256) void k_w1(const float* __restrict__ xre_g,
                                            const float* __restrict__ xim_g,
                                            const float* __restrict__ w1re,
                                            const float* __restrict__ w1im,
                                            float* __restrict__ xw) {
  __shared__ float xre[64][65], xim[64][65];
  __shared__ float redr[4][512], redi[4][512];
  const int oc = blockIdx.x & 7;
  const int bh = blockIdx.x >> 3;
  const int h = bh & 7;
  const int tid = threadIdx.x;

  for (int idx = tid; idx < 4096; idx += 256) {
    int x = idx >> 6, e = idx & 63;   // x-major global layout
    xre[e][x] = xre_g[(size_t)bh * 4096 + idx];
    xim[e][x] = xim_g[(size_t)bh * 4096 + idx];
  }
  __syncthreads();

  const int x = tid & 63, g = tid >> 6;
  float accr[8], acci[8];
#pragma unroll
  for (int oo = 0; oo < 8; ++oo) { accr[oo] = 0.f; acci[oo] = 0.f; }

  for (int ee = 0; ee < 16; ++ee) {
    int e = g * 16 + ee;
    float a = xre[e][x], b = xim[e][x];
    size_t wbase = (((size_t)h * 64 + e) * 64 + oc * 8) * 64 + x;
#pragma unroll
    for (int oo = 0; oo < 8; ++oo) {
      float c = w1re[wbase + (size_t)oo * 64];
      float d = w1im[wbase + (size_t)oo * 64];
      accr[oo] = fmaf(a, c, fmaf(-b, d, accr[oo]));
      acci[oo] = fmaf(a, d, fmaf(b, c, acci[oo]));
    }
  }
#pragma unroll
  for (int oo = 0; oo < 8; ++oo) {
    redr[g][oo * 64 + x] = accr[oo];
    redi[g][oo * 64 + x] = acci[oo];
  }
  __syncthreads();

  const float INV = 1.0f / (512.0f * 512.0f);
  for (int idx = tid; idx < 512; idx += 256) {
    int oo = idx >> 6, x2 = idx & 63;
    float r = redr[0][idx] + redr[1][idx] + redr[2][idx] + redr[3][idx];
    float i = redi[0][idx] + redi[1][idx] + redi[2][idx] + redi[3][idx];
    size_t oidx = ((size_t)(bh * 64 + oc * 8 + oo) * 64 + x2) * 2;
    xw[oidx] = r * INV;
    xw[oidx + 1] = i * INV;
  }
}

// ---------------------------------------------------------------------------
// Kernel 6: 64-mode irfft via per-thread rotation (no LDS tables, no bank
// conflicts), add 0.5*spec into d_out (which holds 0.5*attn).
// ---------------------------------------------------------------------------
__global__ __launch_bounds__(256) void k_final(const float* __restrict__ xw,
                                               float* __restrict__ out) {
  __shared__ float Xre[8][64], Xim[8][64];   // pre-scaled by 2
  const int oc = blockIdx.x & 7;
  const int bh = blockIdx.x >> 3;
  const int o0 = oc * 8;
  const int tid = threadIdx.x;

  for (int idx = tid; idx < 512; idx += 256) {
    int o = idx >> 6, m = idx & 63;
    size_t s = ((size_t)(bh * 64 + o0 + o) * 64 + m) * 2;
    Xre[o][m] = 2.f * xw[s]; Xim[o][m] = 2.f * xw[s + 1];
  }
  __syncthreads();

  const int ts = tid & 31, ol = tid >> 5;
  const float HALF_INVN = 0.5f / 1024.0f;
  const float TWO_PI = 6.283185307179586f;
  for (int k = 0; k < 32; ++k) {
    int t = ts + k * 32;
    float th = TWO_PI * (float)t * (1.0f / 1024.0f);
    float s1, c1;
    __sincosf(th, &s1, &c1);
    float cm = c1, sm = s1;
    float acc = 0.5f * Xre[ol][0];
#pragma unroll 9
    for (int m = 1; m < 64; ++m) {
      acc = fmaf(Xre[ol][m], cm, acc);
      acc = fmaf(-Xim[ol][m], sm, acc);
      float cn = fmaf(cm, c1, -sm * s1);
      float sn = fmaf(sm, c1, cm * s1);
      cm = cn; sm = sn;
    }
    size_t oi = ((size_t)(bh * 64 + o0 + ol)) * 1024 + t;
    out[oi] = fmaf(acc, HALF_INVN, out[oi]);
  }
}

// ---------------------------------------------------------------------------
extern "C" void kernel_launch(void* const* d_in, const int* in_sizes, int n_in,
                              void* d_out, int out_size, void* d_ws, size_t ws_size,
                              hipStream_t stream) {
  const float* tfq   = (const float*)d_in[0];
  const float* q     = (const float*)d_in[1];
  const float* k     = (const float*)d_in[2];
  const float* v     = (const float*)d_in[3];
  const float* wfuse = (const float*)d_in[5];
  const float* w1re  = (const float*)d_in[6];
  const float* w1im  = (const float*)d_in[7];
  float* out = (float*)d_out;
  float* ws  = (float*)d_ws;

  // ws layout (floats):
  //   xre_g[131072] | xim_g[131072] | sel(int)[4096] |
  //   amp2[524288] ALIASES qft[262144]|kft[262144] (amp2 dead after k_topk,
  //   which runs before k_dft in stream order) | xw[262144]
  float* xre_g  = ws;
  float* xim_g  = ws + 131072;
  int*   sel    = (int*)(ws + 262144);
  float* amp2   = ws + 266240;
  float* qft    = ws + 266240;
  float* kft    = ws + 528384;
  float* xw     = ws + 790528;

  k_corr<<<512, 512, 0, stream>>>(q, k, amp2);
  k_topk<<<64, 256, 0, stream>>>(amp2, tfq, sel);
  k_attn<<<512, 256, 0, stream>>>(q, tfq, k, v, wfuse, sel, out);
  k_dft<<<512, 256, 0, stream>>>(q, k, qft, kft);
  k_spec12<<<256, 256, 0, stream>>>(qft, kft, xre_g, xim_g);
  k_w1<<<256, 256, 0, stream>>>(xre_g, xim_g, w1re, w1im, xw);
  k_final<<<256, 256, 0, stream>>>(xw, out);
}

// Round 7
// 267.119 us; speedup vs baseline: 2.9344x; 1.0186x over previous
//
#include <hip/hip_runtime.h>
#include <math.h>

#define B_ 4
#define H_ 8
#define L_ 1024
#define E_ 64
#define NTOP 35
#define SCALE_ 0.04419417382415922f  /* 1/sqrt(512) */
// Involution swizzle: inject slot bit3 into bit0 so that lane-stride-2 b128
// reads hit 8 distinct bank-quads per 8-lane service group (conflict-free).
#define SWZ(i) ((i) ^ (((i) >> 3) & 1))

// ---------------------------------------------------------------------------
// Kernel 1: partial circular cross-correlation amplitude^2.
// Grid: (bh, e-chunk of 4, tau-half) = 1024 blocks x 256 threads.
// Wave eq owns 1 e; lane ti owns 8 CONSECUTIVE taus (tau = th*512 + ti*8)
// via a 3-float4 rotating window -> 32 FMA per 16B lane read.
// amp2_part[(bh*16+chunk)*1024 + tau] = sum_{e in chunk} corr_e(tau)^2
// ---------------------------------------------------------------------------
__global__ __launch_bounds__(256) void k_corr(const float* __restrict__ q_g,
                                              const float* __restrict__ k_g,
                                              float* __restrict__ amp2_part) {
  __shared__ __align__(16) float4 q_s4[4][256];
  __shared__ __align__(16) float4 k_s4[4][256];
  __shared__ float red[3][64][9];
  const int th = blockIdx.x & 1;          // tau half
  const int chunk = (blockIdx.x >> 1) & 15;
  const int bh = blockIdx.x >> 5;
  const int b = bh >> 3, h = bh & 7;
  const int tid = threadIdx.x;

  float* q_sf = reinterpret_cast<float*>(q_s4);
  float* k_sf = reinterpret_cast<float*>(k_s4);
  // one float4 per t covers the block's 4 e's; swizzled scalar writes (<=2-way)
  for (int t = tid; t < 1024; t += 256) {
    size_t g4 = ((size_t)(b * L_ + t) * H_ + h) * 16 + chunk;
    float4 qv = reinterpret_cast<const float4*>(q_g)[g4];
    float4 kv = reinterpret_cast<const float4*>(k_g)[g4];
    int sa = SWZ(t >> 2) * 4 + (t & 3);
    q_sf[0 * 1024 + sa] = qv.x; q_sf[1 * 1024 + sa] = qv.y;
    q_sf[2 * 1024 + sa] = qv.z; q_sf[3 * 1024 + sa] = qv.w;
    k_sf[0 * 1024 + sa] = kv.x; k_sf[1 * 1024 + sa] = kv.y;
    k_sf[2 * 1024 + sa] = kv.z; k_sf[3 * 1024 + sa] = kv.w;
  }
  __syncthreads();

  const int eq = tid >> 6;      // e row = wave index
  const int ti = tid & 63;      // tau block: tau = th*512 + 8*ti .. +7
  const int base4 = th * 128 + 2 * ti;
  const float4* q4 = &q_s4[eq][0];
  const float4* k4 = &k_s4[eq][0];

  float c0 = 0.f, c1 = 0.f, c2 = 0.f, c3 = 0.f;
  float c4 = 0.f, c5 = 0.f, c6 = 0.f, c7 = 0.f;
  float4 w0 = q4[SWZ(base4 & 255)];
  float4 w1 = q4[SWZ((base4 + 1) & 255)];
#pragma unroll 8
  for (int t4 = 0; t4 < 256; ++t4) {
    float4 w2 = q4[SWZ((base4 + t4 + 2) & 255)];
    float4 kv = k4[SWZ(t4)];
    c0 = fmaf(w0.x, kv.x, c0); c0 = fmaf(w0.y, kv.y, c0); c0 = fmaf(w0.z, kv.z, c0); c0 = fmaf(w0.w, kv.w, c0);
    c1 = fmaf(w0.y, kv.x, c1); c1 = fmaf(w0.z, kv.y, c1); c1 = fmaf(w0.w, kv.z, c1); c1 = fmaf(w1.x, kv.w, c1);
    c2 = fmaf(w0.z, kv.x, c2); c2 = fmaf(w0.w, kv.y, c2); c2 = fmaf(w1.x, kv.z, c2); c2 = fmaf(w1.y, kv.w, c2);
    c3 = fmaf(w0.w, kv.x, c3); c3 = fmaf(w1.x, kv.y, c3); c3 = fmaf(w1.y, kv.z, c3); c3 = fmaf(w1.z, kv.w, c3);
    c4 = fmaf(w1.x, kv.x, c4); c4 = fmaf(w1.y, kv.y, c4); c4 = fmaf(w1.z, kv.z, c4); c4 = fmaf(w1.w, kv.w, c4);
    c5 = fmaf(w1.y, kv.x, c5); c5 = fmaf(w1.z, kv.y, c5); c5 = fmaf(w1.w, kv.z, c5); c5 = fmaf(w2.x, kv.w, c5);
    c6 = fmaf(w1.z, kv.x, c6); c6 = fmaf(w1.w, kv.y, c6); c6 = fmaf(w2.x, kv.z, c6); c6 = fmaf(w2.y, kv.w, c6);
    c7 = fmaf(w1.w, kv.x, c7); c7 = fmaf(w2.x, kv.y, c7); c7 = fmaf(w2.y, kv.z, c7); c7 = fmaf(w2.z, kv.w, c7);
    w0 = w1; w1 = w2;
  }
  float a0 = c0 * c0, a1 = c1 * c1, a2 = c2 * c2, a3 = c3 * c3;
  float a4 = c4 * c4, a5 = c5 * c5, a6 = c6 * c6, a7 = c7 * c7;

  if (eq > 0) {
    float* rr = red[eq - 1][ti];
    rr[0] = a0; rr[1] = a1; rr[2] = a2; rr[3] = a3;
    rr[4] = a4; rr[5] = a5; rr[6] = a6; rr[7] = a7;
  }
  __syncthreads();
  if (eq == 0) {
#pragma unroll
    for (int g = 0; g < 3; ++g) {
      const float* rr = red[g][ti];
      a0 += rr[0]; a1 += rr[1]; a2 += rr[2]; a3 += rr[3];
      a4 += rr[4]; a5 += rr[5]; a6 += rr[6]; a7 += rr[7];
    }
    float* dst = &amp2_part[(size_t)(bh * 16 + chunk) * 1024 + th * 512 + ti * 8];
    reinterpret_cast<float4*>(dst)[0] = make_float4(a0, a1, a2, a3);
    reinterpret_cast<float4*>(dst)[1] = make_float4(a4, a5, a6, a7);
  }
}

// ---------------------------------------------------------------------------
// Kernel 2: top-35 selection per (b,h,src). Wave-shuffle argmax per round;
// only the owner thread rescans after removal. Lowest-index tie-break.
// ---------------------------------------------------------------------------
__global__ __launch_bounds__(256) void k_topk(const float* __restrict__ amp2_part,
                                              const float* __restrict__ tfq,
                                              int* __restrict__ sel_ws) {
  __shared__ float amp[1024];
  __shared__ float wv_s[4];
  __shared__ int wi_s[4];
  __shared__ int winner_s;
  const int src = blockIdx.x & 1;
  const int bh = blockIdx.x >> 1;
  const int b = bh >> 3, h = bh & 7;
  const int tid = threadIdx.x;

  if (src == 0) {
    for (int t = tid; t < 1024; t += 256) {
      float s = 0.f;
#pragma unroll
      for (int c = 0; c < 16; ++c) s += amp2_part[(size_t)(bh * 16 + c) * 1024 + t];
      amp[t] = s;
    }
  } else {
    for (int l = tid; l < 1024; l += 256) {
      const float4* p4 = reinterpret_cast<const float4*>(
          &tfq[((size_t)(b * L_ + l) * H_ + h) * E_]);
      float s = 0.f;
#pragma unroll
      for (int e4 = 0; e4 < 16; ++e4) {
        float4 v = p4[e4];
        s += v.x * v.x + v.y * v.y + v.z * v.z + v.w * v.w;
      }
      amp[l] = s;
    }
  }
  __syncthreads();

  // local max over the 4 owned slots (t = tid + 256k), ascending scan
  float bv = -1.f; int bi = tid;
#pragma unroll
  for (int kk = 0; kk < 4; ++kk) {
    int t = tid + kk * 256;
    float v = amp[t];
    if (v > bv) { bv = v; bi = t; }
  }
  const int lane = tid & 63, w = tid >> 6;

  for (int it = 0; it < NTOP; ++it) {
    float v = bv; int i = bi;
#pragma unroll
    for (int d = 1; d < 64; d <<= 1) {
      float ov = __shfl_xor(v, d);
      int oi = __shfl_xor(i, d);
      if (ov > v || (ov == v && oi < i)) { v = ov; i = oi; }
    }
    if (lane == 0) { wv_s[w] = v; wi_s[w] = i; }
    __syncthreads();
    if (tid == 0) {
      float fv = wv_s[0]; int fi = wi_s[0];
#pragma unroll
      for (int j = 1; j < 4; ++j) {
        if (wv_s[j] > fv || (wv_s[j] == fv && wi_s[j] < fi)) { fv = wv_s[j]; fi = wi_s[j]; }
      }
      winner_s = fi;
      sel_ws[(bh * 2 + src) * 64 + it] = fi;
    }
    __syncthreads();
    int fi = winner_s;
    if ((fi & 255) == tid) {
      amp[fi] = -1.f;
      bv = -1.f; bi = tid;
#pragma unroll
      for (int kk = 0; kk < 4; ++kk) {
        int t = tid + kk * 256;
        float vv = amp[t];
        if (vv > bv) { bv = vv; bi = t; }
      }
    }
  }
}

// ---------------------------------------------------------------------------
// Kernel 3: scores over selected rows -> two softmaxes -> fuse -> times V.
// Grid: (bh, a-chunk of 64) = 512 blocks x 256 threads.
// Thread = (row r = tid>>2, quarter qd = tid&3): qd splits the e-sum for
// scores (shfl_xor combine within wave) and the d-range for the output.
// Writes 0.5*attn directly into d_out at [(bh*64+d)*1024 + a].
// ---------------------------------------------------------------------------
__global__ __launch_bounds__(256) void k_attn(const float* __restrict__ q_g,
                                              const float* __restrict__ tfq,
                                              const float* __restrict__ k_g,
                                              const float* __restrict__ v_g,
                                              const float* __restrict__ wfuse,
                                              const int* __restrict__ sel_ws,
                                              float* __restrict__ out) {
  __shared__ float qselt[NTOP][64];
  __shared__ float qseltf[NTOP][64];
  __shared__ float vselt[NTOP][64];
  __shared__ float vseltf[NTOP][64];
  __shared__ float ks[64][65];
  const int ac = blockIdx.x & 15;
  const int bh = blockIdx.x >> 4;
  const int b = bh >> 3, h = bh & 7;
  const int a0 = ac * 64;
  const int tid = threadIdx.x;

  for (int idx = tid; idx < NTOP * 64; idx += 256) {
    int i = idx >> 6, e = idx & 63;
    int st = sel_ws[(bh * 2 + 0) * 64 + i];
    int sf = sel_ws[(bh * 2 + 1) * 64 + i];
    qselt[i][e]  = q_g[((size_t)(b * L_ + st) * H_ + h) * E_ + e];
    qseltf[i][e] = tfq[((size_t)(b * L_ + sf) * H_ + h) * E_ + e];
    vselt[i][e]  = v_g[((size_t)(b * L_ + st) * H_ + h) * E_ + e];
    vseltf[i][e] = v_g[((size_t)(b * L_ + sf) * H_ + h) * E_ + e];
  }
  for (int idx = tid; idx < 64 * 64; idx += 256) {
    int r = idx >> 6, e = idx & 63;
    ks[r][e] = k_g[((size_t)(b * L_ + a0 + r) * H_ + h) * E_ + e];
  }
  __syncthreads();

  const int qd = tid & 3, r = tid >> 2;
  const int a = a0 + r;
  const int eb = qd * 16;

  float ct[NTOP], ctf[NTOP];
#pragma unroll
  for (int i = 0; i < NTOP; ++i) { ct[i] = 0.f; ctf[i] = 0.f; }
  // partial scores over this quarter's 16 e's
  for (int j = 0; j < 16; ++j) {
    float kv = ks[r][eb + j];
#pragma unroll
    for (int i = 0; i < NTOP; ++i) {
      ct[i]  = fmaf(qselt[i][eb + j], kv, ct[i]);
      ctf[i] = fmaf(qseltf[i][eb + j], kv, ctf[i]);
    }
  }
  // combine quarters (lanes 4r..4r+3 are in the same wave)
#pragma unroll
  for (int i = 0; i < NTOP; ++i) {
    ct[i] += __shfl_xor(ct[i], 1);  ct[i] += __shfl_xor(ct[i], 2);
    ctf[i] += __shfl_xor(ctf[i], 1); ctf[i] += __shfl_xor(ctf[i], 2);
  }

  float wf0 = wfuse[(h * L_ + a) * 2 + 0];
  float wf1 = wfuse[(h * L_ + a) * 2 + 1];
  float wm = fmaxf(wf0, wf1);
  float ew0 = expf(wf0 - wm), ew1 = expf(wf1 - wm);
  float nw0 = ew0 / (ew0 + ew1), nw1 = ew1 / (ew0 + ew1);

  // softmaxes (replicated across the 4 lanes of the row)
  {
    float m = -1e30f;
#pragma unroll
    for (int i = 0; i < NTOP; ++i) { ct[i] *= SCALE_; m = fmaxf(m, ct[i]); }
    float sum = 0.f;
#pragma unroll
    for (int i = 0; i < NTOP; ++i) { ct[i] = expf(ct[i] - m); sum += ct[i]; }
    float c = 0.5f * nw0 / sum;
#pragma unroll
    for (int i = 0; i < NTOP; ++i) ct[i] *= c;
  }
  {
    float m = -1e30f;
#pragma unroll
    for (int i = 0; i < NTOP; ++i) { ctf[i] *= SCALE_; m = fmaxf(m, ctf[i]); }
    float sum = 0.f;
#pragma unroll
    for (int i = 0; i < NTOP; ++i) { ctf[i] = expf(ctf[i] - m); sum += ctf[i]; }
    float c = 0.5f * nw1 / sum;
#pragma unroll
    for (int i = 0; i < NTOP; ++i) ctf[i] *= c;
  }
  // output: this thread covers d = qd*16 .. qd*16+15 for its row
  for (int j = 0; j < 16; ++j) {
    int d = eb + j;
    float acc = 0.f;
#pragma unroll
    for (int i = 0; i < NTOP; ++i) acc = fmaf(ct[i], vselt[i][d], acc);
#pragma unroll
    for (int i = 0; i < NTOP; ++i) acc = fmaf(ctf[i], vseltf[i][d], acc);
    out[((size_t)(bh * 64 + d)) * 1024 + a] = acc;
  }
}

// ---------------------------------------------------------------------------
// Kernel 4: first 64 rfft modes via stride-4 rotation recurrence (chain /4,
// high ILP). Grid: (bh, src, e-chunk of 8) = 512 blocks. Thread: m = tid&63,
// 2 e's. LDS reads are wave-broadcast float4; stores coalesced float2.
// ---------------------------------------------------------------------------
__global__ __launch_bounds__(256) void k_dft(const float* __restrict__ q_g,
                                             const float* __restrict__ k_g,
                                             float* __restrict__ qft,
                                             float* __restrict__ kft) {
  __shared__ float xs[8][1024];
  const int src = blockIdx.x & 1;
  const int ec = (blockIdx.x >> 1) & 7;
  const int bh = blockIdx.x >> 4;
  const int b = bh >> 3, h = bh & 7;
  const int e0 = ec * 8;
  const int tid = threadIdx.x;
  const float* xg = src ? k_g : q_g;
  float* oft = src ? kft : qft;

  for (int idx = tid; idx < 2048; idx += 256) {
    int t = idx >> 1, f = idx & 1;
    size_t g4 = ((size_t)(b * L_ + t) * H_ + h) * 16 + ec * 2 + f;
    float4 xv = reinterpret_cast<const float4*>(xg)[g4];
    xs[f * 4 + 0][t] = xv.x; xs[f * 4 + 1][t] = xv.y;
    xs[f * 4 + 2][t] = xv.z; xs[f * 4 + 3][t] = xv.w;
  }
  __syncthreads();

  const int m = tid & 63, eg = tid >> 6;
  const float4* xa4 = reinterpret_cast<const float4*>(xs[eg * 2]);
  const float4* xb4 = reinterpret_cast<const float4*>(xs[eg * 2 + 1]);
  const float TWO_PI = 6.283185307179586f;
  float c1o, s1o;
  sincosf(TWO_PI * (float)m * (1.0f / 1024.0f), &s1o, &c1o);
  float c2o = c1o * c1o - s1o * s1o, s2o = 2.f * s1o * c1o;
  float c3o = c2o * c1o - s2o * s1o, s3o = s2o * c1o + c2o * s1o;
  float c4o = c2o * c2o - s2o * s2o, s4o = 2.f * s2o * c2o;

  float cm = 1.f, sm = 0.f;
  float r0 = 0.f, i0 = 0.f, r1 = 0.f, i1 = 0.f;
#pragma unroll 4
  for (int t4 = 0; t4 < 256; ++t4) {
    float4 xa = xa4[t4];
    float4 xb = xb4[t4];
    float ct1 = fmaf(cm, c1o, -sm * s1o), st1 = fmaf(sm, c1o, cm * s1o);
    float ct2 = fmaf(cm, c2o, -sm * s2o), st2 = fmaf(sm, c2o, cm * s2o);
    float ct3 = fmaf(cm, c3o, -sm * s3o), st3 = fmaf(sm, c3o, cm * s3o);
    r0 = fmaf(xa.x, cm, r0);  i0 = fmaf(xa.x, sm, i0);
    r0 = fmaf(xa.y, ct1, r0); i0 = fmaf(xa.y, st1, i0);
    r0 = fmaf(xa.z, ct2, r0); i0 = fmaf(xa.z, st2, i0);
    r0 = fmaf(xa.w, ct3, r0); i0 = fmaf(xa.w, st3, i0);
    r1 = fmaf(xb.x, cm, r1);  i1 = fmaf(xb.x, sm, i1);
    r1 = fmaf(xb.y, ct1, r1); i1 = fmaf(xb.y, st1, i1);
    r1 = fmaf(xb.z, ct2, r1); i1 = fmaf(xb.z, st2, i1);
    r1 = fmaf(xb.w, ct3, r1); i1 = fmaf(xb.w, st3, i1);
    float cn = fmaf(cm, c4o, -sm * s4o);
    float sn = fmaf(sm, c4o, cm * s4o);
    cm = cn; sm = sn;
  }
  float2 o0 = make_float2(r0, -i0);
  float2 o1 = make_float2(r1, -i1);
  reinterpret_cast<float2*>(oft)[(size_t)(bh * 64 + e0 + eg * 2) * 64 + m] = o0;
  reinterpret_cast<float2*>(oft)[(size_t)(bh * 64 + e0 + eg * 2 + 1) * 64 + m] = o1;
}

// ---------------------------------------------------------------------------
// Kernel 5a: xqk = ctanh(q_ft^T k_ft); xqkv = xqk @ k_ft^T.
// Grid: (bh, x-chunk of 8) = 256 blocks, 256 threads.
// Stores xqkv x-major: xre_g[bh*4096 + x*64 + e] (lane-coalesced).
// ---------------------------------------------------------------------------
__global__ __launch_bounds__(256) void k_spec12(const float* __restrict__ qft,
                                                 const float* __restrict__ kft,
                                                 float* __restrict__ xre_g,
                                                 float* __restrict__ xim_g) {
  __shared__ float kre[64][65], kim[64][65];
  __shared__ float qre[64][8], qim[64][8];
  __shared__ float tre[8][64], tim[8][64];
  const int xc = blockIdx.x & 7;
  const int bh = blockIdx.x >> 3;
  const int tid = threadIdx.x;

  for (int idx = tid; idx < 4096; idx += 256) {
    int e = idx >> 6, y = idx & 63;
    size_t o = ((size_t)(bh * 64 + e) * 64 + y) * 2;
    kre[e][y] = kft[o]; kim[e][y] = kft[o + 1];
  }
  for (int idx = tid; idx < 512; idx += 256) {
    int e = idx >> 3, xl = idx & 7;
    size_t o = ((size_t)(bh * 64 + e) * 64 + xc * 8 + xl) * 2;
    qre[e][xl] = qft[o]; qim[e][xl] = qft[o + 1];
  }
  __syncthreads();

  const int y = tid & 63, xg = tid >> 6;
  // xqk[x][y] = ctanh( sum_e conj-free complex dot )
#pragma unroll
  for (int xi = 0; xi < 2; ++xi) {
    int xl = xg + xi * 4;
    float ar = 0.f, ai = 0.f;
    for (int e = 0; e < 64; ++e) {
      float a = qre[e][xl], b = qim[e][xl];
      float c = kre[e][y], d = kim[e][y];
      ar = fmaf(a, c, fmaf(-b, d, ar));
      ai = fmaf(a, d, fmaf(b, c, ai));
    }
    float trv, tiv;
    float x2 = 2.f * ar, y2 = 2.f * ai;
    if (fabsf(x2) > 30.f) {
      trv = copysignf(1.f, ar); tiv = 0.f;
    } else {
      float sh = sinhf(x2), ch = coshf(x2);
      float sn = sinf(y2), cs = cosf(y2);
      float dd = ch + cs;
      trv = sh / dd; tiv = sn / dd;
    }
    tre[xl][y] = trv; tim[xl][y] = tiv;
  }
  __syncthreads();

  const int e2 = tid & 63, xg2 = tid >> 6;
  // xqkv[e][x] = sum_y xqk[x][y]*k[e][y]
#pragma unroll
  for (int xi = 0; xi < 2; ++xi) {
    int xl = xg2 + xi * 4;
    float ar = 0.f, ai = 0.f;
    for (int yy = 0; yy < 64; ++yy) {
      float a = tre[xl][yy], b = tim[xl][yy];
      float c = kre[e2][yy], d = kim[e2][yy];
      ar = fmaf(a, c, fmaf(-b, d, ar));
      ai = fmaf(a, d, fmaf(b, c, ai));
    }
    xre_g[(size_t)bh * 4096 + (xc * 8 + xl) * 64 + e2] = ar;
    xim_g[(size_t)bh * 4096 + (xc * 8 + xl) * 64 + e2] = ai;
  }
}

// ---------------------------------------------------------------------------
// Kernel 5b: xqkvw[o][x] = (sum_e xqkv[e][x]*w1[h,e,o,x]) / 512^2.
// xqkv planes are x-major: xre_g[bh*4096 + x*64 + e].
// ---------------------------------------------------------------------------
__global__ __launch_bounds__(256) void k_w1(const float* __restrict__ xre_g,
                                            const float* __restrict__ xim_g,
                                            const float* __restrict__ w1re,
                                            const float* __restrict__ w1im,
                                            float* __restrict__ xw) {
  __shared__ float xre[64][65], xim[64][65];
  __shared__ float redr[4][512], redi[4][512];
  const int oc = blockIdx.x & 7;
  const int bh = blockIdx.x >> 3;
  const int h = bh & 7;
  const int tid = threadIdx.x;

  for (int idx = tid; idx < 4096; idx += 256) {
    int x = idx >> 6, e = idx & 63;   // x-major global layout
    xre[e][x] = xre_g[(size_t)bh * 4096 + idx];
    xim[e][x] = xim_g[(size_t)bh * 4096 + idx];
  }
  __syncthreads();

  const int x = tid & 63, g = tid >> 6;
  float accr[8], acci[8];
#pragma unroll
  for (int oo = 0; oo < 8; ++oo) { accr[oo] = 0.f; acci[oo] = 0.f; }

  for (int ee = 0; ee < 16; ++ee) {
    int e = g * 16 + ee;
    float a = xre[e][x], b = xim[e][x];
    size_t wbase = (((size_t)h * 64 + e) * 64 + oc * 8) * 64 + x;
#pragma unroll
    for (int oo = 0; oo < 8; ++oo) {
      float c = w1re[wbase + (size_t)oo * 64];
      float d = w1im[wbase + (size_t)oo * 64];
      accr[oo] = fmaf(a, c, fmaf(-b, d, accr[oo]));
      acci[oo] = fmaf(a, d, fmaf(b, c, acci[oo]));
    }
  }
#pragma unroll
  for (int oo = 0; oo < 8; ++oo) {
    redr[g][oo * 64 + x] = accr[oo];
    redi[g][oo * 64 + x] = acci[oo];
  }
  __syncthreads();

  const float INV = 1.0f / (512.0f * 512.0f);
  for (int idx = tid; idx < 512; idx += 256) {
    int oo = idx >> 6, x2 = idx & 63;
    float r = redr[0][idx] + redr[1][idx] + redr[2][idx] + redr[3][idx];
    float i = redi[0][idx] + redi[1][idx] + redi[2][idx] + redi[3][idx];
    size_t oidx = ((size_t)(bh * 64 + oc * 8 + oo) * 64 + x2) * 2;
    xw[oidx] = r * INV;
    xw[oidx + 1] = i * INV;
  }
}

// ---------------------------------------------------------------------------
// Kernel 6: 64-mode irfft via per-thread rotation (no LDS tables, no bank
// conflicts), add 0.5*spec into d_out (which holds 0.5*attn).
// ---------------------------------------------------------------------------
__global__ __launch_bounds__(256) void k_final(const float* __restrict__ xw,
                                               float* __restrict__ out) {
  __shared__ float Xre[8][64], Xim[8][64];   // pre-scaled by 2
  const int oc = blockIdx.x & 7;
  const int bh = blockIdx.x >> 3;
  const int o0 = oc * 8;
  const int tid = threadIdx.x;

  for (int idx = tid; idx < 512; idx += 256) {
    int o = idx >> 6, m = idx & 63;
    size_t s = ((size_t)(bh * 64 + o0 + o) * 64 + m) * 2;
    Xre[o][m] = 2.f * xw[s]; Xim[o][m] = 2.f * xw[s + 1];
  }
  __syncthreads();

  const int ts = tid & 31, ol = tid >> 5;
  const float HALF_INVN = 0.5f / 1024.0f;
  const float TWO_PI = 6.283185307179586f;
  for (int k = 0; k < 32; ++k) {
    int t = ts + k * 32;
    float th = TWO_PI * (float)t * (1.0f / 1024.0f);
    float s1, c1;
    __sincosf(th, &s1, &c1);
    float cm = c1, sm = s1;
    float acc = 0.5f * Xre[ol][0];
#pragma unroll 9
    for (int m = 1; m < 64; ++m) {
      acc = fmaf(Xre[ol][m], cm, acc);
      acc = fmaf(-Xim[ol][m], sm, acc);
      float cn = fmaf(cm, c1, -sm * s1);
      float sn = fmaf(sm, c1, cm * s1);
      cm = cn; sm = sn;
    }
    size_t oi = ((size_t)(bh * 64 + o0 + ol)) * 1024 + t;
    out[oi] = fmaf(acc, HALF_INVN, out[oi]);
  }
}

// ---------------------------------------------------------------------------
extern "C" void kernel_launch(void* const* d_in, const int* in_sizes, int n_in,
                              void* d_out, int out_size, void* d_ws, size_t ws_size,
                              hipStream_t stream) {
  const float* tfq   = (const float*)d_in[0];
  const float* q     = (const float*)d_in[1];
  const float* k     = (const float*)d_in[2];
  const float* v     = (const float*)d_in[3];
  const float* wfuse = (const float*)d_in[5];
  const float* w1re  = (const float*)d_in[6];
  const float* w1im  = (const float*)d_in[7];
  float* out = (float*)d_out;
  float* ws  = (float*)d_ws;

  // ws layout (floats):
  //   xre_g[131072] | xim_g[131072] | sel(int)[4096] |
  //   amp2[524288] ALIASES qft[262144]|kft[262144] (amp2 dead after k_topk,
  //   which runs before k_dft in stream order) | xw[262144]
  float* xre_g  = ws;
  float* xim_g  = ws + 131072;
  int*   sel    = (int*)(ws + 262144);
  float* amp2   = ws + 266240;
  float* qft    = ws + 266240;
  float* kft    = ws + 528384;
  float* xw     = ws + 790528;

  k_corr<<<1024, 256, 0, stream>>>(q, k, amp2);
  k_topk<<<64, 256, 0, stream>>>(amp2, tfq, sel);
  k_attn<<<512, 256, 0, stream>>>(q, tfq, k, v, wfuse, sel, out);
  k_dft<<<512, 256, 0, stream>>>(q, k, qft, kft);
  k_spec12<<<256, 256, 0, stream>>>(qft, kft, xre_g, xim_g);
  k_w1<<<256, 256, 0, stream>>>(xre_g, xim_g, w1re, w1im, xw);
  k_final<<<256, 256, 0, stream>>>(xw, out);
}

// Round 8
// 213.453 us; speedup vs baseline: 3.6721x; 1.2514x over previous
//
#include <hip/hip_runtime.h>
#include <math.h>

#define B_ 4
#define H_ 8
#define L_ 1024
#define E_ 64
#define NTOP 35
#define SCALE_ 0.04419417382415922f  /* 1/sqrt(512) */

// ---------------------------------------------------------------------------
// Kernel 1 (replaces k_corr AND k_dft): FFT-based circular cross-correlation
// amplitude + first-64-mode spectra.
// Grid: (bh, e-group of 4) = 512 blocks x 256 threads.
// Per block: z = q + i*k for 4 consecutive e -> 4 forward complex FFTs
// (DIF, natural->bitrev) -> Hermitian unpack (dump modes 0..63 to qft/kft)
// -> P = Fq*conj(Fk) -> pack e-pairs S = P0 + i*P1 -> 2 inverse FFTs
// (DIT, bitrev->natural) -> amp2 = sum_e corr^2 (unscaled; rank-invariant).
// amp2_part[(bh*16+eg)*1024 + tau]
// ---------------------------------------------------------------------------
__global__ __launch_bounds__(256) void k_fft(const float* __restrict__ q_g,
                                             const float* __restrict__ k_g,
                                             float* __restrict__ amp2_part,
                                             float* __restrict__ qft,
                                             float* __restrict__ kft) {
  __shared__ float zre[4][1024], zim[4][1024];
  __shared__ float ctab[512], stab[512];
  const int eg = blockIdx.x & 15;
  const int bh = blockIdx.x >> 4;
  const int b = bh >> 3, h = bh & 7;
  const int tid = threadIdx.x;
  const float TWO_PI_N = 6.283185307179586f / 1024.0f;

  for (int j = tid; j < 512; j += 256) {
    float s, c;
    sincosf(TWO_PI_N * (float)j, &s, &c);
    ctab[j] = c; stab[j] = s;     // W^j = c - i*s
  }
  // stage q,k: one float4 per t covers this block's 4 e's (line-exact loads)
  for (int t = tid; t < 1024; t += 256) {
    size_t g4 = ((size_t)(b * L_ + t) * H_ + h) * 16 + eg;
    float4 qv = reinterpret_cast<const float4*>(q_g)[g4];
    float4 kv = reinterpret_cast<const float4*>(k_g)[g4];
    zre[0][t] = qv.x; zre[1][t] = qv.y; zre[2][t] = qv.z; zre[3][t] = qv.w;
    zim[0][t] = kv.x; zim[1][t] = kv.y; zim[2][t] = kv.z; zim[3][t] = kv.w;
  }
  __syncthreads();

  // ---- forward DIF: 4 FFTs x 512 butterflies = 2048/stage, 8 per thread
  for (int s = 0; s < 10; ++s) {
    const int half = 512 >> s;
#pragma unroll
    for (int it = 0; it < 8; ++it) {
      int idx = tid + it * 256;         // 0..2047
      int ee = idx >> 9;
      int bf = idx & 511;
      int j = bf & (half - 1);
      int p0 = ((bf >> (9 - s)) << (10 - s)) + j;
      int p1 = p0 + half;
      float ur = zre[ee][p0], ui = zim[ee][p0];
      float vr = zre[ee][p1], vi = zim[ee][p1];
      float dr = ur - vr, di = ui - vi;
      zre[ee][p0] = ur + vr; zim[ee][p0] = ui + vi;
      int twi = j << s;
      float c = ctab[twi], sn = stab[twi];
      zre[ee][p1] = fmaf(dr, c, di * sn);     // (dr+i di)(c - i sn)
      zim[ee][p1] = fmaf(di, c, -dr * sn);
    }
    __syncthreads();
  }

  // ---- Hermitian unpack + P = Fq*conj(Fk); dump modes 0..63 to qft/kft.
  // Storage position p holds frequency m = bitrev10(p).
  float pr[16], pi_[16];
#pragma unroll
  for (int it = 0; it < 16; ++it) {
    int idx = tid + it * 256;           // 0..4095
    int ee = idx >> 10;
    int p = idx & 1023;
    int m = __brev((unsigned)p) >> 22;
    int mp = (1024 - m) & 1023;
    int pp = __brev((unsigned)mp) >> 22;
    float ar = zre[ee][p], ai = zim[ee][p];
    float br = zre[ee][pp], bi = zim[ee][pp];   // Z[-m]
    float qr = 0.5f * (ar + br), qi = 0.5f * (ai - bi);   // rfft(q)[m]
    float kr = 0.5f * (ai + bi), ki = -0.5f * (ar - br);  // rfft(k)[m]
    pr[it]  = fmaf(qr, kr, qi * ki);    // P = Fq * conj(Fk)
    pi_[it] = fmaf(qi, kr, -qr * ki);
    if (m < 64) {
      size_t o = ((size_t)(bh * 64 + eg * 4 + ee) * 64 + m) * 2;
      qft[o] = qr; qft[o + 1] = qi;
      kft[o] = kr; kft[o + 1] = ki;
    }
  }
  __syncthreads();
#pragma unroll
  for (int it = 0; it < 16; ++it) {
    int idx = tid + it * 256;
    int ee = idx >> 10;
    int p = idx & 1023;
    zre[ee][p] = pr[it]; zim[ee][p] = pi_[it];
  }
  __syncthreads();

  // ---- pair-mix: slot 2u := P_{2u} + i*P_{2u+1}  (disjoint writes, race-free)
  for (int idx = tid; idx < 2048; idx += 256) {
    int u = idx >> 10;
    int p = idx & 1023;
    int e0 = 2 * u, e1 = 2 * u + 1;
    float s_r = zre[e0][p] - zim[e1][p];
    float s_i = zim[e0][p] + zre[e1][p];
    zre[e0][p] = s_r; zim[e0][p] = s_i;
  }
  __syncthreads();

  // ---- inverse DIT on slots 0,2: 1024 butterflies/stage, 4 per thread
  for (int s = 9; s >= 0; --s) {
    const int half = 512 >> s;
#pragma unroll
    for (int it = 0; it < 4; ++it) {
      int idx = tid + it * 256;         // 0..1023
      int ee = (idx >> 9) * 2;          // slot 0 or 2
      int bf = idx & 511;
      int j = bf & (half - 1);
      int p0 = ((bf >> (9 - s)) << (10 - s)) + j;
      int p1 = p0 + half;
      int twi = j << s;
      float c = ctab[twi], sn = stab[twi];
      float ur = zre[ee][p0], ui = zim[ee][p0];
      float wr = zre[ee][p1], wi = zim[ee][p1];
      float vr = fmaf(wr, c, -wi * sn);   // w * conj(W)^j = w*(c + i sn)
      float vi = fmaf(wi, c, wr * sn);
      zre[ee][p0] = ur + vr; zim[ee][p0] = ui + vi;
      zre[ee][p1] = ur - vr; zim[ee][p1] = ui - vi;
    }
    __syncthreads();
  }

  // ---- amp2: slot0 = corr_e0 + i corr_e1, slot2 = corr_e2 + i corr_e3
  for (int t = tid; t < 1024; t += 256) {
    float r0 = zre[0][t], i0 = zim[0][t];
    float r2 = zre[2][t], i2 = zim[2][t];
    amp2_part[(size_t)(bh * 16 + eg) * 1024 + t] =
        fmaf(r0, r0, fmaf(i0, i0, fmaf(r2, r2, i2 * i2)));
  }
}

// ---------------------------------------------------------------------------
// Kernel 2: top-35 selection per (b,h,src). Wave-shuffle argmax per round;
// only the owner thread rescans after removal. Lowest-index tie-break.
// ---------------------------------------------------------------------------
__global__ __launch_bounds__(256) void k_topk(const float* __restrict__ amp2_part,
                                              const float* __restrict__ tfq,
                                              int* __restrict__ sel_ws) {
  __shared__ float amp[1024];
  __shared__ float wv_s[4];
  __shared__ int wi_s[4];
  __shared__ int winner_s;
  const int src = blockIdx.x & 1;
  const int bh = blockIdx.x >> 1;
  const int b = bh >> 3, h = bh & 7;
  const int tid = threadIdx.x;

  if (src == 0) {
    for (int t = tid; t < 1024; t += 256) {
      float s = 0.f;
#pragma unroll
      for (int c = 0; c < 16; ++c) s += amp2_part[(size_t)(bh * 16 + c) * 1024 + t];
      amp[t] = s;
    }
  } else {
    for (int l = tid; l < 1024; l += 256) {
      const float4* p4 = reinterpret_cast<const float4*>(
          &tfq[((size_t)(b * L_ + l) * H_ + h) * E_]);
      float s = 0.f;
#pragma unroll
      for (int e4 = 0; e4 < 16; ++e4) {
        float4 v = p4[e4];
        s += v.x * v.x + v.y * v.y + v.z * v.z + v.w * v.w;
      }
      amp[l] = s;
    }
  }
  __syncthreads();

  float bv = -1.f; int bi = tid;
#pragma unroll
  for (int kk = 0; kk < 4; ++kk) {
    int t = tid + kk * 256;
    float v = amp[t];
    if (v > bv) { bv = v; bi = t; }
  }
  const int lane = tid & 63, w = tid >> 6;

  for (int it = 0; it < NTOP; ++it) {
    float v = bv; int i = bi;
#pragma unroll
    for (int d = 1; d < 64; d <<= 1) {
      float ov = __shfl_xor(v, d);
      int oi = __shfl_xor(i, d);
      if (ov > v || (ov == v && oi < i)) { v = ov; i = oi; }
    }
    if (lane == 0) { wv_s[w] = v; wi_s[w] = i; }
    __syncthreads();
    if (tid == 0) {
      float fv = wv_s[0]; int fi = wi_s[0];
#pragma unroll
      for (int j = 1; j < 4; ++j) {
        if (wv_s[j] > fv || (wv_s[j] == fv && wi_s[j] < fi)) { fv = wv_s[j]; fi = wi_s[j]; }
      }
      winner_s = fi;
      sel_ws[(bh * 2 + src) * 64 + it] = fi;
    }
    __syncthreads();
    int fi = winner_s;
    if ((fi & 255) == tid) {
      amp[fi] = -1.f;
      bv = -1.f; bi = tid;
#pragma unroll
      for (int kk = 0; kk < 4; ++kk) {
        int t = tid + kk * 256;
        float vv = amp[t];
        if (vv > bv) { bv = vv; bi = t; }
      }
    }
  }
}

// ---------------------------------------------------------------------------
// Kernel 3: scores over selected rows -> two softmaxes -> fuse -> times V.
// Grid: (bh, a-chunk of 64) = 512 blocks x 256 threads.
// Writes 0.5*attn directly into d_out at [(bh*64+d)*1024 + a].
// ---------------------------------------------------------------------------
__global__ __launch_bounds__(256) void k_attn(const float* __restrict__ q_g,
                                              const float* __restrict__ tfq,
                                              const float* __restrict__ k_g,
                                              const float* __restrict__ v_g,
                                              const float* __restrict__ wfuse,
                                              const int* __restrict__ sel_ws,
                                              float* __restrict__ out) {
  __shared__ float qselt[NTOP][64];
  __shared__ float qseltf[NTOP][64];
  __shared__ float vselt[NTOP][64];
  __shared__ float vseltf[NTOP][64];
  __shared__ float ks[64][65];
  const int ac = blockIdx.x & 15;
  const int bh = blockIdx.x >> 4;
  const int b = bh >> 3, h = bh & 7;
  const int a0 = ac * 64;
  const int tid = threadIdx.x;

  for (int idx = tid; idx < NTOP * 64; idx += 256) {
    int i = idx >> 6, e = idx & 63;
    int st = sel_ws[(bh * 2 + 0) * 64 + i];
    int sf = sel_ws[(bh * 2 + 1) * 64 + i];
    qselt[i][e]  = q_g[((size_t)(b * L_ + st) * H_ + h) * E_ + e];
    qseltf[i][e] = tfq[((size_t)(b * L_ + sf) * H_ + h) * E_ + e];
    vselt[i][e]  = v_g[((size_t)(b * L_ + st) * H_ + h) * E_ + e];
    vseltf[i][e] = v_g[((size_t)(b * L_ + sf) * H_ + h) * E_ + e];
  }
  for (int idx = tid; idx < 64 * 64; idx += 256) {
    int r = idx >> 6, e = idx & 63;
    ks[r][e] = k_g[((size_t)(b * L_ + a0 + r) * H_ + h) * E_ + e];
  }
  __syncthreads();

  const int qd = tid & 3, r = tid >> 2;
  const int a = a0 + r;
  const int eb = qd * 16;

  float ct[NTOP], ctf[NTOP];
#pragma unroll
  for (int i = 0; i < NTOP; ++i) { ct[i] = 0.f; ctf[i] = 0.f; }
  for (int j = 0; j < 16; ++j) {
    float kv = ks[r][eb + j];
#pragma unroll
    for (int i = 0; i < NTOP; ++i) {
      ct[i]  = fmaf(qselt[i][eb + j], kv, ct[i]);
      ctf[i] = fmaf(qseltf[i][eb + j], kv, ctf[i]);
    }
  }
#pragma unroll
  for (int i = 0; i < NTOP; ++i) {
    ct[i] += __shfl_xor(ct[i], 1);  ct[i] += __shfl_xor(ct[i], 2);
    ctf[i] += __shfl_xor(ctf[i], 1); ctf[i] += __shfl_xor(ctf[i], 2);
  }

  float wf0 = wfuse[(h * L_ + a) * 2 + 0];
  float wf1 = wfuse[(h * L_ + a) * 2 + 1];
  float wm = fmaxf(wf0, wf1);
  float ew0 = expf(wf0 - wm), ew1 = expf(wf1 - wm);
  float nw0 = ew0 / (ew0 + ew1), nw1 = ew1 / (ew0 + ew1);

  {
    float m = -1e30f;
#pragma unroll
    for (int i = 0; i < NTOP; ++i) { ct[i] *= SCALE_; m = fmaxf(m, ct[i]); }
    float sum = 0.f;
#pragma unroll
    for (int i = 0; i < NTOP; ++i) { ct[i] = expf(ct[i] - m); sum += ct[i]; }
    float c = 0.5f * nw0 / sum;
#pragma unroll
    for (int i = 0; i < NTOP; ++i) ct[i] *= c;
  }
  {
    float m = -1e30f;
#pragma unroll
    for (int i = 0; i < NTOP; ++i) { ctf[i] *= SCALE_; m = fmaxf(m, ctf[i]); }
    float sum = 0.f;
#pragma unroll
    for (int i = 0; i < NTOP; ++i) { ctf[i] = expf(ctf[i] - m); sum += ctf[i]; }
    float c = 0.5f * nw1 / sum;
#pragma unroll
    for (int i = 0; i < NTOP; ++i) ctf[i] *= c;
  }
  for (int j = 0; j < 16; ++j) {
    int d = eb + j;
    float acc = 0.f;
#pragma unroll
    for (int i = 0; i < NTOP; ++i) acc = fmaf(ct[i], vselt[i][d], acc);
#pragma unroll
    for (int i = 0; i < NTOP; ++i) acc = fmaf(ctf[i], vseltf[i][d], acc);
    out[((size_t)(bh * 64 + d)) * 1024 + a] = acc;
  }
}

// ---------------------------------------------------------------------------
// Kernel 5a: xqk = ctanh(q_ft^T k_ft); xqkv = xqk @ k_ft^T.
// Grid: (bh, x-chunk of 8) = 256 blocks, 256 threads.
// ---------------------------------------------------------------------------
__global__ __launch_bounds__(256) void k_spec12(const float* __restrict__ qft,
                                                 const float* __restrict__ kft,
                                                 float* __restrict__ xre_g,
                                                 float* __restrict__ xim_g) {
  __shared__ float kre[64][65], kim[64][65];
  __shared__ float qre[64][8], qim[64][8];
  __shared__ float tre[8][64], tim[8][64];
  const int xc = blockIdx.x & 7;
  const int bh = blockIdx.x >> 3;
  const int tid = threadIdx.x;

  for (int idx = tid; idx < 4096; idx += 256) {
    int e = idx >> 6, y = idx & 63;
    size_t o = ((size_t)(bh * 64 + e) * 64 + y) * 2;
    kre[e][y] = kft[o]; kim[e][y] = kft[o + 1];
  }
  for (int idx = tid; idx < 512; idx += 256) {
    int e = idx >> 3, xl = idx & 7;
    size_t o = ((size_t)(bh * 64 + e) * 64 + xc * 8 + xl) * 2;
    qre[e][xl] = qft[o]; qim[e][xl] = qft[o + 1];
  }
  __syncthreads();

  const int y = tid & 63, xg = tid >> 6;
#pragma unroll
  for (int xi = 0; xi < 2; ++xi) {
    int xl = xg + xi * 4;
    float ar = 0.f, ai = 0.f;
    for (int e = 0; e < 64; ++e) {
      float a = qre[e][xl], b = qim[e][xl];
      float c = kre[e][y], d = kim[e][y];
      ar = fmaf(a, c, fmaf(-b, d, ar));
      ai = fmaf(a, d, fmaf(b, c, ai));
    }
    float trv, tiv;
    float x2 = 2.f * ar, y2 = 2.f * ai;
    if (fabsf(x2) > 30.f) {
      trv = copysignf(1.f, ar); tiv = 0.f;
    } else {
      float sh = sinhf(x2), ch = coshf(x2);
      float sn = sinf(y2), cs = cosf(y2);
      float dd = ch + cs;
      trv = sh / dd; tiv = sn / dd;
    }
    tre[xl][y] = trv; tim[xl][y] = tiv;
  }
  __syncthreads();

  const int e2 = tid & 63, xg2 = tid >> 6;
#pragma unroll
  for (int xi = 0; xi < 2; ++xi) {
    int xl = xg2 + xi * 4;
    float ar = 0.f, ai = 0.f;
    for (int yy = 0; yy < 64; ++yy) {
      float a = tre[xl][yy], b = tim[xl][yy];
      float c = kre[e2][yy], d = kim[e2][yy];
      ar = fmaf(a, c, fmaf(-b, d, ar));
      ai = fmaf(a, d, fmaf(b, c, ai));
    }
    xre_g[(size_t)bh * 4096 + (xc * 8 + xl) * 64 + e2] = ar;
    xim_g[(size_t)bh * 4096 + (xc * 8 + xl) * 64 + e2] = ai;
  }
}

// ---------------------------------------------------------------------------
// Kernel 5b: xqkvw[o][x] = (sum_e xqkv[e][x]*w1[h,e,o,x]) / 512^2.
// ---------------------------------------------------------------------------
__global__ __launch_bounds__(256) void k_w1(const float* __restrict__ xre_g,
                                            const float* __restrict__ xim_g,
                                            const float* __restrict__ w1re,
                                            const float* __restrict__ w1im,
                                            float* __restrict__ xw) {
  __shared__ float xre[64][65], xim[64][65];
  __shared__ float redr[4][512], redi[4][512];
  const int oc = blockIdx.x & 7;
  const int bh = blockIdx.x >> 3;
  const int h = bh & 7;
  const int tid = threadIdx.x;

  for (int idx = tid; idx < 4096; idx += 256) {
    int x = idx >> 6, e = idx & 63;
    xre[e][x] = xre_g[(size_t)bh * 4096 + idx];
    xim[e][x] = xim_g[(size_t)bh * 4096 + idx];
  }
  __syncthreads();

  const int x = tid & 63, g = tid >> 6;
  float accr[8], acci[8];
#pragma unroll
  for (int oo = 0; oo < 8; ++oo) { accr[oo] = 0.f; acci[oo] = 0.f; }

  for (int ee = 0; ee < 16; ++ee) {
    int e = g * 16 + ee;
    float a = xre[e][x], b = xim[e][x];
    size_t wbase = (((size_t)h * 64 + e) * 64 + oc * 8) * 64 + x;
#pragma unroll
    for (int oo = 0; oo < 8; ++oo) {
      float c = w1re[wbase + (size_t)oo * 64];
      float d = w1im[wbase + (size_t)oo * 64];
      accr[oo] = fmaf(a, c, fmaf(-b, d, accr[oo]));
      acci[oo] = fmaf(a, d, fmaf(b, c, acci[oo]));
    }
  }
#pragma unroll
  for (int oo = 0; oo < 8; ++oo) {
    redr[g][oo * 64 + x] = accr[oo];
    redi[g][oo * 64 + x] = acci[oo];
  }
  __syncthreads();

  const float INV = 1.0f / (512.0f * 512.0f);
  for (int idx = tid; idx < 512; idx += 256) {
    int oo = idx >> 6, x2 = idx & 63;
    float r = redr[0][idx] + redr[1][idx] + redr[2][idx] + redr[3][idx];
    float i = redi[0][idx] + redi[1][idx] + redi[2][idx] + redi[3][idx];
    size_t oidx = ((size_t)(bh * 64 + oc * 8 + oo) * 64 + x2) * 2;
    xw[oidx] = r * INV;
    xw[oidx + 1] = i * INV;
  }
}

// ---------------------------------------------------------------------------
// Kernel 6: 64-mode irfft via per-thread rotation, add 0.5*spec into d_out.
// ---------------------------------------------------------------------------
__global__ __launch_bounds__(256) void k_final(const float* __restrict__ xw,
                                               float* __restrict__ out) {
  __shared__ float Xre[8][64], Xim[8][64];   // pre-scaled by 2
  const int oc = blockIdx.x & 7;
  const int bh = blockIdx.x >> 3;
  const int o0 = oc * 8;
  const int tid = threadIdx.x;

  for (int idx = tid; idx < 512; idx += 256) {
    int o = idx >> 6, m = idx & 63;
    size_t s = ((size_t)(bh * 64 + o0 + o) * 64 + m) * 2;
    Xre[o][m] = 2.f * xw[s]; Xim[o][m] = 2.f * xw[s + 1];
  }
  __syncthreads();

  const int ts = tid & 31, ol = tid >> 5;
  const float HALF_INVN = 0.5f / 1024.0f;
  const float TWO_PI = 6.283185307179586f;
  for (int k = 0; k < 32; ++k) {
    int t = ts + k * 32;
    float th = TWO_PI * (float)t * (1.0f / 1024.0f);
    float s1, c1;
    __sincosf(th, &s1, &c1);
    float cm = c1, sm = s1;
    float acc = 0.5f * Xre[ol][0];
#pragma unroll 9
    for (int m = 1; m < 64; ++m) {
      acc = fmaf(Xre[ol][m], cm, acc);
      acc = fmaf(-Xim[ol][m], sm, acc);
      float cn = fmaf(cm, c1, -sm * s1);
      float sn = fmaf(sm, c1, cm * s1);
      cm = cn; sm = sn;
    }
    size_t oi = ((size_t)(bh * 64 + o0 + ol)) * 1024 + t;
    out[oi] = fmaf(acc, HALF_INVN, out[oi]);
  }
}

// ---------------------------------------------------------------------------
extern "C" void kernel_launch(void* const* d_in, const int* in_sizes, int n_in,
                              void* d_out, int out_size, void* d_ws, size_t ws_size,
                              hipStream_t stream) {
  const float* tfq   = (const float*)d_in[0];
  const float* q     = (const float*)d_in[1];
  const float* k     = (const float*)d_in[2];
  const float* v     = (const float*)d_in[3];
  const float* wfuse = (const float*)d_in[5];
  const float* w1re  = (const float*)d_in[6];
  const float* w1im  = (const float*)d_in[7];
  float* out = (float*)d_out;
  float* ws  = (float*)d_ws;

  // ws layout (floats), total 1052672 (4.2 MB):
  //   region A [0..524288): amp2 (k_fft -> k_topk); REUSED afterwards as
  //     xre_g[0:131072] | xim_g[131072:262144] | xw[262144:524288]
  //     (all written only after k_topk has consumed amp2 — same stream).
  //   qft [524288..786432) | kft [786432..1048576)  (k_fft -> k_spec12)
  //   sel (int) at [1048576..1052672)
  float* amp2  = ws;
  float* xre_g = ws;
  float* xim_g = ws + 131072;
  float* xw    = ws + 262144;
  float* qft   = ws + 524288;
  float* kft   = ws + 786432;
  int*   sel   = (int*)(ws + 1048576);

  k_fft<<<512, 256, 0, stream>>>(q, k, amp2, qft, kft);
  k_topk<<<64, 256, 0, stream>>>(amp2, tfq, sel);
  k_attn<<<512, 256, 0, stream>>>(q, tfq, k, v, wfuse, sel, out);
  k_spec12<<<256, 256, 0, stream>>>(qft, kft, xre_g, xim_g);
  k_w1<<<256, 256, 0, stream>>>(xre_g, xim_g, w1re, w1im, xw);
  k_final<<<256, 256, 0, stream>>>(xw, out);
}

// Round 9
// 176.714 us; speedup vs baseline: 4.4356x; 1.2079x over previous
//
#include <hip/hip_runtime.h>
#include <math.h>

#define B_ 4
#define H_ 8
#define L_ 1024
#define E_ 64
#define NTOP 35
#define SCALE_ 0.04419417382415922f  /* 1/sqrt(512) */

// ---------------------------------------------------------------------------
// Kernel 1 (replaces k_corr AND k_dft): FFT-based circular cross-correlation
// amplitude + first-64-mode spectra.
// Grid: (bh, e-group of 4) = 512 blocks x 256 threads.
// Per block: z = q + i*k for 4 consecutive e -> 4 forward complex FFTs
// (DIF, natural->bitrev) -> Hermitian unpack (dump modes 0..63 to qft/kft)
// -> P = Fq*conj(Fk) -> pack e-pairs S = P0 + i*P1 -> 2 inverse FFTs
// (DIT, bitrev->natural) -> amp2 = sum_e corr^2 (unscaled; rank-invariant).
// ---------------------------------------------------------------------------
__global__ __launch_bounds__(256) void k_fft(const float* __restrict__ q_g,
                                             const float* __restrict__ k_g,
                                             float* __restrict__ amp2_part,
                                             float* __restrict__ qft,
                                             float* __restrict__ kft) {
  __shared__ float zre[4][1024], zim[4][1024];
  __shared__ float ctab[512], stab[512];
  const int eg = blockIdx.x & 15;
  const int bh = blockIdx.x >> 4;
  const int b = bh >> 3, h = bh & 7;
  const int tid = threadIdx.x;
  const float TWO_PI_N = 6.283185307179586f / 1024.0f;

  for (int j = tid; j < 512; j += 256) {
    float s, c;
    sincosf(TWO_PI_N * (float)j, &s, &c);
    ctab[j] = c; stab[j] = s;     // W^j = c - i*s
  }
  for (int t = tid; t < 1024; t += 256) {
    size_t g4 = ((size_t)(b * L_ + t) * H_ + h) * 16 + eg;
    float4 qv = reinterpret_cast<const float4*>(q_g)[g4];
    float4 kv = reinterpret_cast<const float4*>(k_g)[g4];
    zre[0][t] = qv.x; zre[1][t] = qv.y; zre[2][t] = qv.z; zre[3][t] = qv.w;
    zim[0][t] = kv.x; zim[1][t] = kv.y; zim[2][t] = kv.z; zim[3][t] = kv.w;
  }
  __syncthreads();

  // ---- forward DIF: 4 FFTs x 512 butterflies = 2048/stage, 8 per thread
  for (int s = 0; s < 10; ++s) {
    const int half = 512 >> s;
#pragma unroll
    for (int it = 0; it < 8; ++it) {
      int idx = tid + it * 256;
      int ee = idx >> 9;
      int bf = idx & 511;
      int j = bf & (half - 1);
      int p0 = ((bf >> (9 - s)) << (10 - s)) + j;
      int p1 = p0 + half;
      float ur = zre[ee][p0], ui = zim[ee][p0];
      float vr = zre[ee][p1], vi = zim[ee][p1];
      float dr = ur - vr, di = ui - vi;
      zre[ee][p0] = ur + vr; zim[ee][p0] = ui + vi;
      int twi = j << s;
      float c = ctab[twi], sn = stab[twi];
      zre[ee][p1] = fmaf(dr, c, di * sn);
      zim[ee][p1] = fmaf(di, c, -dr * sn);
    }
    __syncthreads();
  }

  // ---- Hermitian unpack + P = Fq*conj(Fk); dump modes 0..63 to qft/kft.
  float pr[16], pi_[16];
#pragma unroll
  for (int it = 0; it < 16; ++it) {
    int idx = tid + it * 256;
    int ee = idx >> 10;
    int p = idx & 1023;
    int m = __brev((unsigned)p) >> 22;
    int mp = (1024 - m) & 1023;
    int pp = __brev((unsigned)mp) >> 22;
    float ar = zre[ee][p], ai = zim[ee][p];
    float br = zre[ee][pp], bi = zim[ee][pp];
    float qr = 0.5f * (ar + br), qi = 0.5f * (ai - bi);
    float kr = 0.5f * (ai + bi), ki = -0.5f * (ar - br);
    pr[it]  = fmaf(qr, kr, qi * ki);
    pi_[it] = fmaf(qi, kr, -qr * ki);
    if (m < 64) {
      size_t o = ((size_t)(bh * 64 + eg * 4 + ee) * 64 + m) * 2;
      qft[o] = qr; qft[o + 1] = qi;
      kft[o] = kr; kft[o + 1] = ki;
    }
  }
  __syncthreads();
#pragma unroll
  for (int it = 0; it < 16; ++it) {
    int idx = tid + it * 256;
    int ee = idx >> 10;
    int p = idx & 1023;
    zre[ee][p] = pr[it]; zim[ee][p] = pi_[it];
  }
  __syncthreads();

  // ---- pair-mix: slot 2u := P_{2u} + i*P_{2u+1}
  for (int idx = tid; idx < 2048; idx += 256) {
    int u = idx >> 10;
    int p = idx & 1023;
    int e0 = 2 * u, e1 = 2 * u + 1;
    float s_r = zre[e0][p] - zim[e1][p];
    float s_i = zim[e0][p] + zre[e1][p];
    zre[e0][p] = s_r; zim[e0][p] = s_i;
  }
  __syncthreads();

  // ---- inverse DIT on slots 0,2
  for (int s = 9; s >= 0; --s) {
    const int half = 512 >> s;
#pragma unroll
    for (int it = 0; it < 4; ++it) {
      int idx = tid + it * 256;
      int ee = (idx >> 9) * 2;
      int bf = idx & 511;
      int j = bf & (half - 1);
      int p0 = ((bf >> (9 - s)) << (10 - s)) + j;
      int p1 = p0 + half;
      int twi = j << s;
      float c = ctab[twi], sn = stab[twi];
      float ur = zre[ee][p0], ui = zim[ee][p0];
      float wr = zre[ee][p1], wi = zim[ee][p1];
      float vr = fmaf(wr, c, -wi * sn);
      float vi = fmaf(wi, c, wr * sn);
      zre[ee][p0] = ur + vr; zim[ee][p0] = ui + vi;
      zre[ee][p1] = ur - vr; zim[ee][p1] = ui - vi;
    }
    __syncthreads();
  }

  // ---- amp2
  for (int t = tid; t < 1024; t += 256) {
    float r0 = zre[0][t], i0 = zim[0][t];
    float r2 = zre[2][t], i2 = zim[2][t];
    amp2_part[(size_t)(bh * 16 + eg) * 1024 + t] =
        fmaf(r0, r0, fmaf(i0, i0, fmaf(r2, r2, i2 * i2)));
  }
}

// ---------------------------------------------------------------------------
// Kernel 2: top-35 selection per (b,h,src). Wave-shuffle argmax per round;
// only the owner thread rescans after removal. Lowest-index tie-break.
// ---------------------------------------------------------------------------
__global__ __launch_bounds__(256) void k_topk(const float* __restrict__ amp2_part,
                                              const float* __restrict__ tfq,
                                              int* __restrict__ sel_ws) {
  __shared__ float amp[1024];
  __shared__ float wv_s[4];
  __shared__ int wi_s[4];
  __shared__ int winner_s;
  const int src = blockIdx.x & 1;
  const int bh = blockIdx.x >> 1;
  const int b = bh >> 3, h = bh & 7;
  const int tid = threadIdx.x;

  if (src == 0) {
    for (int t = tid; t < 1024; t += 256) {
      float s = 0.f;
#pragma unroll
      for (int c = 0; c < 16; ++c) s += amp2_part[(size_t)(bh * 16 + c) * 1024 + t];
      amp[t] = s;
    }
  } else {
    for (int l = tid; l < 1024; l += 256) {
      const float4* p4 = reinterpret_cast<const float4*>(
          &tfq[((size_t)(b * L_ + l) * H_ + h) * E_]);
      float s = 0.f;
#pragma unroll
      for (int e4 = 0; e4 < 16; ++e4) {
        float4 v = p4[e4];
        s += v.x * v.x + v.y * v.y + v.z * v.z + v.w * v.w;
      }
      amp[l] = s;
    }
  }
  __syncthreads();

  float bv = -1.f; int bi = tid;
#pragma unroll
  for (int kk = 0; kk < 4; ++kk) {
    int t = tid + kk * 256;
    float v = amp[t];
    if (v > bv) { bv = v; bi = t; }
  }
  const int lane = tid & 63, w = tid >> 6;

  for (int it = 0; it < NTOP; ++it) {
    float v = bv; int i = bi;
#pragma unroll
    for (int d = 1; d < 64; d <<= 1) {
      float ov = __shfl_xor(v, d);
      int oi = __shfl_xor(i, d);
      if (ov > v || (ov == v && oi < i)) { v = ov; i = oi; }
    }
    if (lane == 0) { wv_s[w] = v; wi_s[w] = i; }
    __syncthreads();
    if (tid == 0) {
      float fv = wv_s[0]; int fi = wi_s[0];
#pragma unroll
      for (int j = 1; j < 4; ++j) {
        if (wv_s[j] > fv || (wv_s[j] == fv && wi_s[j] < fi)) { fv = wv_s[j]; fi = wi_s[j]; }
      }
      winner_s = fi;
      sel_ws[(bh * 2 + src) * 64 + it] = fi;
    }
    __syncthreads();
    int fi = winner_s;
    if ((fi & 255) == tid) {
      amp[fi] = -1.f;
      bv = -1.f; bi = tid;
#pragma unroll
      for (int kk = 0; kk < 4; ++kk) {
        int t = tid + kk * 256;
        float vv = amp[t];
        if (vv > bv) { bv = vv; bi = t; }
      }
    }
  }
}

// ---------------------------------------------------------------------------
// Kernel 3: scores over selected rows -> two softmaxes -> fuse -> times V.
// Grid: (bh, a-chunk of 64) = 512 blocks x 256 threads.
// ---------------------------------------------------------------------------
__global__ __launch_bounds__(256) void k_attn(const float* __restrict__ q_g,
                                              const float* __restrict__ tfq,
                                              const float* __restrict__ k_g,
                                              const float* __restrict__ v_g,
                                              const float* __restrict__ wfuse,
                                              const int* __restrict__ sel_ws,
                                              float* __restrict__ out) {
  __shared__ float qselt[NTOP][64];
  __shared__ float qseltf[NTOP][64];
  __shared__ float vselt[NTOP][64];
  __shared__ float vseltf[NTOP][64];
  __shared__ float ks[64][65];
  const int ac = blockIdx.x & 15;
  const int bh = blockIdx.x >> 4;
  const int b = bh >> 3, h = bh & 7;
  const int a0 = ac * 64;
  const int tid = threadIdx.x;

  for (int idx = tid; idx < NTOP * 64; idx += 256) {
    int i = idx >> 6, e = idx & 63;
    int st = sel_ws[(bh * 2 + 0) * 64 + i];
    int sf = sel_ws[(bh * 2 + 1) * 64 + i];
    qselt[i][e]  = q_g[((size_t)(b * L_ + st) * H_ + h) * E_ + e];
    qseltf[i][e] = tfq[((size_t)(b * L_ + sf) * H_ + h) * E_ + e];
    vselt[i][e]  = v_g[((size_t)(b * L_ + st) * H_ + h) * E_ + e];
    vseltf[i][e] = v_g[((size_t)(b * L_ + sf) * H_ + h) * E_ + e];
  }
  for (int idx = tid; idx < 64 * 64; idx += 256) {
    int r = idx >> 6, e = idx & 63;
    ks[r][e] = k_g[((size_t)(b * L_ + a0 + r) * H_ + h) * E_ + e];
  }
  __syncthreads();

  const int qd = tid & 3, r = tid >> 2;
  const int a = a0 + r;
  const int eb = qd * 16;

  float ct[NTOP], ctf[NTOP];
#pragma unroll
  for (int i = 0; i < NTOP; ++i) { ct[i] = 0.f; ctf[i] = 0.f; }
  for (int j = 0; j < 16; ++j) {
    float kv = ks[r][eb + j];
#pragma unroll
    for (int i = 0; i < NTOP; ++i) {
      ct[i]  = fmaf(qselt[i][eb + j], kv, ct[i]);
      ctf[i] = fmaf(qseltf[i][eb + j], kv, ctf[i]);
    }
  }
#pragma unroll
  for (int i = 0; i < NTOP; ++i) {
    ct[i] += __shfl_xor(ct[i], 1);  ct[i] += __shfl_xor(ct[i], 2);
    ctf[i] += __shfl_xor(ctf[i], 1); ctf[i] += __shfl_xor(ctf[i], 2);
  }

  float wf0 = wfuse[(h * L_ + a) * 2 + 0];
  float wf1 = wfuse[(h * L_ + a) * 2 + 1];
  float wm = fmaxf(wf0, wf1);
  float ew0 = expf(wf0 - wm), ew1 = expf(wf1 - wm);
  float nw0 = ew0 / (ew0 + ew1), nw1 = ew1 / (ew0 + ew1);

  {
    float m = -1e30f;
#pragma unroll
    for (int i = 0; i < NTOP; ++i) { ct[i] *= SCALE_; m = fmaxf(m, ct[i]); }
    float sum = 0.f;
#pragma unroll
    for (int i = 0; i < NTOP; ++i) { ct[i] = expf(ct[i] - m); sum += ct[i]; }
    float c = 0.5f * nw0 / sum;
#pragma unroll
    for (int i = 0; i < NTOP; ++i) ct[i] *= c;
  }
  {
    float m = -1e30f;
#pragma unroll
    for (int i = 0; i < NTOP; ++i) { ctf[i] *= SCALE_; m = fmaxf(m, ctf[i]); }
    float sum = 0.f;
#pragma unroll
    for (int i = 0; i < NTOP; ++i) { ctf[i] = expf(ctf[i] - m); sum += ctf[i]; }
    float c = 0.5f * nw1 / sum;
#pragma unroll
    for (int i = 0; i < NTOP; ++i) ctf[i] *= c;
  }
  for (int j = 0; j < 16; ++j) {
    int d = eb + j;
    float acc = 0.f;
#pragma unroll
    for (int i = 0; i < NTOP; ++i) acc = fmaf(ct[i], vselt[i][d], acc);
#pragma unroll
    for (int i = 0; i < NTOP; ++i) acc = fmaf(ctf[i], vseltf[i][d], acc);
    out[((size_t)(bh * 64 + d)) * 1024 + a] = acc;
  }
}

// ---------------------------------------------------------------------------
// Kernel 5a: xqk = ctanh(q_ft^T k_ft); xqkv = xqk @ k_ft^T.
// ---------------------------------------------------------------------------
__global__ __launch_bounds__(256) void k_spec12(const float* __restrict__ qft,
                                                 const float* __restrict__ kft,
                                                 float* __restrict__ xre_g,
                                                 float* __restrict__ xim_g) {
  __shared__ float kre[64][65], kim[64][65];
  __shared__ float qre[64][8], qim[64][8];
  __shared__ float tre[8][64], tim[8][64];
  const int xc = blockIdx.x & 7;
  const int bh = blockIdx.x >> 3;
  const int tid = threadIdx.x;

  for (int idx = tid; idx < 4096; idx += 256) {
    int e = idx >> 6, y = idx & 63;
    size_t o = ((size_t)(bh * 64 + e) * 64 + y) * 2;
    kre[e][y] = kft[o]; kim[e][y] = kft[o + 1];
  }
  for (int idx = tid; idx < 512; idx += 256) {
    int e = idx >> 3, xl = idx & 7;
    size_t o = ((size_t)(bh * 64 + e) * 64 + xc * 8 + xl) * 2;
    qre[e][xl] = qft[o]; qim[e][xl] = qft[o + 1];
  }
  __syncthreads();

  const int y = tid & 63, xg = tid >> 6;
#pragma unroll
  for (int xi = 0; xi < 2; ++xi) {
    int xl = xg + xi * 4;
    float ar = 0.f, ai = 0.f;
    for (int e = 0; e < 64; ++e) {
      float a = qre[e][xl], b = qim[e][xl];
      float c = kre[e][y], d = kim[e][y];
      ar = fmaf(a, c, fmaf(-b, d, ar));
      ai = fmaf(a, d, fmaf(b, c, ai));
    }
    float trv, tiv;
    float x2 = 2.f * ar, y2 = 2.f * ai;
    if (fabsf(x2) > 30.f) {
      trv = copysignf(1.f, ar); tiv = 0.f;
    } else {
      float sh = sinhf(x2), ch = coshf(x2);
      float sn = sinf(y2), cs = cosf(y2);
      float dd = ch + cs;
      trv = sh / dd; tiv = sn / dd;
    }
    tre[xl][y] = trv; tim[xl][y] = tiv;
  }
  __syncthreads();

  const int e2 = tid & 63, xg2 = tid >> 6;
#pragma unroll
  for (int xi = 0; xi < 2; ++xi) {
    int xl = xg2 + xi * 4;
    float ar = 0.f, ai = 0.f;
    for (int yy = 0; yy < 64; ++yy) {
      float a = tre[xl][yy], b = tim[xl][yy];
      float c = kre[e2][yy], d = kim[e2][yy];
      ar = fmaf(a, c, fmaf(-b, d, ar));
      ai = fmaf(a, d, fmaf(b, c, ai));
    }
    xre_g[(size_t)bh * 4096 + (xc * 8 + xl) * 64 + e2] = ar;
    xim_g[(size_t)bh * 4096 + (xc * 8 + xl) * 64 + e2] = ai;
  }
}

// ---------------------------------------------------------------------------
// Kernel 5b: xqkvw[o][x] = (sum_e xqkv[e][x]*w1[h,e,o,x]) / 512^2.
// ---------------------------------------------------------------------------
__global__ __launch_bounds__(256) void k_w1(const float* __restrict__ xre_g,
                                            const float* __restrict__ xim_g,
                                            const float* __restrict__ w1re,
                                            const float* __restrict__ w1im,
                                            float* __restrict__ xw) {
  __shared__ float xre[64][65], xim[64][65];
  __shared__ float redr[4][512], redi[4][512];
  const int oc = blockIdx.x & 7;
  const int bh = blockIdx.x >> 3;
  const int h = bh & 7;
  const int tid = threadIdx.x;

  for (int idx = tid; idx < 4096; idx += 256) {
    int x = idx >> 6, e = idx & 63;
    xre[e][x] = xre_g[(size_t)bh * 4096 + idx];
    xim[e][x] = xim_g[(size_t)bh * 4096 + idx];
  }
  __syncthreads();

  const int x = tid & 63, g = tid >> 6;
  float accr[8], acci[8];
#pragma unroll
  for (int oo = 0; oo < 8; ++oo) { accr[oo] = 0.f; acci[oo] = 0.f; }

  for (int ee = 0; ee < 16; ++ee) {
    int e = g * 16 + ee;
    float a = xre[e][x], b = xim[e][x];
    size_t wbase = (((size_t)h * 64 + e) * 64 + oc * 8) * 64 + x;
#pragma unroll
    for (int oo = 0; oo < 8; ++oo) {
      float c = w1re[wbase + (size_t)oo * 64];
      float d = w1im[wbase + (size_t)oo * 64];
      accr[oo] = fmaf(a, c, fmaf(-b, d, accr[oo]));
      acci[oo] = fmaf(a, d, fmaf(b, c, acci[oo]));
    }
  }
#pragma unroll
  for (int oo = 0; oo < 8; ++oo) {
    redr[g][oo * 64 + x] = accr[oo];
    redi[g][oo * 64 + x] = acci[oo];
  }
  __syncthreads();

  const float INV = 1.0f / (512.0f * 512.0f);
  for (int idx = tid; idx < 512; idx += 256) {
    int oo = idx >> 6, x2 = idx & 63;
    float r = redr[0][idx] + redr[1][idx] + redr[2][idx] + redr[3][idx];
    float i = redi[0][idx] + redi[1][idx] + redi[2][idx] + redi[3][idx];
    size_t oidx = ((size_t)(bh * 64 + oc * 8 + oo) * 64 + x2) * 2;
    xw[oidx] = r * INV;
    xw[oidx + 1] = i * INV;
  }
}

// ---------------------------------------------------------------------------
// Kernel 6: 64-mode irfft, loop-inverted: one thread per t, 8 o's
// accumulated simultaneously (16 indep FMA per rotation step -> chain
// hidden; rotation chain runs once per thread, not 32x).
// Grid: (bh, o-chunk of 8, t-quarter) = 1024 blocks x 256 threads.
// out[t] += 0.5*spec (d_out already holds 0.5*attn).
// ---------------------------------------------------------------------------
__global__ __launch_bounds__(256) void k_final(const float* __restrict__ xw,
                                               float* __restrict__ out) {
  __shared__ float Xre[8][64], Xim[8][64];   // pre-scaled by 2
  const int tc = blockIdx.x & 3;
  const int oc = (blockIdx.x >> 2) & 7;
  const int bh = blockIdx.x >> 5;
  const int o0 = oc * 8;
  const int tid = threadIdx.x;

  for (int idx = tid; idx < 512; idx += 256) {
    int o = idx >> 6, m = idx & 63;
    size_t s = ((size_t)(bh * 64 + o0 + o) * 64 + m) * 2;
    Xre[o][m] = 2.f * xw[s]; Xim[o][m] = 2.f * xw[s + 1];
  }
  __syncthreads();

  const int t = tc * 256 + tid;
  const float HALF_INVN = 0.5f / 1024.0f;
  const float TWO_PI = 6.283185307179586f;
  float th = TWO_PI * (float)t * (1.0f / 1024.0f);
  float s1, c1;
  __sincosf(th, &s1, &c1);
  float cm = c1, sm = s1;

  float acc[8];
#pragma unroll
  for (int o = 0; o < 8; ++o) acc[o] = 0.5f * Xre[o][0];

  for (int m = 1; m < 64; ++m) {
#pragma unroll
    for (int o = 0; o < 8; ++o) {
      acc[o] = fmaf(Xre[o][m], cm, acc[o]);
      acc[o] = fmaf(-Xim[o][m], sm, acc[o]);
    }
    float cn = fmaf(cm, c1, -sm * s1);
    float sn = fmaf(sm, c1, cm * s1);
    cm = cn; sm = sn;
  }
#pragma unroll
  for (int o = 0; o < 8; ++o) {
    size_t oi = ((size_t)(bh * 64 + o0 + o)) * 1024 + t;
    out[oi] = fmaf(acc[o], HALF_INVN, out[oi]);
  }
}

// ---------------------------------------------------------------------------
extern "C" void kernel_launch(void* const* d_in, const int* in_sizes, int n_in,
                              void* d_out, int out_size, void* d_ws, size_t ws_size,
                              hipStream_t stream) {
  const float* tfq   = (const float*)d_in[0];
  const float* q     = (const float*)d_in[1];
  const float* k     = (const float*)d_in[2];
  const float* v     = (const float*)d_in[3];
  const float* wfuse = (const float*)d_in[5];
  const float* w1re  = (const float*)d_in[6];
  const float* w1im  = (const float*)d_in[7];
  float* out = (float*)d_out;
  float* ws  = (float*)d_ws;

  // ws layout (floats), total 1052672 (4.2 MB):
  //   region A [0..524288): amp2 (k_fft -> k_topk); REUSED afterwards as
  //     xre_g[0:131072] | xim_g[131072:262144] | xw[262144:524288]
  //   qft [524288..786432) | kft [786432..1048576)
  //   sel (int) at [1048576..1052672)
  float* amp2  = ws;
  float* xre_g = ws;
  float* xim_g = ws + 131072;
  float* xw    = ws + 262144;
  float* qft   = ws + 524288;
  float* kft   = ws + 786432;
  int*   sel   = (int*)(ws + 1048576);

  k_fft<<<512, 256, 0, stream>>>(q, k, amp2, qft, kft);
  k_topk<<<64, 256, 0, stream>>>(amp2, tfq, sel);
  k_attn<<<512, 256, 0, stream>>>(q, tfq, k, v, wfuse, sel, out);
  k_spec12<<<256, 256, 0, stream>>>(qft, kft, xre_g, xim_g);
  k_w1<<<256, 256, 0, stream>>>(xre_g, xim_g, w1re, w1im, xw);
  k_final<<<256, 256, 0, stream>>>(xw, out);
}

// Round 10
// 152.095 us; speedup vs baseline: 5.1535x; 1.1619x over previous
//
#include <hip/hip_runtime.h>
#include <math.h>

#define B_ 4
#define H_ 8
#define L_ 1024
#define E_ 64
#define NTOP 35
#define SCALE_ 0.04419417382415922f  /* 1/sqrt(512) */

// ---------------------------------------------------------------------------
// Kernel 1: FFT-based circular cross-correlation amplitude + 64-mode spectra.
// Grid: (bh, e-group of 4) = 512 blocks x 256 threads.
// ---------------------------------------------------------------------------
__global__ __launch_bounds__(256) void k_fft(const float* __restrict__ q_g,
                                             const float* __restrict__ k_g,
                                             float* __restrict__ amp2_part,
                                             float* __restrict__ qft,
                                             float* __restrict__ kft) {
  __shared__ float zre[4][1024], zim[4][1024];
  __shared__ float ctab[512], stab[512];
  const int eg = blockIdx.x & 15;
  const int bh = blockIdx.x >> 4;
  const int b = bh >> 3, h = bh & 7;
  const int tid = threadIdx.x;
  const float TWO_PI_N = 6.283185307179586f / 1024.0f;

  for (int j = tid; j < 512; j += 256) {
    float s, c;
    sincosf(TWO_PI_N * (float)j, &s, &c);
    ctab[j] = c; stab[j] = s;     // W^j = c - i*s
  }
  for (int t = tid; t < 1024; t += 256) {
    size_t g4 = ((size_t)(b * L_ + t) * H_ + h) * 16 + eg;
    float4 qv = reinterpret_cast<const float4*>(q_g)[g4];
    float4 kv = reinterpret_cast<const float4*>(k_g)[g4];
    zre[0][t] = qv.x; zre[1][t] = qv.y; zre[2][t] = qv.z; zre[3][t] = qv.w;
    zim[0][t] = kv.x; zim[1][t] = kv.y; zim[2][t] = kv.z; zim[3][t] = kv.w;
  }
  __syncthreads();

  // ---- forward DIF: 4 FFTs x 512 butterflies = 2048/stage, 8 per thread
  for (int s = 0; s < 10; ++s) {
    const int half = 512 >> s;
#pragma unroll
    for (int it = 0; it < 8; ++it) {
      int idx = tid + it * 256;
      int ee = idx >> 9;
      int bf = idx & 511;
      int j = bf & (half - 1);
      int p0 = ((bf >> (9 - s)) << (10 - s)) + j;
      int p1 = p0 + half;
      float ur = zre[ee][p0], ui = zim[ee][p0];
      float vr = zre[ee][p1], vi = zim[ee][p1];
      float dr = ur - vr, di = ui - vi;
      zre[ee][p0] = ur + vr; zim[ee][p0] = ui + vi;
      int twi = j << s;
      float c = ctab[twi], sn = stab[twi];
      zre[ee][p1] = fmaf(dr, c, di * sn);
      zim[ee][p1] = fmaf(di, c, -dr * sn);
    }
    __syncthreads();
  }

  // ---- Hermitian unpack + P = Fq*conj(Fk); dump modes 0..63 to qft/kft.
  float pr[16], pi_[16];
#pragma unroll
  for (int it = 0; it < 16; ++it) {
    int idx = tid + it * 256;
    int ee = idx >> 10;
    int p = idx & 1023;
    int m = __brev((unsigned)p) >> 22;
    int mp = (1024 - m) & 1023;
    int pp = __brev((unsigned)mp) >> 22;
    float ar = zre[ee][p], ai = zim[ee][p];
    float br = zre[ee][pp], bi = zim[ee][pp];
    float qr = 0.5f * (ar + br), qi = 0.5f * (ai - bi);
    float kr = 0.5f * (ai + bi), ki = -0.5f * (ar - br);
    pr[it]  = fmaf(qr, kr, qi * ki);
    pi_[it] = fmaf(qi, kr, -qr * ki);
    if (m < 64) {
      size_t o = ((size_t)(bh * 64 + eg * 4 + ee) * 64 + m) * 2;
      qft[o] = qr; qft[o + 1] = qi;
      kft[o] = kr; kft[o + 1] = ki;
    }
  }
  __syncthreads();
#pragma unroll
  for (int it = 0; it < 16; ++it) {
    int idx = tid + it * 256;
    int ee = idx >> 10;
    int p = idx & 1023;
    zre[ee][p] = pr[it]; zim[ee][p] = pi_[it];
  }
  __syncthreads();

  // ---- pair-mix: slot 2u := P_{2u} + i*P_{2u+1}
  for (int idx = tid; idx < 2048; idx += 256) {
    int u = idx >> 10;
    int p = idx & 1023;
    int e0 = 2 * u, e1 = 2 * u + 1;
    float s_r = zre[e0][p] - zim[e1][p];
    float s_i = zim[e0][p] + zre[e1][p];
    zre[e0][p] = s_r; zim[e0][p] = s_i;
  }
  __syncthreads();

  // ---- inverse DIT on slots 0,2
  for (int s = 9; s >= 0; --s) {
    const int half = 512 >> s;
#pragma unroll
    for (int it = 0; it < 4; ++it) {
      int idx = tid + it * 256;
      int ee = (idx >> 9) * 2;
      int bf = idx & 511;
      int j = bf & (half - 1);
      int p0 = ((bf >> (9 - s)) << (10 - s)) + j;
      int p1 = p0 + half;
      int twi = j << s;
      float c = ctab[twi], sn = stab[twi];
      float ur = zre[ee][p0], ui = zim[ee][p0];
      float wr = zre[ee][p1], wi = zim[ee][p1];
      float vr = fmaf(wr, c, -wi * sn);
      float vi = fmaf(wi, c, wr * sn);
      zre[ee][p0] = ur + vr; zim[ee][p0] = ui + vi;
      zre[ee][p1] = ur - vr; zim[ee][p1] = ui - vi;
    }
    __syncthreads();
  }

  // ---- amp2
  for (int t = tid; t < 1024; t += 256) {
    float r0 = zre[0][t], i0 = zim[0][t];
    float r2 = zre[2][t], i2 = zim[2][t];
    amp2_part[(size_t)(bh * 16 + eg) * 1024 + t] =
        fmaf(r0, r0, fmaf(i0, i0, fmaf(r2, r2, i2 * i2)));
  }
}

// ---------------------------------------------------------------------------
// Kernel 2: top-35 selection per (b,h,src).
// ---------------------------------------------------------------------------
__global__ __launch_bounds__(256) void k_topk(const float* __restrict__ amp2_part,
                                              const float* __restrict__ tfq,
                                              int* __restrict__ sel_ws) {
  __shared__ float amp[1024];
  __shared__ float wv_s[4];
  __shared__ int wi_s[4];
  __shared__ int winner_s;
  const int src = blockIdx.x & 1;
  const int bh = blockIdx.x >> 1;
  const int b = bh >> 3, h = bh & 7;
  const int tid = threadIdx.x;

  if (src == 0) {
    for (int t = tid; t < 1024; t += 256) {
      float s = 0.f;
#pragma unroll
      for (int c = 0; c < 16; ++c) s += amp2_part[(size_t)(bh * 16 + c) * 1024 + t];
      amp[t] = s;
    }
  } else {
    for (int l = tid; l < 1024; l += 256) {
      const float4* p4 = reinterpret_cast<const float4*>(
          &tfq[((size_t)(b * L_ + l) * H_ + h) * E_]);
      float s = 0.f;
#pragma unroll
      for (int e4 = 0; e4 < 16; ++e4) {
        float4 v = p4[e4];
        s += v.x * v.x + v.y * v.y + v.z * v.z + v.w * v.w;
      }
      amp[l] = s;
    }
  }
  __syncthreads();

  float bv = -1.f; int bi = tid;
#pragma unroll
  for (int kk = 0; kk < 4; ++kk) {
    int t = tid + kk * 256;
    float v = amp[t];
    if (v > bv) { bv = v; bi = t; }
  }
  const int lane = tid & 63, w = tid >> 6;

  for (int it = 0; it < NTOP; ++it) {
    float v = bv; int i = bi;
#pragma unroll
    for (int d = 1; d < 64; d <<= 1) {
      float ov = __shfl_xor(v, d);
      int oi = __shfl_xor(i, d);
      if (ov > v || (ov == v && oi < i)) { v = ov; i = oi; }
    }
    if (lane == 0) { wv_s[w] = v; wi_s[w] = i; }
    __syncthreads();
    if (tid == 0) {
      float fv = wv_s[0]; int fi = wi_s[0];
#pragma unroll
      for (int j = 1; j < 4; ++j) {
        if (wv_s[j] > fv || (wv_s[j] == fv && wi_s[j] < fi)) { fv = wv_s[j]; fi = wi_s[j]; }
      }
      winner_s = fi;
      sel_ws[(bh * 2 + src) * 64 + it] = fi;
    }
    __syncthreads();
    int fi = winner_s;
    if ((fi & 255) == tid) {
      amp[fi] = -1.f;
      bv = -1.f; bi = tid;
#pragma unroll
      for (int kk = 0; kk < 4; ++kk) {
        int t = tid + kk * 256;
        float vv = amp[t];
        if (vv > bv) { bv = vv; bi = t; }
      }
    }
  }
}

// ---------------------------------------------------------------------------
// Kernel 3: scores over selected rows -> two softmaxes -> fuse -> times V.
// Grid: (bh, a-chunk of 64) = 512 blocks x 256 threads.
// Thread = (row r = tid>>2, quarter qd = tid&3). q/v staged as float4 LDS
// (b128 reads, 8 FMA per read); K rows loaded straight to registers (64B/thr)
// so LDS stays at 35KB -> 4 blocks/CU.
// ---------------------------------------------------------------------------
__global__ __launch_bounds__(256) void k_attn(const float* __restrict__ q_g,
                                              const float* __restrict__ tfq,
                                              const float* __restrict__ k_g,
                                              const float* __restrict__ v_g,
                                              const float* __restrict__ wfuse,
                                              const int* __restrict__ sel_ws,
                                              float* __restrict__ out) {
  __shared__ float4 qs4[2][NTOP][16];   // [src][i][e4]
  __shared__ float4 vs4[2][NTOP][16];
  const int ac = blockIdx.x & 15;
  const int bh = blockIdx.x >> 4;
  const int b = bh >> 3, h = bh & 7;
  const int a0 = ac * 64;
  const int tid = threadIdx.x;

  for (int idx = tid; idx < 2 * NTOP * 16; idx += 256) {
    int src = idx / (NTOP * 16);
    int rem = idx - src * (NTOP * 16);
    int i = rem >> 4, e4 = rem & 15;
    int row = sel_ws[(bh * 2 + src) * 64 + i];
    size_t rb = ((size_t)(b * L_ + row) * H_ + h) * E_;
    const float* qbase = src ? tfq : q_g;
    qs4[src][i][e4] = reinterpret_cast<const float4*>(qbase + rb)[e4];
    vs4[src][i][e4] = reinterpret_cast<const float4*>(v_g + rb)[e4];
  }
  __syncthreads();

  const int qd = tid & 3, r = tid >> 2;
  const int a = a0 + r;
  const int eb = qd * 16;

  // K row segment straight to registers (16 floats = this quarter's e-range)
  size_t krb = ((size_t)(b * L_ + a) * H_ + h) * E_;
  const float4* k4p = reinterpret_cast<const float4*>(k_g + krb);
  float4 kq[4];
#pragma unroll
  for (int j4 = 0; j4 < 4; ++j4) kq[j4] = k4p[qd * 4 + j4];

  float ct[NTOP], ctf[NTOP];
#pragma unroll
  for (int i = 0; i < NTOP; ++i) { ct[i] = 0.f; ctf[i] = 0.f; }

#pragma unroll
  for (int j4 = 0; j4 < 4; ++j4) {
    float4 kv = kq[j4];
#pragma unroll
    for (int i = 0; i < NTOP; ++i) {
      float4 q4 = qs4[0][i][qd * 4 + j4];
      ct[i] = fmaf(q4.x, kv.x, ct[i]); ct[i] = fmaf(q4.y, kv.y, ct[i]);
      ct[i] = fmaf(q4.z, kv.z, ct[i]); ct[i] = fmaf(q4.w, kv.w, ct[i]);
      float4 p4 = qs4[1][i][qd * 4 + j4];
      ctf[i] = fmaf(p4.x, kv.x, ctf[i]); ctf[i] = fmaf(p4.y, kv.y, ctf[i]);
      ctf[i] = fmaf(p4.z, kv.z, ctf[i]); ctf[i] = fmaf(p4.w, kv.w, ctf[i]);
    }
  }
  // combine quarters (lanes 4r..4r+3 are in the same wave)
#pragma unroll
  for (int i = 0; i < NTOP; ++i) {
    ct[i] += __shfl_xor(ct[i], 1);  ct[i] += __shfl_xor(ct[i], 2);
    ctf[i] += __shfl_xor(ctf[i], 1); ctf[i] += __shfl_xor(ctf[i], 2);
  }

  float wf0 = wfuse[(h * L_ + a) * 2 + 0];
  float wf1 = wfuse[(h * L_ + a) * 2 + 1];
  float wm = fmaxf(wf0, wf1);
  float ew0 = expf(wf0 - wm), ew1 = expf(wf1 - wm);
  float nw0 = ew0 / (ew0 + ew1), nw1 = ew1 / (ew0 + ew1);

  {
    float m = -1e30f;
#pragma unroll
    for (int i = 0; i < NTOP; ++i) { ct[i] *= SCALE_; m = fmaxf(m, ct[i]); }
    float sum = 0.f;
#pragma unroll
    for (int i = 0; i < NTOP; ++i) { ct[i] = expf(ct[i] - m); sum += ct[i]; }
    float c = 0.5f * nw0 / sum;
#pragma unroll
    for (int i = 0; i < NTOP; ++i) ct[i] *= c;
  }
  {
    float m = -1e30f;
#pragma unroll
    for (int i = 0; i < NTOP; ++i) { ctf[i] *= SCALE_; m = fmaxf(m, ctf[i]); }
    float sum = 0.f;
#pragma unroll
    for (int i = 0; i < NTOP; ++i) { ctf[i] = expf(ctf[i] - m); sum += ctf[i]; }
    float c = 0.5f * nw1 / sum;
#pragma unroll
    for (int i = 0; i < NTOP; ++i) ctf[i] *= c;
  }
  // output: d = eb + j4*4 + {0..3}; accumulation order i(ct) then i(ctf)
#pragma unroll
  for (int j4 = 0; j4 < 4; ++j4) {
    float ax = 0.f, ay = 0.f, az = 0.f, aw = 0.f;
#pragma unroll
    for (int i = 0; i < NTOP; ++i) {
      float4 v4 = vs4[0][i][qd * 4 + j4];
      ax = fmaf(ct[i], v4.x, ax); ay = fmaf(ct[i], v4.y, ay);
      az = fmaf(ct[i], v4.z, az); aw = fmaf(ct[i], v4.w, aw);
    }
#pragma unroll
    for (int i = 0; i < NTOP; ++i) {
      float4 v4 = vs4[1][i][qd * 4 + j4];
      ax = fmaf(ctf[i], v4.x, ax); ay = fmaf(ctf[i], v4.y, ay);
      az = fmaf(ctf[i], v4.z, az); aw = fmaf(ctf[i], v4.w, aw);
    }
    int d = eb + j4 * 4;
    out[((size_t)(bh * 64 + d + 0)) * 1024 + a] = ax;
    out[((size_t)(bh * 64 + d + 1)) * 1024 + a] = ay;
    out[((size_t)(bh * 64 + d + 2)) * 1024 + a] = az;
    out[((size_t)(bh * 64 + d + 3)) * 1024 + a] = aw;
  }
}

// ---------------------------------------------------------------------------
// Kernel 5a: xqk = ctanh(q_ft^T k_ft); xqkv = xqk @ k_ft^T.
// ---------------------------------------------------------------------------
__global__ __launch_bounds__(256) void k_spec12(const float* __restrict__ qft,
                                                 const float* __restrict__ kft,
                                                 float* __restrict__ xre_g,
                                                 float* __restrict__ xim_g) {
  __shared__ float kre[64][65], kim[64][65];
  __shared__ float qre[64][8], qim[64][8];
  __shared__ float tre[8][64], tim[8][64];
  const int xc = blockIdx.x & 7;
  const int bh = blockIdx.x >> 3;
  const int tid = threadIdx.x;

  for (int idx = tid; idx < 4096; idx += 256) {
    int e = idx >> 6, y = idx & 63;
    size_t o = ((size_t)(bh * 64 + e) * 64 + y) * 2;
    kre[e][y] = kft[o]; kim[e][y] = kft[o + 1];
  }
  for (int idx = tid; idx < 512; idx += 256) {
    int e = idx >> 3, xl = idx & 7;
    size_t o = ((size_t)(bh * 64 + e) * 64 + xc * 8 + xl) * 2;
    qre[e][xl] = qft[o]; qim[e][xl] = qft[o + 1];
  }
  __syncthreads();

  const int y = tid & 63, xg = tid >> 6;
#pragma unroll
  for (int xi = 0; xi < 2; ++xi) {
    int xl = xg + xi * 4;
    float ar = 0.f, ai = 0.f;
    for (int e = 0; e < 64; ++e) {
      float a = qre[e][xl], b = qim[e][xl];
      float c = kre[e][y], d = kim[e][y];
      ar = fmaf(a, c, fmaf(-b, d, ar));
      ai = fmaf(a, d, fmaf(b, c, ai));
    }
    float trv, tiv;
    float x2 = 2.f * ar, y2 = 2.f * ai;
    if (fabsf(x2) > 30.f) {
      trv = copysignf(1.f, ar); tiv = 0.f;
    } else {
      float sh = sinhf(x2), ch = coshf(x2);
      float sn = sinf(y2), cs = cosf(y2);
      float dd = ch + cs;
      trv = sh / dd; tiv = sn / dd;
    }
    tre[xl][y] = trv; tim[xl][y] = tiv;
  }
  __syncthreads();

  const int e2 = tid & 63, xg2 = tid >> 6;
#pragma unroll
  for (int xi = 0; xi < 2; ++xi) {
    int xl = xg2 + xi * 4;
    float ar = 0.f, ai = 0.f;
    for (int yy = 0; yy < 64; ++yy) {
      float a = tre[xl][yy], b = tim[xl][yy];
      float c = kre[e2][yy], d = kim[e2][yy];
      ar = fmaf(a, c, fmaf(-b, d, ar));
      ai = fmaf(a, d, fmaf(b, c, ai));
    }
    xre_g[(size_t)bh * 4096 + (xc * 8 + xl) * 64 + e2] = ar;
    xim_g[(size_t)bh * 4096 + (xc * 8 + xl) * 64 + e2] = ai;
  }
}

// ---------------------------------------------------------------------------
// Kernel 5b: xqkvw[o][x] = (sum_e xqkv[e][x]*w1[h,e,o,x]) / 512^2.
// ---------------------------------------------------------------------------
__global__ __launch_bounds__(256) void k_w1(const float* __restrict__ xre_g,
                                            const float* __restrict__ xim_g,
                                            const float* __restrict__ w1re,
                                            const float* __restrict__ w1im,
                                            float* __restrict__ xw) {
  __shared__ float xre[64][65], xim[64][65];
  __shared__ float redr[4][512], redi[4][512];
  const int oc = blockIdx.x & 7;
  const int bh = blockIdx.x >> 3;
  const int h = bh & 7;
  const int tid = threadIdx.x;

  for (int idx = tid; idx < 4096; idx += 256) {
    int x = idx >> 6, e = idx & 63;
    xre[e][x] = xre_g[(size_t)bh * 4096 + idx];
    xim[e][x] = xim_g[(size_t)bh * 4096 + idx];
  }
  __syncthreads();

  const int x = tid & 63, g = tid >> 6;
  float accr[8], acci[8];
#pragma unroll
  for (int oo = 0; oo < 8; ++oo) { accr[oo] = 0.f; acci[oo] = 0.f; }

  for (int ee = 0; ee < 16; ++ee) {
    int e = g * 16 + ee;
    float a = xre[e][x], b = xim[e][x];
    size_t wbase = (((size_t)h * 64 + e) * 64 + oc * 8) * 64 + x;
#pragma unroll
    for (int oo = 0; oo < 8; ++oo) {
      float c = w1re[wbase + (size_t)oo * 64];
      float d = w1im[wbase + (size_t)oo * 64];
      accr[oo] = fmaf(a, c, fmaf(-b, d, accr[oo]));
      acci[oo] = fmaf(a, d, fmaf(b, c, acci[oo]));
    }
  }
#pragma unroll
  for (int oo = 0; oo < 8; ++oo) {
    redr[g][oo * 64 + x] = accr[oo];
    redi[g][oo * 64 + x] = acci[oo];
  }
  __syncthreads();

  const float INV = 1.0f / (512.0f * 512.0f);
  for (int idx = tid; idx < 512; idx += 256) {
    int oo = idx >> 6, x2 = idx & 63;
    float r = redr[0][idx] + redr[1][idx] + redr[2][idx] + redr[3][idx];
    float i = redi[0][idx] + redi[1][idx] + redi[2][idx] + redi[3][idx];
    size_t oidx = ((size_t)(bh * 64 + oc * 8 + oo) * 64 + x2) * 2;
    xw[oidx] = r * INV;
    xw[oidx + 1] = i * INV;
  }
}

// ---------------------------------------------------------------------------
// Kernel 6: 64-mode irfft, loop-inverted (thread per t, 8 o's at once).
// Grid: (bh, o-chunk of 8, t-quarter) = 1024 blocks x 256 threads.
// ---------------------------------------------------------------------------
__global__ __launch_bounds__(256) void k_final(const float* __restrict__ xw,
                                               float* __restrict__ out) {
  __shared__ float Xre[8][64], Xim[8][64];   // pre-scaled by 2
  const int tc = blockIdx.x & 3;
  const int oc = (blockIdx.x >> 2) & 7;
  const int bh = blockIdx.x >> 5;
  const int o0 = oc * 8;
  const int tid = threadIdx.x;

  for (int idx = tid; idx < 512; idx += 256) {
    int o = idx >> 6, m = idx & 63;
    size_t s = ((size_t)(bh * 64 + o0 + o) * 64 + m) * 2;
    Xre[o][m] = 2.f * xw[s]; Xim[o][m] = 2.f * xw[s + 1];
  }
  __syncthreads();

  const int t = tc * 256 + tid;
  const float HALF_INVN = 0.5f / 1024.0f;
  const float TWO_PI = 6.283185307179586f;
  float th = TWO_PI * (float)t * (1.0f / 1024.0f);
  float s1, c1;
  __sincosf(th, &s1, &c1);
  float cm = c1, sm = s1;

  float acc[8];
#pragma unroll
  for (int o = 0; o < 8; ++o) acc[o] = 0.5f * Xre[o][0];

  for (int m = 1; m < 64; ++m) {
#pragma unroll
    for (int o = 0; o < 8; ++o) {
      acc[o] = fmaf(Xre[o][m], cm, acc[o]);
      acc[o] = fmaf(-Xim[o][m], sm, acc[o]);
    }
    float cn = fmaf(cm, c1, -sm * s1);
    float sn = fmaf(sm, c1, cm * s1);
    cm = cn; sm = sn;
  }
#pragma unroll
  for (int o = 0; o < 8; ++o) {
    size_t oi = ((size_t)(bh * 64 + o0 + o)) * 1024 + t;
    out[oi] = fmaf(acc[o], HALF_INVN, out[oi]);
  }
}

// ---------------------------------------------------------------------------
extern "C" void kernel_launch(void* const* d_in, const int* in_sizes, int n_in,
                              void* d_out, int out_size, void* d_ws, size_t ws_size,
                              hipStream_t stream) {
  const float* tfq   = (const float*)d_in[0];
  const float* q     = (const float*)d_in[1];
  const float* k     = (const float*)d_in[2];
  const float* v     = (const float*)d_in[3];
  const float* wfuse = (const float*)d_in[5];
  const float* w1re  = (const float*)d_in[6];
  const float* w1im  = (const float*)d_in[7];
  float* out = (float*)d_out;
  float* ws  = (float*)d_ws;

  // ws layout (floats), total 1052672 (4.2 MB):
  //   region A [0..524288): amp2 (k_fft -> k_topk); REUSED afterwards as
  //     xre_g[0:131072] | xim_g[131072:262144] | xw[262144:524288]
  //   qft [524288..786432) | kft [786432..1048576)
  //   sel (int) at [1048576..1052672)
  float* amp2  = ws;
  float* xre_g = ws;
  float* xim_g = ws + 131072;
  float* xw    = ws + 262144;
  float* qft   = ws + 524288;
  float* kft   = ws + 786432;
  int*   sel   = (int*)(ws + 1048576);

  k_fft<<<512, 256, 0, stream>>>(q, k, amp2, qft, kft);
  k_topk<<<64, 256, 0, stream>>>(amp2, tfq, sel);
  k_attn<<<512, 256, 0, stream>>>(q, tfq, k, v, wfuse, sel, out);
  k_spec12<<<256, 256, 0, stream>>>(qft, kft, xre_g, xim_g);
  k_w1<<<256, 256, 0, stream>>>(xre_g, xim_g, w1re, w1im, xw);
  k_final<<<256, 256, 0, stream>>>(xw, out);
}

// Round 11
// 142.435 us; speedup vs baseline: 5.5031x; 1.0678x over previous
//
#include <hip/hip_runtime.h>
#include <math.h>

#define B_ 4
#define H_ 8
#define L_ 1024
#define E_ 64
#define NTOP 35
#define SCALE_ 0.04419417382415922f  /* 1/sqrt(512) */

// ---------------------------------------------------------------------------
// Kernel 0: transpose staging  x[b][t][h][e] -> xt[bh][e][t]  (q and k).
// Grid: (t-chunk of 64, src, bh) = 1024 blocks x 256 threads. LDS 64x65 tile;
// reads and writes both use full cache lines (256B contiguous segments).
// ---------------------------------------------------------------------------
__global__ __launch_bounds__(256) void k_stage(const float* __restrict__ q_g,
                                               const float* __restrict__ k_g,
                                               float* __restrict__ xtq,
                                               float* __restrict__ xtk) {
  __shared__ float tile[64][65];
  const int tc = blockIdx.x & 15;
  const int src = (blockIdx.x >> 4) & 1;
  const int bh = blockIdx.x >> 5;
  const int b = bh >> 3, h = bh & 7;
  const int t0 = tc * 64;
  const int tid = threadIdx.x;
  const float* in = src ? k_g : q_g;
  float* out = src ? xtk : xtq;

  for (int idx = tid; idx < 1024; idx += 256) {
    int t = idx >> 4, e4 = idx & 15;
    float4 v = reinterpret_cast<const float4*>(
        in + ((size_t)(b * L_ + t0 + t) * H_ + h) * E_)[e4];
    tile[t][e4 * 4 + 0] = v.x; tile[t][e4 * 4 + 1] = v.y;
    tile[t][e4 * 4 + 2] = v.z; tile[t][e4 * 4 + 3] = v.w;
  }
  __syncthreads();
  for (int idx = tid; idx < 1024; idx += 256) {
    int e = idx >> 4, t4 = idx & 15;
    float4 v = make_float4(tile[t4 * 4 + 0][e], tile[t4 * 4 + 1][e],
                           tile[t4 * 4 + 2][e], tile[t4 * 4 + 3][e]);
    reinterpret_cast<float4*>(out + ((size_t)(bh * 64 + e)) * 1024 + t0)[t4] = v;
  }
}

// ---------------------------------------------------------------------------
// Kernel 1 (coalesced variant): FFT-based circular cross-correlation
// amplitude + 64-mode spectra, reading transposed planes.
// Grid: (bh, e-group of 4) = 512 blocks x 512 threads.
// ---------------------------------------------------------------------------
__global__ __launch_bounds__(512) void k_fft_c(const float* __restrict__ xtq,
                                               const float* __restrict__ xtk,
                                               float* __restrict__ amp2_part,
                                               float* __restrict__ qft,
                                               float* __restrict__ kft) {
  __shared__ __align__(16) float zre[4][1024], zim[4][1024];
  __shared__ float ctab[512], stab[512];
  const int eg = blockIdx.x & 15;
  const int bh = blockIdx.x >> 4;
  const int tid = threadIdx.x;
  const float TWO_PI_N = 6.283185307179586f / 1024.0f;

  if (tid < 512) {
    float s, c;
    sincosf(TWO_PI_N * (float)tid, &s, &c);
    ctab[tid] = c; stab[tid] = s;     // W^j = c - i*s
  }
  // coalesced loads: 4 e-rows x 256 float4 per array
  for (int idx = tid; idx < 1024; idx += 512) {
    int ee = idx >> 8, t4 = idx & 255;
    size_t ro = ((size_t)(bh * 64 + eg * 4 + ee)) * 1024;
    float4 qv = reinterpret_cast<const float4*>(xtq + ro)[t4];
    float4 kv = reinterpret_cast<const float4*>(xtk + ro)[t4];
    *reinterpret_cast<float4*>(&zre[ee][t4 * 4]) = qv;
    *reinterpret_cast<float4*>(&zim[ee][t4 * 4]) = kv;
  }
  __syncthreads();

  // ---- forward DIF: 2048 butterflies/stage, 4 per thread
  for (int s = 0; s < 10; ++s) {
    const int half = 512 >> s;
#pragma unroll
    for (int it = 0; it < 4; ++it) {
      int idx = tid + it * 512;
      int ee = idx >> 9;
      int bf = idx & 511;
      int j = bf & (half - 1);
      int p0 = ((bf >> (9 - s)) << (10 - s)) + j;
      int p1 = p0 + half;
      float ur = zre[ee][p0], ui = zim[ee][p0];
      float vr = zre[ee][p1], vi = zim[ee][p1];
      float dr = ur - vr, di = ui - vi;
      zre[ee][p0] = ur + vr; zim[ee][p0] = ui + vi;
      int twi = j << s;
      float c = ctab[twi], sn = stab[twi];
      zre[ee][p1] = fmaf(dr, c, di * sn);
      zim[ee][p1] = fmaf(di, c, -dr * sn);
    }
    __syncthreads();
  }

  // ---- Hermitian unpack + P = Fq*conj(Fk); dump modes 0..63.
  float pr[8], pi_[8];
#pragma unroll
  for (int it = 0; it < 8; ++it) {
    int idx = tid + it * 512;
    int ee = idx >> 10;
    int p = idx & 1023;
    int m = __brev((unsigned)p) >> 22;
    int mp = (1024 - m) & 1023;
    int pp = __brev((unsigned)mp) >> 22;
    float ar = zre[ee][p], ai = zim[ee][p];
    float br = zre[ee][pp], bi = zim[ee][pp];
    float qr = 0.5f * (ar + br), qi = 0.5f * (ai - bi);
    float kr = 0.5f * (ai + bi), ki = -0.5f * (ar - br);
    pr[it]  = fmaf(qr, kr, qi * ki);
    pi_[it] = fmaf(qi, kr, -qr * ki);
    if (m < 64) {
      size_t o = ((size_t)(bh * 64 + eg * 4 + ee) * 64 + m) * 2;
      qft[o] = qr; qft[o + 1] = qi;
      kft[o] = kr; kft[o + 1] = ki;
    }
  }
  __syncthreads();
#pragma unroll
  for (int it = 0; it < 8; ++it) {
    int idx = tid + it * 512;
    int ee = idx >> 10;
    int p = idx & 1023;
    zre[ee][p] = pr[it]; zim[ee][p] = pi_[it];
  }
  __syncthreads();

  // ---- pair-mix: slot 2u := P_{2u} + i*P_{2u+1}
  for (int idx = tid; idx < 2048; idx += 512) {
    int u = idx >> 10;
    int p = idx & 1023;
    int e0 = 2 * u, e1 = 2 * u + 1;
    float s_r = zre[e0][p] - zim[e1][p];
    float s_i = zim[e0][p] + zre[e1][p];
    zre[e0][p] = s_r; zim[e0][p] = s_i;
  }
  __syncthreads();

  // ---- inverse DIT on slots 0,2: 1024 butterflies/stage, 2 per thread
  for (int s = 9; s >= 0; --s) {
    const int half = 512 >> s;
#pragma unroll
    for (int it = 0; it < 2; ++it) {
      int idx = tid + it * 512;
      int ee = (idx >> 9) * 2;
      int bf = idx & 511;
      int j = bf & (half - 1);
      int p0 = ((bf >> (9 - s)) << (10 - s)) + j;
      int p1 = p0 + half;
      int twi = j << s;
      float c = ctab[twi], sn = stab[twi];
      float ur = zre[ee][p0], ui = zim[ee][p0];
      float wr = zre[ee][p1], wi = zim[ee][p1];
      float vr = fmaf(wr, c, -wi * sn);
      float vi = fmaf(wi, c, wr * sn);
      zre[ee][p0] = ur + vr; zim[ee][p0] = ui + vi;
      zre[ee][p1] = ur - vr; zim[ee][p1] = ui - vi;
    }
    __syncthreads();
  }

  // ---- amp2
  for (int t = tid; t < 1024; t += 512) {
    float r0 = zre[0][t], i0 = zim[0][t];
    float r2 = zre[2][t], i2 = zim[2][t];
    amp2_part[(size_t)(bh * 16 + eg) * 1024 + t] =
        fmaf(r0, r0, fmaf(i0, i0, fmaf(r2, r2, i2 * i2)));
  }
}

// ---------------------------------------------------------------------------
// Kernel 1 (strided fallback, identical to R9): used when ws is too small
// for the transposed staging planes.
// ---------------------------------------------------------------------------
__global__ __launch_bounds__(256) void k_fft_s(const float* __restrict__ q_g,
                                               const float* __restrict__ k_g,
                                               float* __restrict__ amp2_part,
                                               float* __restrict__ qft,
                                               float* __restrict__ kft) {
  __shared__ float zre[4][1024], zim[4][1024];
  __shared__ float ctab[512], stab[512];
  const int eg = blockIdx.x & 15;
  const int bh = blockIdx.x >> 4;
  const int b = bh >> 3, h = bh & 7;
  const int tid = threadIdx.x;
  const float TWO_PI_N = 6.283185307179586f / 1024.0f;

  for (int j = tid; j < 512; j += 256) {
    float s, c;
    sincosf(TWO_PI_N * (float)j, &s, &c);
    ctab[j] = c; stab[j] = s;
  }
  for (int t = tid; t < 1024; t += 256) {
    size_t g4 = ((size_t)(b * L_ + t) * H_ + h) * 16 + eg;
    float4 qv = reinterpret_cast<const float4*>(q_g)[g4];
    float4 kv = reinterpret_cast<const float4*>(k_g)[g4];
    zre[0][t] = qv.x; zre[1][t] = qv.y; zre[2][t] = qv.z; zre[3][t] = qv.w;
    zim[0][t] = kv.x; zim[1][t] = kv.y; zim[2][t] = kv.z; zim[3][t] = kv.w;
  }
  __syncthreads();

  for (int s = 0; s < 10; ++s) {
    const int half = 512 >> s;
#pragma unroll
    for (int it = 0; it < 8; ++it) {
      int idx = tid + it * 256;
      int ee = idx >> 9;
      int bf = idx & 511;
      int j = bf & (half - 1);
      int p0 = ((bf >> (9 - s)) << (10 - s)) + j;
      int p1 = p0 + half;
      float ur = zre[ee][p0], ui = zim[ee][p0];
      float vr = zre[ee][p1], vi = zim[ee][p1];
      float dr = ur - vr, di = ui - vi;
      zre[ee][p0] = ur + vr; zim[ee][p0] = ui + vi;
      int twi = j << s;
      float c = ctab[twi], sn = stab[twi];
      zre[ee][p1] = fmaf(dr, c, di * sn);
      zim[ee][p1] = fmaf(di, c, -dr * sn);
    }
    __syncthreads();
  }

  float pr[16], pi_[16];
#pragma unroll
  for (int it = 0; it < 16; ++it) {
    int idx = tid + it * 256;
    int ee = idx >> 10;
    int p = idx & 1023;
    int m = __brev((unsigned)p) >> 22;
    int mp = (1024 - m) & 1023;
    int pp = __brev((unsigned)mp) >> 22;
    float ar = zre[ee][p], ai = zim[ee][p];
    float br = zre[ee][pp], bi = zim[ee][pp];
    float qr = 0.5f * (ar + br), qi = 0.5f * (ai - bi);
    float kr = 0.5f * (ai + bi), ki = -0.5f * (ar - br);
    pr[it]  = fmaf(qr, kr, qi * ki);
    pi_[it] = fmaf(qi, kr, -qr * ki);
    if (m < 64) {
      size_t o = ((size_t)(bh * 64 + eg * 4 + ee) * 64 + m) * 2;
      qft[o] = qr; qft[o + 1] = qi;
      kft[o] = kr; kft[o + 1] = ki;
    }
  }
  __syncthreads();
#pragma unroll
  for (int it = 0; it < 16; ++it) {
    int idx = tid + it * 256;
    int ee = idx >> 10;
    int p = idx & 1023;
    zre[ee][p] = pr[it]; zim[ee][p] = pi_[it];
  }
  __syncthreads();

  for (int idx = tid; idx < 2048; idx += 256) {
    int u = idx >> 10;
    int p = idx & 1023;
    int e0 = 2 * u, e1 = 2 * u + 1;
    float s_r = zre[e0][p] - zim[e1][p];
    float s_i = zim[e0][p] + zre[e1][p];
    zre[e0][p] = s_r; zim[e0][p] = s_i;
  }
  __syncthreads();

  for (int s = 9; s >= 0; --s) {
    const int half = 512 >> s;
#pragma unroll
    for (int it = 0; it < 4; ++it) {
      int idx = tid + it * 256;
      int ee = (idx >> 9) * 2;
      int bf = idx & 511;
      int j = bf & (half - 1);
      int p0 = ((bf >> (9 - s)) << (10 - s)) + j;
      int p1 = p0 + half;
      int twi = j << s;
      float c = ctab[twi], sn = stab[twi];
      float ur = zre[ee][p0], ui = zim[ee][p0];
      float wr = zre[ee][p1], wi = zim[ee][p1];
      float vr = fmaf(wr, c, -wi * sn);
      float vi = fmaf(wi, c, wr * sn);
      zre[ee][p0] = ur + vr; zim[ee][p0] = ui + vi;
      zre[ee][p1] = ur - vr; zim[ee][p1] = ui - vi;
    }
    __syncthreads();
  }

  for (int t = tid; t < 1024; t += 256) {
    float r0 = zre[0][t], i0 = zim[0][t];
    float r2 = zre[2][t], i2 = zim[2][t];
    amp2_part[(size_t)(bh * 16 + eg) * 1024 + t] =
        fmaf(r0, r0, fmaf(i0, i0, fmaf(r2, r2, i2 * i2)));
  }
}

// ---------------------------------------------------------------------------
// Kernel 2: top-35 selection per (b,h,src).
// ---------------------------------------------------------------------------
__global__ __launch_bounds__(256) void k_topk(const float* __restrict__ amp2_part,
                                              const float* __restrict__ tfq,
                                              int* __restrict__ sel_ws) {
  __shared__ float amp[1024];
  __shared__ float wv_s[4];
  __shared__ int wi_s[4];
  __shared__ int winner_s;
  const int src = blockIdx.x & 1;
  const int bh = blockIdx.x >> 1;
  const int b = bh >> 3, h = bh & 7;
  const int tid = threadIdx.x;

  if (src == 0) {
    for (int t = tid; t < 1024; t += 256) {
      float s = 0.f;
#pragma unroll
      for (int c = 0; c < 16; ++c) s += amp2_part[(size_t)(bh * 16 + c) * 1024 + t];
      amp[t] = s;
    }
  } else {
    for (int l = tid; l < 1024; l += 256) {
      const float4* p4 = reinterpret_cast<const float4*>(
          &tfq[((size_t)(b * L_ + l) * H_ + h) * E_]);
      float s = 0.f;
#pragma unroll
      for (int e4 = 0; e4 < 16; ++e4) {
        float4 v = p4[e4];
        s += v.x * v.x + v.y * v.y + v.z * v.z + v.w * v.w;
      }
      amp[l] = s;
    }
  }
  __syncthreads();

  float bv = -1.f; int bi = tid;
#pragma unroll
  for (int kk = 0; kk < 4; ++kk) {
    int t = tid + kk * 256;
    float v = amp[t];
    if (v > bv) { bv = v; bi = t; }
  }
  const int lane = tid & 63, w = tid >> 6;

  for (int it = 0; it < NTOP; ++it) {
    float v = bv; int i = bi;
#pragma unroll
    for (int d = 1; d < 64; d <<= 1) {
      float ov = __shfl_xor(v, d);
      int oi = __shfl_xor(i, d);
      if (ov > v || (ov == v && oi < i)) { v = ov; i = oi; }
    }
    if (lane == 0) { wv_s[w] = v; wi_s[w] = i; }
    __syncthreads();
    if (tid == 0) {
      float fv = wv_s[0]; int fi = wi_s[0];
#pragma unroll
      for (int j = 1; j < 4; ++j) {
        if (wv_s[j] > fv || (wv_s[j] == fv && wi_s[j] < fi)) { fv = wv_s[j]; fi = wi_s[j]; }
      }
      winner_s = fi;
      sel_ws[(bh * 2 + src) * 64 + it] = fi;
    }
    __syncthreads();
    int fi = winner_s;
    if ((fi & 255) == tid) {
      amp[fi] = -1.f;
      bv = -1.f; bi = tid;
#pragma unroll
      for (int kk = 0; kk < 4; ++kk) {
        int t = tid + kk * 256;
        float vv = amp[t];
        if (vv > bv) { bv = vv; bi = t; }
      }
    }
  }
}

// ---------------------------------------------------------------------------
// Kernel 3: scores over selected rows -> two softmaxes -> fuse -> times V.
// ---------------------------------------------------------------------------
__global__ __launch_bounds__(256) void k_attn(const float* __restrict__ q_g,
                                              const float* __restrict__ tfq,
                                              const float* __restrict__ k_g,
                                              const float* __restrict__ v_g,
                                              const float* __restrict__ wfuse,
                                              const int* __restrict__ sel_ws,
                                              float* __restrict__ out) {
  __shared__ float4 qs4[2][NTOP][16];   // [src][i][e4]
  __shared__ float4 vs4[2][NTOP][16];
  const int ac = blockIdx.x & 15;
  const int bh = blockIdx.x >> 4;
  const int b = bh >> 3, h = bh & 7;
  const int a0 = ac * 64;
  const int tid = threadIdx.x;

  for (int idx = tid; idx < 2 * NTOP * 16; idx += 256) {
    int src = idx / (NTOP * 16);
    int rem = idx - src * (NTOP * 16);
    int i = rem >> 4, e4 = rem & 15;
    int row = sel_ws[(bh * 2 + src) * 64 + i];
    size_t rb = ((size_t)(b * L_ + row) * H_ + h) * E_;
    const float* qbase = src ? tfq : q_g;
    qs4[src][i][e4] = reinterpret_cast<const float4*>(qbase + rb)[e4];
    vs4[src][i][e4] = reinterpret_cast<const float4*>(v_g + rb)[e4];
  }
  __syncthreads();

  const int qd = tid & 3, r = tid >> 2;
  const int a = a0 + r;
  const int eb = qd * 16;

  size_t krb = ((size_t)(b * L_ + a) * H_ + h) * E_;
  const float4* k4p = reinterpret_cast<const float4*>(k_g + krb);
  float4 kq[4];
#pragma unroll
  for (int j4 = 0; j4 < 4; ++j4) kq[j4] = k4p[qd * 4 + j4];

  float ct[NTOP], ctf[NTOP];
#pragma unroll
  for (int i = 0; i < NTOP; ++i) { ct[i] = 0.f; ctf[i] = 0.f; }

#pragma unroll
  for (int j4 = 0; j4 < 4; ++j4) {
    float4 kv = kq[j4];
#pragma unroll
    for (int i = 0; i < NTOP; ++i) {
      float4 q4 = qs4[0][i][qd * 4 + j4];
      ct[i] = fmaf(q4.x, kv.x, ct[i]); ct[i] = fmaf(q4.y, kv.y, ct[i]);
      ct[i] = fmaf(q4.z, kv.z, ct[i]); ct[i] = fmaf(q4.w, kv.w, ct[i]);
      float4 p4 = qs4[1][i][qd * 4 + j4];
      ctf[i] = fmaf(p4.x, kv.x, ctf[i]); ctf[i] = fmaf(p4.y, kv.y, ctf[i]);
      ctf[i] = fmaf(p4.z, kv.z, ctf[i]); ctf[i] = fmaf(p4.w, kv.w, ctf[i]);
    }
  }
#pragma unroll
  for (int i = 0; i < NTOP; ++i) {
    ct[i] += __shfl_xor(ct[i], 1);  ct[i] += __shfl_xor(ct[i], 2);
    ctf[i] += __shfl_xor(ctf[i], 1); ctf[i] += __shfl_xor(ctf[i], 2);
  }

  float wf0 = wfuse[(h * L_ + a) * 2 + 0];
  float wf1 = wfuse[(h * L_ + a) * 2 + 1];
  float wm = fmaxf(wf0, wf1);
  float ew0 = expf(wf0 - wm), ew1 = expf(wf1 - wm);
  float nw0 = ew0 / (ew0 + ew1), nw1 = ew1 / (ew0 + ew1);

  {
    float m = -1e30f;
#pragma unroll
    for (int i = 0; i < NTOP; ++i) { ct[i] *= SCALE_; m = fmaxf(m, ct[i]); }
    float sum = 0.f;
#pragma unroll
    for (int i = 0; i < NTOP; ++i) { ct[i] = expf(ct[i] - m); sum += ct[i]; }
    float c = 0.5f * nw0 / sum;
#pragma unroll
    for (int i = 0; i < NTOP; ++i) ct[i] *= c;
  }
  {
    float m = -1e30f;
#pragma unroll
    for (int i = 0; i < NTOP; ++i) { ctf[i] *= SCALE_; m = fmaxf(m, ctf[i]); }
    float sum = 0.f;
#pragma unroll
    for (int i = 0; i < NTOP; ++i) { ctf[i] = expf(ctf[i] - m); sum += ctf[i]; }
    float c = 0.5f * nw1 / sum;
#pragma unroll
    for (int i = 0; i < NTOP; ++i) ctf[i] *= c;
  }
#pragma unroll
  for (int j4 = 0; j4 < 4; ++j4) {
    float ax = 0.f, ay = 0.f, az = 0.f, aw = 0.f;
#pragma unroll
    for (int i = 0; i < NTOP; ++i) {
      float4 v4 = vs4[0][i][qd * 4 + j4];
      ax = fmaf(ct[i], v4.x, ax); ay = fmaf(ct[i], v4.y, ay);
      az = fmaf(ct[i], v4.z, az); aw = fmaf(ct[i], v4.w, aw);
    }
#pragma unroll
    for (int i = 0; i < NTOP; ++i) {
      float4 v4 = vs4[1][i][qd * 4 + j4];
      ax = fmaf(ctf[i], v4.x, ax); ay = fmaf(ctf[i], v4.y, ay);
      az = fmaf(ctf[i], v4.z, az); aw = fmaf(ctf[i], v4.w, aw);
    }
    int d = eb + j4 * 4;
    out[((size_t)(bh * 64 + d + 0)) * 1024 + a] = ax;
    out[((size_t)(bh * 64 + d + 1)) * 1024 + a] = ay;
    out[((size_t)(bh * 64 + d + 2)) * 1024 + a] = az;
    out[((size_t)(bh * 64 + d + 3)) * 1024 + a] = aw;
  }
}

// ---------------------------------------------------------------------------
// Kernel 5a: xqk = ctanh(q_ft^T k_ft); xqkv = xqk @ k_ft^T.
// ---------------------------------------------------------------------------
__global__ __launch_bounds__(256) void k_spec12(const float* __restrict__ qft,
                                                 const float* __restrict__ kft,
                                                 float* __restrict__ xre_g,
                                                 float* __restrict__ xim_g) {
  __shared__ float kre[64][65], kim[64][65];
  __shared__ float qre[64][8], qim[64][8];
  __shared__ float tre[8][64], tim[8][64];
  const int xc = blockIdx.x & 7;
  const int bh = blockIdx.x >> 3;
  const int tid = threadIdx.x;

  for (int idx = tid; idx < 4096; idx += 256) {
    int e = idx >> 6, y = idx & 63;
    size_t o = ((size_t)(bh * 64 + e) * 64 + y) * 2;
    kre[e][y] = kft[o]; kim[e][y] = kft[o + 1];
  }
  for (int idx = tid; idx < 512; idx += 256) {
    int e = idx >> 3, xl = idx & 7;
    size_t o = ((size_t)(bh * 64 + e) * 64 + xc * 8 + xl) * 2;
    qre[e][xl] = qft[o]; qim[e][xl] = qft[o + 1];
  }
  __syncthreads();

  const int y = tid & 63, xg = tid >> 6;
#pragma unroll
  for (int xi = 0; xi < 2; ++xi) {
    int xl = xg + xi * 4;
    float ar = 0.f, ai = 0.f;
    for (int e = 0; e < 64; ++e) {
      float a = qre[e][xl], b = qim[e][xl];
      float c = kre[e][y], d = kim[e][y];
      ar = fmaf(a, c, fmaf(-b, d, ar));
      ai = fmaf(a, d, fmaf(b, c, ai));
    }
    float trv, tiv;
    float x2 = 2.f * ar, y2 = 2.f * ai;
    if (fabsf(x2) > 30.f) {
      trv = copysignf(1.f, ar); tiv = 0.f;
    } else {
      float sh = sinhf(x2), ch = coshf(x2);
      float sn = sinf(y2), cs = cosf(y2);
      float dd = ch + cs;
      trv = sh / dd; tiv = sn / dd;
    }
    tre[xl][y] = trv; tim[xl][y] = tiv;
  }
  __syncthreads();

  const int e2 = tid & 63, xg2 = tid >> 6;
#pragma unroll
  for (int xi = 0; xi < 2; ++xi) {
    int xl = xg2 + xi * 4;
    float ar = 0.f, ai = 0.f;
    for (int yy = 0; yy < 64; ++yy) {
      float a = tre[xl][yy], b = tim[xl][yy];
      float c = kre[e2][yy], d = kim[e2][yy];
      ar = fmaf(a, c, fmaf(-b, d, ar));
      ai = fmaf(a, d, fmaf(b, c, ai));
    }
    xre_g[(size_t)bh * 4096 + (xc * 8 + xl) * 64 + e2] = ar;
    xim_g[(size_t)bh * 4096 + (xc * 8 + xl) * 64 + e2] = ai;
  }
}

// ---------------------------------------------------------------------------
// Kernel 5b: xqkvw[o][x] = (sum_e xqkv[e][x]*w1[h,e,o,x]) / 512^2.
// ---------------------------------------------------------------------------
__global__ __launch_bounds__(256) void k_w1(const float* __restrict__ xre_g,
                                            const float* __restrict__ xim_g,
                                            const float* __restrict__ w1re,
                                            const float* __restrict__ w1im,
                                            float* __restrict__ xw) {
  __shared__ float xre[64][65], xim[64][65];
  __shared__ float redr[4][512], redi[4][512];
  const int oc = blockIdx.x & 7;
  const int bh = blockIdx.x >> 3;
  const int h = bh & 7;
  const int tid = threadIdx.x;

  for (int idx = tid; idx < 4096; idx += 256) {
    int x = idx >> 6, e = idx & 63;
    xre[e][x] = xre_g[(size_t)bh * 4096 + idx];
    xim[e][x] = xim_g[(size_t)bh * 4096 + idx];
  }
  __syncthreads();

  const int x = tid & 63, g = tid >> 6;
  float accr[8], acci[8];
#pragma unroll
  for (int oo = 0; oo < 8; ++oo) { accr[oo] = 0.f; acci[oo] = 0.f; }

  for (int ee = 0; ee < 16; ++ee) {
    int e = g * 16 + ee;
    float a = xre[e][x], b = xim[e][x];
    size_t wbase = (((size_t)h * 64 + e) * 64 + oc * 8) * 64 + x;
#pragma unroll
    for (int oo = 0; oo < 8; ++oo) {
      float c = w1re[wbase + (size_t)oo * 64];
      float d = w1im[wbase + (size_t)oo * 64];
      accr[oo] = fmaf(a, c, fmaf(-b, d, accr[oo]));
      acci[oo] = fmaf(a, d, fmaf(b, c, acci[oo]));
    }
  }
#pragma unroll
  for (int oo = 0; oo < 8; ++oo) {
    redr[g][oo * 64 + x] = accr[oo];
    redi[g][oo * 64 + x] = acci[oo];
  }
  __syncthreads();

  const float INV = 1.0f / (512.0f * 512.0f);
  for (int idx = tid; idx < 512; idx += 256) {
    int oo = idx >> 6, x2 = idx & 63;
    float r = redr[0][idx] + redr[1][idx] + redr[2][idx] + redr[3][idx];
    float i = redi[0][idx] + redi[1][idx] + redi[2][idx] + redi[3][idx];
    size_t oidx = ((size_t)(bh * 64 + oc * 8 + oo) * 64 + x2) * 2;
    xw[oidx] = r * INV;
    xw[oidx + 1] = i * INV;
  }
}

// ---------------------------------------------------------------------------
// Kernel 6: 64-mode irfft, loop-inverted (thread per t, 8 o's at once).
// ---------------------------------------------------------------------------
__global__ __launch_bounds__(256) void k_final(const float* __restrict__ xw,
                                               float* __restrict__ out) {
  __shared__ float Xre[8][64], Xim[8][64];   // pre-scaled by 2
  const int tc = blockIdx.x & 3;
  const int oc = (blockIdx.x >> 2) & 7;
  const int bh = blockIdx.x >> 5;
  const int o0 = oc * 8;
  const int tid = threadIdx.x;

  for (int idx = tid; idx < 512; idx += 256) {
    int o = idx >> 6, m = idx & 63;
    size_t s = ((size_t)(bh * 64 + o0 + o) * 64 + m) * 2;
    Xre[o][m] = 2.f * xw[s]; Xim[o][m] = 2.f * xw[s + 1];
  }
  __syncthreads();

  const int t = tc * 256 + tid;
  const float HALF_INVN = 0.5f / 1024.0f;
  const float TWO_PI = 6.283185307179586f;
  float th = TWO_PI * (float)t * (1.0f / 1024.0f);
  float s1, c1;
  __sincosf(th, &s1, &c1);
  float cm = c1, sm = s1;

  float acc[8];
#pragma unroll
  for (int o = 0; o < 8; ++o) acc[o] = 0.5f * Xre[o][0];

  for (int m = 1; m < 64; ++m) {
#pragma unroll
    for (int o = 0; o < 8; ++o) {
      acc[o] = fmaf(Xre[o][m], cm, acc[o]);
      acc[o] = fmaf(-Xim[o][m], sm, acc[o]);
    }
    float cn = fmaf(cm, c1, -sm * s1);
    float sn = fmaf(sm, c1, cm * s1);
    cm = cn; sm = sn;
  }
#pragma unroll
  for (int o = 0; o < 8; ++o) {
    size_t oi = ((size_t)(bh * 64 + o0 + o)) * 1024 + t;
    out[oi] = fmaf(acc[o], HALF_INVN, out[oi]);
  }
}

// ---------------------------------------------------------------------------
extern "C" void kernel_launch(void* const* d_in, const int* in_sizes, int n_in,
                              void* d_out, int out_size, void* d_ws, size_t ws_size,
                              hipStream_t stream) {
  const float* tfq   = (const float*)d_in[0];
  const float* q     = (const float*)d_in[1];
  const float* k     = (const float*)d_in[2];
  const float* v     = (const float*)d_in[3];
  const float* wfuse = (const float*)d_in[5];
  const float* w1re  = (const float*)d_in[6];
  const float* w1im  = (const float*)d_in[7];
  float* out = (float*)d_out;
  float* ws  = (float*)d_ws;

  const size_t STAGED_FLOATS = 5246976;   // ~21.0 MB
  if (ws_size >= STAGED_FLOATS * sizeof(float)) {
    // staged layout:
    //   xtq [0..2097152) | xtk [..4194304) | amp2 [..4718592)
    //   qft [..4980736) | kft [..5242880) | sel [..5246976)
    //   xre_g/xim_g/xw alias xtq region (dead after k_fft_c).
    float* xtq   = ws;
    float* xtk   = ws + 2097152;
    float* amp2  = ws + 4194304;
    float* qft   = ws + 4718592;
    float* kft   = ws + 4980736;
    int*   sel   = (int*)(ws + 5242880);
    float* xre_g = ws;
    float* xim_g = ws + 131072;
    float* xw    = ws + 262144;

    k_stage<<<1024, 256, 0, stream>>>(q, k, xtq, xtk);
    k_fft_c<<<512, 512, 0, stream>>>(xtq, xtk, amp2, qft, kft);
    k_topk<<<64, 256, 0, stream>>>(amp2, tfq, sel);
    k_attn<<<512, 256, 0, stream>>>(q, tfq, k, v, wfuse, sel, out);
    k_spec12<<<256, 256, 0, stream>>>(qft, kft, xre_g, xim_g);
    k_w1<<<256, 256, 0, stream>>>(xre_g, xim_g, w1re, w1im, xw);
    k_final<<<1024, 256, 0, stream>>>(xw, out);
  } else {
    // fallback (R9 layout, 4.2 MB)
    float* amp2  = ws;
    float* xre_g = ws;
    float* xim_g = ws + 131072;
    float* xw    = ws + 262144;
    float* qft   = ws + 524288;
    float* kft   = ws + 786432;
    int*   sel   = (int*)(ws + 1048576);

    k_fft_s<<<512, 256, 0, stream>>>(q, k, amp2, qft, kft);
    k_topk<<<64, 256, 0, stream>>>(amp2, tfq, sel);
    k_attn<<<512, 256, 0, stream>>>(q, tfq, k, v, wfuse, sel, out);
    k_spec12<<<256, 256, 0, stream>>>(qft, kft, xre_g, xim_g);
    k_w1<<<256, 256, 0, stream>>>(xre_g, xim_g, w1re, w1im, xw);
    k_final<<<1024, 256, 0, stream>>>(xw, out);
  }
}

// Round 12
// 134.010 us; speedup vs baseline: 5.8490x; 1.0629x over previous
//
#include <hip/hip_runtime.h>
#include <math.h>

#define B_ 4
#define H_ 8
#define L_ 1024
#define E_ 64
#define NTOP 35
#define SCALE_ 0.04419417382415922f  /* 1/sqrt(512) */

// ---------------------------------------------------------------------------
// Kernel 0: transpose staging  x[b][t][h][e] -> xt[bh][e][t]  (q and k).
// ---------------------------------------------------------------------------
__global__ __launch_bounds__(256) void k_stage(const float* __restrict__ q_g,
                                               const float* __restrict__ k_g,
                                               float* __restrict__ xtq,
                                               float* __restrict__ xtk) {
  __shared__ float tile[64][65];
  const int tc = blockIdx.x & 15;
  const int src = (blockIdx.x >> 4) & 1;
  const int bh = blockIdx.x >> 5;
  const int b = bh >> 3, h = bh & 7;
  const int t0 = tc * 64;
  const int tid = threadIdx.x;
  const float* in = src ? k_g : q_g;
  float* out = src ? xtk : xtq;

  for (int idx = tid; idx < 1024; idx += 256) {
    int t = idx >> 4, e4 = idx & 15;
    float4 v = reinterpret_cast<const float4*>(
        in + ((size_t)(b * L_ + t0 + t) * H_ + h) * E_)[e4];
    tile[t][e4 * 4 + 0] = v.x; tile[t][e4 * 4 + 1] = v.y;
    tile[t][e4 * 4 + 2] = v.z; tile[t][e4 * 4 + 3] = v.w;
  }
  __syncthreads();
  for (int idx = tid; idx < 1024; idx += 256) {
    int e = idx >> 4, t4 = idx & 15;
    float4 v = make_float4(tile[t4 * 4 + 0][e], tile[t4 * 4 + 1][e],
                           tile[t4 * 4 + 2][e], tile[t4 * 4 + 3][e]);
    reinterpret_cast<float4*>(out + ((size_t)(bh * 64 + e)) * 1024 + t0)[t4] = v;
  }
}

// ---------------------------------------------------------------------------
// Kernel 1 (coalesced variant): FFT-based circular cross-correlation
// amplitude + 64-mode spectra, reading transposed planes.
// Grid: (bh, e-group of 4) = 512 blocks x 512 threads.
// ---------------------------------------------------------------------------
__global__ __launch_bounds__(512) void k_fft_c(const float* __restrict__ xtq,
                                               const float* __restrict__ xtk,
                                               float* __restrict__ amp2_part,
                                               float* __restrict__ qft,
                                               float* __restrict__ kft) {
  __shared__ __align__(16) float zre[4][1024], zim[4][1024];
  __shared__ float ctab[512], stab[512];
  const int eg = blockIdx.x & 15;
  const int bh = blockIdx.x >> 4;
  const int tid = threadIdx.x;
  const float TWO_PI_N = 6.283185307179586f / 1024.0f;

  if (tid < 512) {
    float s, c;
    sincosf(TWO_PI_N * (float)tid, &s, &c);
    ctab[tid] = c; stab[tid] = s;     // W^j = c - i*s
  }
  for (int idx = tid; idx < 1024; idx += 512) {
    int ee = idx >> 8, t4 = idx & 255;
    size_t ro = ((size_t)(bh * 64 + eg * 4 + ee)) * 1024;
    float4 qv = reinterpret_cast<const float4*>(xtq + ro)[t4];
    float4 kv = reinterpret_cast<const float4*>(xtk + ro)[t4];
    *reinterpret_cast<float4*>(&zre[ee][t4 * 4]) = qv;
    *reinterpret_cast<float4*>(&zim[ee][t4 * 4]) = kv;
  }
  __syncthreads();

  // ---- forward DIF: 2048 butterflies/stage, 4 per thread
  for (int s = 0; s < 10; ++s) {
    const int half = 512 >> s;
#pragma unroll
    for (int it = 0; it < 4; ++it) {
      int idx = tid + it * 512;
      int ee = idx >> 9;
      int bf = idx & 511;
      int j = bf & (half - 1);
      int p0 = ((bf >> (9 - s)) << (10 - s)) + j;
      int p1 = p0 + half;
      float ur = zre[ee][p0], ui = zim[ee][p0];
      float vr = zre[ee][p1], vi = zim[ee][p1];
      float dr = ur - vr, di = ui - vi;
      zre[ee][p0] = ur + vr; zim[ee][p0] = ui + vi;
      int twi = j << s;
      float c = ctab[twi], sn = stab[twi];
      zre[ee][p1] = fmaf(dr, c, di * sn);
      zim[ee][p1] = fmaf(di, c, -dr * sn);
    }
    __syncthreads();
  }

  // ---- Hermitian unpack + P = Fq*conj(Fk); dump modes 0..63.
  float pr[8], pi_[8];
#pragma unroll
  for (int it = 0; it < 8; ++it) {
    int idx = tid + it * 512;
    int ee = idx >> 10;
    int p = idx & 1023;
    int m = __brev((unsigned)p) >> 22;
    int mp = (1024 - m) & 1023;
    int pp = __brev((unsigned)mp) >> 22;
    float ar = zre[ee][p], ai = zim[ee][p];
    float br = zre[ee][pp], bi = zim[ee][pp];
    float qr = 0.5f * (ar + br), qi = 0.5f * (ai - bi);
    float kr = 0.5f * (ai + bi), ki = -0.5f * (ar - br);
    pr[it]  = fmaf(qr, kr, qi * ki);
    pi_[it] = fmaf(qi, kr, -qr * ki);
    if (m < 64) {
      size_t o = ((size_t)(bh * 64 + eg * 4 + ee) * 64 + m) * 2;
      qft[o] = qr; qft[o + 1] = qi;
      kft[o] = kr; kft[o + 1] = ki;
    }
  }
  __syncthreads();
#pragma unroll
  for (int it = 0; it < 8; ++it) {
    int idx = tid + it * 512;
    int ee = idx >> 10;
    int p = idx & 1023;
    zre[ee][p] = pr[it]; zim[ee][p] = pi_[it];
  }
  __syncthreads();

  // ---- pair-mix: slot 2u := P_{2u} + i*P_{2u+1}
  for (int idx = tid; idx < 2048; idx += 512) {
    int u = idx >> 10;
    int p = idx & 1023;
    int e0 = 2 * u, e1 = 2 * u + 1;
    float s_r = zre[e0][p] - zim[e1][p];
    float s_i = zim[e0][p] + zre[e1][p];
    zre[e0][p] = s_r; zim[e0][p] = s_i;
  }
  __syncthreads();

  // ---- inverse DIT on slots 0,2: 1024 butterflies/stage, 2 per thread
  for (int s = 9; s >= 0; --s) {
    const int half = 512 >> s;
#pragma unroll
    for (int it = 0; it < 2; ++it) {
      int idx = tid + it * 512;
      int ee = (idx >> 9) * 2;
      int bf = idx & 511;
      int j = bf & (half - 1);
      int p0 = ((bf >> (9 - s)) << (10 - s)) + j;
      int p1 = p0 + half;
      int twi = j << s;
      float c = ctab[twi], sn = stab[twi];
      float ur = zre[ee][p0], ui = zim[ee][p0];
      float wr = zre[ee][p1], wi = zim[ee][p1];
      float vr = fmaf(wr, c, -wi * sn);
      float vi = fmaf(wi, c, wr * sn);
      zre[ee][p0] = ur + vr; zim[ee][p0] = ui + vi;
      zre[ee][p1] = ur - vr; zim[ee][p1] = ui - vi;
    }
    __syncthreads();
  }

  // ---- amp2
  for (int t = tid; t < 1024; t += 512) {
    float r0 = zre[0][t], i0 = zim[0][t];
    float r2 = zre[2][t], i2 = zim[2][t];
    amp2_part[(size_t)(bh * 16 + eg) * 1024 + t] =
        fmaf(r0, r0, fmaf(i0, i0, fmaf(r2, r2, i2 * i2)));
  }
}

// ---------------------------------------------------------------------------
// Kernel 1 (strided fallback): used when ws is too small for staging.
// ---------------------------------------------------------------------------
__global__ __launch_bounds__(256) void k_fft_s(const float* __restrict__ q_g,
                                               const float* __restrict__ k_g,
                                               float* __restrict__ amp2_part,
                                               float* __restrict__ qft,
                                               float* __restrict__ kft) {
  __shared__ float zre[4][1024], zim[4][1024];
  __shared__ float ctab[512], stab[512];
  const int eg = blockIdx.x & 15;
  const int bh = blockIdx.x >> 4;
  const int b = bh >> 3, h = bh & 7;
  const int tid = threadIdx.x;
  const float TWO_PI_N = 6.283185307179586f / 1024.0f;

  for (int j = tid; j < 512; j += 256) {
    float s, c;
    sincosf(TWO_PI_N * (float)j, &s, &c);
    ctab[j] = c; stab[j] = s;
  }
  for (int t = tid; t < 1024; t += 256) {
    size_t g4 = ((size_t)(b * L_ + t) * H_ + h) * 16 + eg;
    float4 qv = reinterpret_cast<const float4*>(q_g)[g4];
    float4 kv = reinterpret_cast<const float4*>(k_g)[g4];
    zre[0][t] = qv.x; zre[1][t] = qv.y; zre[2][t] = qv.z; zre[3][t] = qv.w;
    zim[0][t] = kv.x; zim[1][t] = kv.y; zim[2][t] = kv.z; zim[3][t] = kv.w;
  }
  __syncthreads();

  for (int s = 0; s < 10; ++s) {
    const int half = 512 >> s;
#pragma unroll
    for (int it = 0; it < 8; ++it) {
      int idx = tid + it * 256;
      int ee = idx >> 9;
      int bf = idx & 511;
      int j = bf & (half - 1);
      int p0 = ((bf >> (9 - s)) << (10 - s)) + j;
      int p1 = p0 + half;
      float ur = zre[ee][p0], ui = zim[ee][p0];
      float vr = zre[ee][p1], vi = zim[ee][p1];
      float dr = ur - vr, di = ui - vi;
      zre[ee][p0] = ur + vr; zim[ee][p0] = ui + vi;
      int twi = j << s;
      float c = ctab[twi], sn = stab[twi];
      zre[ee][p1] = fmaf(dr, c, di * sn);
      zim[ee][p1] = fmaf(di, c, -dr * sn);
    }
    __syncthreads();
  }

  float pr[16], pi_[16];
#pragma unroll
  for (int it = 0; it < 16; ++it) {
    int idx = tid + it * 256;
    int ee = idx >> 10;
    int p = idx & 1023;
    int m = __brev((unsigned)p) >> 22;
    int mp = (1024 - m) & 1023;
    int pp = __brev((unsigned)mp) >> 22;
    float ar = zre[ee][p], ai = zim[ee][p];
    float br = zre[ee][pp], bi = zim[ee][pp];
    float qr = 0.5f * (ar + br), qi = 0.5f * (ai - bi);
    float kr = 0.5f * (ai + bi), ki = -0.5f * (ar - br);
    pr[it]  = fmaf(qr, kr, qi * ki);
    pi_[it] = fmaf(qi, kr, -qr * ki);
    if (m < 64) {
      size_t o = ((size_t)(bh * 64 + eg * 4 + ee) * 64 + m) * 2;
      qft[o] = qr; qft[o + 1] = qi;
      kft[o] = kr; kft[o + 1] = ki;
    }
  }
  __syncthreads();
#pragma unroll
  for (int it = 0; it < 16; ++it) {
    int idx = tid + it * 256;
    int ee = idx >> 10;
    int p = idx & 1023;
    zre[ee][p] = pr[it]; zim[ee][p] = pi_[it];
  }
  __syncthreads();

  for (int idx = tid; idx < 2048; idx += 256) {
    int u = idx >> 10;
    int p = idx & 1023;
    int e0 = 2 * u, e1 = 2 * u + 1;
    float s_r = zre[e0][p] - zim[e1][p];
    float s_i = zim[e0][p] + zre[e1][p];
    zre[e0][p] = s_r; zim[e0][p] = s_i;
  }
  __syncthreads();

  for (int s = 9; s >= 0; --s) {
    const int half = 512 >> s;
#pragma unroll
    for (int it = 0; it < 4; ++it) {
      int idx = tid + it * 256;
      int ee = (idx >> 9) * 2;
      int bf = idx & 511;
      int j = bf & (half - 1);
      int p0 = ((bf >> (9 - s)) << (10 - s)) + j;
      int p1 = p0 + half;
      int twi = j << s;
      float c = ctab[twi], sn = stab[twi];
      float ur = zre[ee][p0], ui = zim[ee][p0];
      float wr = zre[ee][p1], wi = zim[ee][p1];
      float vr = fmaf(wr, c, -wi * sn);
      float vi = fmaf(wi, c, wr * sn);
      zre[ee][p0] = ur + vr; zim[ee][p0] = ui + vi;
      zre[ee][p1] = ur - vr; zim[ee][p1] = ui - vi;
    }
    __syncthreads();
  }

  for (int t = tid; t < 1024; t += 256) {
    float r0 = zre[0][t], i0 = zim[0][t];
    float r2 = zre[2][t], i2 = zim[2][t];
    amp2_part[(size_t)(bh * 16 + eg) * 1024 + t] =
        fmaf(r0, r0, fmaf(i0, i0, fmaf(r2, r2, i2 * i2)));
  }
}

// ---------------------------------------------------------------------------
// Kernel 2a: amplitude reduction -> ampsum[p][t], p = bh*2+src.
// Grid: 160 blocks (32 for src0 partial-sums, 128 for src1 row-norms).
// ---------------------------------------------------------------------------
__global__ __launch_bounds__(256) void k_red(const float* __restrict__ amp2_part,
                                             const float* __restrict__ tfq,
                                             float* __restrict__ ampsum) {
  const int blk = blockIdx.x;
  const int tid = threadIdx.x;
  if (blk < 32) {
    const int bh = blk;
    for (int t = tid; t < 1024; t += 256) {
      float s = 0.f;
#pragma unroll
      for (int c = 0; c < 16; ++c)
        s += amp2_part[(size_t)(bh * 16 + c) * 1024 + t];
      ampsum[(size_t)(bh * 2) * 1024 + t] = s;
    }
  } else {
    const int idx = blk - 32;
    const int bh = idx >> 2, qt = idx & 3;
    const int b = bh >> 3, h = bh & 7;
    const int l = qt * 256 + tid;
    const float4* p4 = reinterpret_cast<const float4*>(
        &tfq[((size_t)(b * L_ + l) * H_ + h) * E_]);
    float s = 0.f;
#pragma unroll
    for (int e4 = 0; e4 < 16; ++e4) {
      float4 v = p4[e4];
      s += v.x * v.x + v.y * v.y + v.z * v.z + v.w * v.w;
    }
    ampsum[(size_t)(bh * 2 + 1) * 1024 + l] = s;
  }
}

// ---------------------------------------------------------------------------
// Kernel 2b: top-35 selection, one WAVE per problem p = bh*2+src.
// Lane holds 16 candidates in registers (t = j*64+lane, ascending j = asc t);
// 35 rounds of 6-step shfl argmax (value desc, index asc) -- no LDS/barriers.
// Same comparator as before -> identical selection.
// ---------------------------------------------------------------------------
__global__ __launch_bounds__(64) void k_sel(const float* __restrict__ ampsum,
                                            int* __restrict__ sel_ws) {
  const int p = blockIdx.x;
  const int lane = threadIdx.x;
  float val[16];
#pragma unroll
  for (int j = 0; j < 16; ++j)
    val[j] = ampsum[(size_t)p * 1024 + j * 64 + lane];

  float bv = -1.f; int bi = lane;
#pragma unroll
  for (int j = 0; j < 16; ++j) {
    if (val[j] > bv) { bv = val[j]; bi = j * 64 + lane; }
  }

  for (int it = 0; it < NTOP; ++it) {
    float v = bv; int i = bi;
#pragma unroll
    for (int d = 1; d < 64; d <<= 1) {
      float ov = __shfl_xor(v, d);
      int oi = __shfl_xor(i, d);
      if (ov > v || (ov == v && oi < i)) { v = ov; i = oi; }
    }
    if (lane == 0) sel_ws[p * 64 + it] = i;
    if ((i & 63) == lane) {
      int jr = i >> 6;
#pragma unroll
      for (int j = 0; j < 16; ++j) if (j == jr) val[j] = -1.f;
      bv = -1.f; bi = lane;
#pragma unroll
      for (int j = 0; j < 16; ++j) {
        if (val[j] > bv) { bv = val[j]; bi = j * 64 + lane; }
      }
    }
  }
}

// ---------------------------------------------------------------------------
// Kernel 2 (fallback): old LDS top-k for the small-ws path.
// ---------------------------------------------------------------------------
__global__ __launch_bounds__(256) void k_topk(const float* __restrict__ amp2_part,
                                              const float* __restrict__ tfq,
                                              int* __restrict__ sel_ws) {
  __shared__ float amp[1024];
  __shared__ float wv_s[4];
  __shared__ int wi_s[4];
  __shared__ int winner_s;
  const int src = blockIdx.x & 1;
  const int bh = blockIdx.x >> 1;
  const int b = bh >> 3, h = bh & 7;
  const int tid = threadIdx.x;

  if (src == 0) {
    for (int t = tid; t < 1024; t += 256) {
      float s = 0.f;
#pragma unroll
      for (int c = 0; c < 16; ++c) s += amp2_part[(size_t)(bh * 16 + c) * 1024 + t];
      amp[t] = s;
    }
  } else {
    for (int l = tid; l < 1024; l += 256) {
      const float4* p4 = reinterpret_cast<const float4*>(
          &tfq[((size_t)(b * L_ + l) * H_ + h) * E_]);
      float s = 0.f;
#pragma unroll
      for (int e4 = 0; e4 < 16; ++e4) {
        float4 v = p4[e4];
        s += v.x * v.x + v.y * v.y + v.z * v.z + v.w * v.w;
      }
      amp[l] = s;
    }
  }
  __syncthreads();

  float bv = -1.f; int bi = tid;
#pragma unroll
  for (int kk = 0; kk < 4; ++kk) {
    int t = tid + kk * 256;
    float v = amp[t];
    if (v > bv) { bv = v; bi = t; }
  }
  const int lane = tid & 63, w = tid >> 6;

  for (int it = 0; it < NTOP; ++it) {
    float v = bv; int i = bi;
#pragma unroll
    for (int d = 1; d < 64; d <<= 1) {
      float ov = __shfl_xor(v, d);
      int oi = __shfl_xor(i, d);
      if (ov > v || (ov == v && oi < i)) { v = ov; i = oi; }
    }
    if (lane == 0) { wv_s[w] = v; wi_s[w] = i; }
    __syncthreads();
    if (tid == 0) {
      float fv = wv_s[0]; int fi = wi_s[0];
#pragma unroll
      for (int j = 1; j < 4; ++j) {
        if (wv_s[j] > fv || (wv_s[j] == fv && wi_s[j] < fi)) { fv = wv_s[j]; fi = wi_s[j]; }
      }
      winner_s = fi;
      sel_ws[(bh * 2 + src) * 64 + it] = fi;
    }
    __syncthreads();
    int fi = winner_s;
    if ((fi & 255) == tid) {
      amp[fi] = -1.f;
      bv = -1.f; bi = tid;
#pragma unroll
      for (int kk = 0; kk < 4; ++kk) {
        int t = tid + kk * 256;
        float vv = amp[t];
        if (vv > bv) { bv = vv; bi = t; }
      }
    }
  }
}

// ---------------------------------------------------------------------------
// Kernel 3: scores over selected rows -> two softmaxes -> fuse -> times V.
// ---------------------------------------------------------------------------
__global__ __launch_bounds__(256) void k_attn(const float* __restrict__ q_g,
                                              const float* __restrict__ tfq,
                                              const float* __restrict__ k_g,
                                              const float* __restrict__ v_g,
                                              const float* __restrict__ wfuse,
                                              const int* __restrict__ sel_ws,
                                              float* __restrict__ out) {
  __shared__ float4 qs4[2][NTOP][16];   // [src][i][e4]
  __shared__ float4 vs4[2][NTOP][16];
  const int ac = blockIdx.x & 15;
  const int bh = blockIdx.x >> 4;
  const int b = bh >> 3, h = bh & 7;
  const int a0 = ac * 64;
  const int tid = threadIdx.x;

  for (int idx = tid; idx < 2 * NTOP * 16; idx += 256) {
    int src = idx / (NTOP * 16);
    int rem = idx - src * (NTOP * 16);
    int i = rem >> 4, e4 = rem & 15;
    int row = sel_ws[(bh * 2 + src) * 64 + i];
    size_t rb = ((size_t)(b * L_ + row) * H_ + h) * E_;
    const float* qbase = src ? tfq : q_g;
    qs4[src][i][e4] = reinterpret_cast<const float4*>(qbase + rb)[e4];
    vs4[src][i][e4] = reinterpret_cast<const float4*>(v_g + rb)[e4];
  }
  __syncthreads();

  const int qd = tid & 3, r = tid >> 2;
  const int a = a0 + r;
  const int eb = qd * 16;

  size_t krb = ((size_t)(b * L_ + a) * H_ + h) * E_;
  const float4* k4p = reinterpret_cast<const float4*>(k_g + krb);
  float4 kq[4];
#pragma unroll
  for (int j4 = 0; j4 < 4; ++j4) kq[j4] = k4p[qd * 4 + j4];

  float ct[NTOP], ctf[NTOP];
#pragma unroll
  for (int i = 0; i < NTOP; ++i) { ct[i] = 0.f; ctf[i] = 0.f; }

#pragma unroll
  for (int j4 = 0; j4 < 4; ++j4) {
    float4 kv = kq[j4];
#pragma unroll
    for (int i = 0; i < NTOP; ++i) {
      float4 q4 = qs4[0][i][qd * 4 + j4];
      ct[i] = fmaf(q4.x, kv.x, ct[i]); ct[i] = fmaf(q4.y, kv.y, ct[i]);
      ct[i] = fmaf(q4.z, kv.z, ct[i]); ct[i] = fmaf(q4.w, kv.w, ct[i]);
      float4 p4 = qs4[1][i][qd * 4 + j4];
      ctf[i] = fmaf(p4.x, kv.x, ctf[i]); ctf[i] = fmaf(p4.y, kv.y, ctf[i]);
      ctf[i] = fmaf(p4.z, kv.z, ctf[i]); ctf[i] = fmaf(p4.w, kv.w, ctf[i]);
    }
  }
#pragma unroll
  for (int i = 0; i < NTOP; ++i) {
    ct[i] += __shfl_xor(ct[i], 1);  ct[i] += __shfl_xor(ct[i], 2);
    ctf[i] += __shfl_xor(ctf[i], 1); ctf[i] += __shfl_xor(ctf[i], 2);
  }

  float wf0 = wfuse[(h * L_ + a) * 2 + 0];
  float wf1 = wfuse[(h * L_ + a) * 2 + 1];
  float wm = fmaxf(wf0, wf1);
  float ew0 = expf(wf0 - wm), ew1 = expf(wf1 - wm);
  float nw0 = ew0 / (ew0 + ew1), nw1 = ew1 / (ew0 + ew1);

  {
    float m = -1e30f;
#pragma unroll
    for (int i = 0; i < NTOP; ++i) { ct[i] *= SCALE_; m = fmaxf(m, ct[i]); }
    float sum = 0.f;
#pragma unroll
    for (int i = 0; i < NTOP; ++i) { ct[i] = expf(ct[i] - m); sum += ct[i]; }
    float c = 0.5f * nw0 / sum;
#pragma unroll
    for (int i = 0; i < NTOP; ++i) ct[i] *= c;
  }
  {
    float m = -1e30f;
#pragma unroll
    for (int i = 0; i < NTOP; ++i) { ctf[i] *= SCALE_; m = fmaxf(m, ctf[i]); }
    float sum = 0.f;
#pragma unroll
    for (int i = 0; i < NTOP; ++i) { ctf[i] = expf(ctf[i] - m); sum += ctf[i]; }
    float c = 0.5f * nw1 / sum;
#pragma unroll
    for (int i = 0; i < NTOP; ++i) ctf[i] *= c;
  }
#pragma unroll
  for (int j4 = 0; j4 < 4; ++j4) {
    float ax = 0.f, ay = 0.f, az = 0.f, aw = 0.f;
#pragma unroll
    for (int i = 0; i < NTOP; ++i) {
      float4 v4 = vs4[0][i][qd * 4 + j4];
      ax = fmaf(ct[i], v4.x, ax); ay = fmaf(ct[i], v4.y, ay);
      az = fmaf(ct[i], v4.z, az); aw = fmaf(ct[i], v4.w, aw);
    }
#pragma unroll
    for (int i = 0; i < NTOP; ++i) {
      float4 v4 = vs4[1][i][qd * 4 + j4];
      ax = fmaf(ctf[i], v4.x, ax); ay = fmaf(ctf[i], v4.y, ay);
      az = fmaf(ctf[i], v4.z, az); aw = fmaf(ctf[i], v4.w, aw);
    }
    int d = eb + j4 * 4;
    out[((size_t)(bh * 64 + d + 0)) * 1024 + a] = ax;
    out[((size_t)(bh * 64 + d + 1)) * 1024 + a] = ay;
    out[((size_t)(bh * 64 + d + 2)) * 1024 + a] = az;
    out[((size_t)(bh * 64 + d + 3)) * 1024 + a] = aw;
  }
}

// ---------------------------------------------------------------------------
// Kernel 5a: xqk = ctanh(q_ft^T k_ft); xqkv = xqk @ k_ft^T.
// ---------------------------------------------------------------------------
__global__ __launch_bounds__(256) void k_spec12(const float* __restrict__ qft,
                                                 const float* __restrict__ kft,
                                                 float* __restrict__ xre_g,
                                                 float* __restrict__ xim_g) {
  __shared__ float kre[64][65], kim[64][65];
  __shared__ float qre[64][8], qim[64][8];
  __shared__ float tre[8][64], tim[8][64];
  const int xc = blockIdx.x & 7;
  const int bh = blockIdx.x >> 3;
  const int tid = threadIdx.x;

  for (int idx = tid; idx < 4096; idx += 256) {
    int e = idx >> 6, y = idx & 63;
    size_t o = ((size_t)(bh * 64 + e) * 64 + y) * 2;
    kre[e][y] = kft[o]; kim[e][y] = kft[o + 1];
  }
  for (int idx = tid; idx < 512; idx += 256) {
    int e = idx >> 3, xl = idx & 7;
    size_t o = ((size_t)(bh * 64 + e) * 64 + xc * 8 + xl) * 2;
    qre[e][xl] = qft[o]; qim[e][xl] = qft[o + 1];
  }
  __syncthreads();

  const int y = tid & 63, xg = tid >> 6;
#pragma unroll
  for (int xi = 0; xi < 2; ++xi) {
    int xl = xg + xi * 4;
    float ar = 0.f, ai = 0.f;
    for (int e = 0; e < 64; ++e) {
      float a = qre[e][xl], b = qim[e][xl];
      float c = kre[e][y], d = kim[e][y];
      ar = fmaf(a, c, fmaf(-b, d, ar));
      ai = fmaf(a, d, fmaf(b, c, ai));
    }
    float trv, tiv;
    float x2 = 2.f * ar, y2 = 2.f * ai;
    if (fabsf(x2) > 30.f) {
      trv = copysignf(1.f, ar); tiv = 0.f;
    } else {
      float sh = sinhf(x2), ch = coshf(x2);
      float sn = sinf(y2), cs = cosf(y2);
      float dd = ch + cs;
      trv = sh / dd; tiv = sn / dd;
    }
    tre[xl][y] = trv; tim[xl][y] = tiv;
  }
  __syncthreads();

  const int e2 = tid & 63, xg2 = tid >> 6;
#pragma unroll
  for (int xi = 0; xi < 2; ++xi) {
    int xl = xg2 + xi * 4;
    float ar = 0.f, ai = 0.f;
    for (int yy = 0; yy < 64; ++yy) {
      float a = tre[xl][yy], b = tim[xl][yy];
      float c = kre[e2][yy], d = kim[e2][yy];
      ar = fmaf(a, c, fmaf(-b, d, ar));
      ai = fmaf(a, d, fmaf(b, c, ai));
    }
    xre_g[(size_t)bh * 4096 + (xc * 8 + xl) * 64 + e2] = ar;
    xim_g[(size_t)bh * 4096 + (xc * 8 + xl) * 64 + e2] = ai;
  }
}

// ---------------------------------------------------------------------------
// Kernel 5b: xqkvw[o][x] = (sum_e xqkv[e][x]*w1[h,e,o,x]) / 512^2.
// ---------------------------------------------------------------------------
__global__ __launch_bounds__(256) void k_w1(const float* __restrict__ xre_g,
                                            const float* __restrict__ xim_g,
                                            const float* __restrict__ w1re,
                                            const float* __restrict__ w1im,
                                            float* __restrict__ xw) {
  __shared__ float xre[64][65], xim[64][65];
  __shared__ float redr[4][512], redi[4][512];
  const int oc = blockIdx.x & 7;
  const int bh = blockIdx.x >> 3;
  const int h = bh & 7;
  const int tid = threadIdx.x;

  for (int idx = tid; idx < 4096; idx += 256) {
    int x = idx >> 6, e = idx & 63;
    xre[e][x] = xre_g[(size_t)bh * 4096 + idx];
    xim[e][x] = xim_g[(size_t)bh * 4096 + idx];
  }
  __syncthreads();

  const int x = tid & 63, g = tid >> 6;
  float accr[8], acci[8];
#pragma unroll
  for (int oo = 0; oo < 8; ++oo) { accr[oo] = 0.f; acci[oo] = 0.f; }

  for (int ee = 0; ee < 16; ++ee) {
    int e = g * 16 + ee;
    float a = xre[e][x], b = xim[e][x];
    size_t wbase = (((size_t)h * 64 + e) * 64 + oc * 8) * 64 + x;
#pragma unroll
    for (int oo = 0; oo < 8; ++oo) {
      float c = w1re[wbase + (size_t)oo * 64];
      float d = w1im[wbase + (size_t)oo * 64];
      accr[oo] = fmaf(a, c, fmaf(-b, d, accr[oo]));
      acci[oo] = fmaf(a, d, fmaf(b, c, acci[oo]));
    }
  }
#pragma unroll
  for (int oo = 0; oo < 8; ++oo) {
    redr[g][oo * 64 + x] = accr[oo];
    redi[g][oo * 64 + x] = acci[oo];
  }
  __syncthreads();

  const float INV = 1.0f / (512.0f * 512.0f);
  for (int idx = tid; idx < 512; idx += 256) {
    int oo = idx >> 6, x2 = idx & 63;
    float r = redr[0][idx] + redr[1][idx] + redr[2][idx] + redr[3][idx];
    float i = redi[0][idx] + redi[1][idx] + redi[2][idx] + redi[3][idx];
    size_t oidx = ((size_t)(bh * 64 + oc * 8 + oo) * 64 + x2) * 2;
    xw[oidx] = r * INV;
    xw[oidx + 1] = i * INV;
  }
}

// ---------------------------------------------------------------------------
// Kernel 6: 64-mode irfft, loop-inverted (thread per t, 8 o's at once).
// ---------------------------------------------------------------------------
__global__ __launch_bounds__(256) void k_final(const float* __restrict__ xw,
                                               float* __restrict__ out) {
  __shared__ float Xre[8][64], Xim[8][64];   // pre-scaled by 2
  const int tc = blockIdx.x & 3;
  const int oc = (blockIdx.x >> 2) & 7;
  const int bh = blockIdx.x >> 5;
  const int o0 = oc * 8;
  const int tid = threadIdx.x;

  for (int idx = tid; idx < 512; idx += 256) {
    int o = idx >> 6, m = idx & 63;
    size_t s = ((size_t)(bh * 64 + o0 + o) * 64 + m) * 2;
    Xre[o][m] = 2.f * xw[s]; Xim[o][m] = 2.f * xw[s + 1];
  }
  __syncthreads();

  const int t = tc * 256 + tid;
  const float HALF_INVN = 0.5f / 1024.0f;
  const float TWO_PI = 6.283185307179586f;
  float th = TWO_PI * (float)t * (1.0f / 1024.0f);
  float s1, c1;
  __sincosf(th, &s1, &c1);
  float cm = c1, sm = s1;

  float acc[8];
#pragma unroll
  for (int o = 0; o < 8; ++o) acc[o] = 0.5f * Xre[o][0];

  for (int m = 1; m < 64; ++m) {
#pragma unroll
    for (int o = 0; o < 8; ++o) {
      acc[o] = fmaf(Xre[o][m], cm, acc[o]);
      acc[o] = fmaf(-Xim[o][m], sm, acc[o]);
    }
    float cn = fmaf(cm, c1, -sm * s1);
    float sn = fmaf(sm, c1, cm * s1);
    cm = cn; sm = sn;
  }
#pragma unroll
  for (int o = 0; o < 8; ++o) {
    size_t oi = ((size_t)(bh * 64 + o0 + o)) * 1024 + t;
    out[oi] = fmaf(acc[o], HALF_INVN, out[oi]);
  }
}

// ---------------------------------------------------------------------------
extern "C" void kernel_launch(void* const* d_in, const int* in_sizes, int n_in,
                              void* d_out, int out_size, void* d_ws, size_t ws_size,
                              hipStream_t stream) {
  const float* tfq   = (const float*)d_in[0];
  const float* q     = (const float*)d_in[1];
  const float* k     = (const float*)d_in[2];
  const float* v     = (const float*)d_in[3];
  const float* wfuse = (const float*)d_in[5];
  const float* w1re  = (const float*)d_in[6];
  const float* w1im  = (const float*)d_in[7];
  float* out = (float*)d_out;
  float* ws  = (float*)d_ws;

  const size_t STAGED_FLOATS = 5312512;   // ~21.25 MB
  if (ws_size >= STAGED_FLOATS * sizeof(float)) {
    // staged layout:
    //   xtq [0..2097152) | xtk [..4194304) | amp2 [..4718592)
    //   qft [..4980736) | kft [..5242880) | sel [..5246976) | ampsum [..5312512)
    //   xre_g/xim_g/xw alias xtq region (dead after k_fft_c).
    float* xtq    = ws;
    float* xtk    = ws + 2097152;
    float* amp2   = ws + 4194304;
    float* qft    = ws + 4718592;
    float* kft    = ws + 4980736;
    int*   sel    = (int*)(ws + 5242880);
    float* ampsum = ws + 5246976;
    float* xre_g  = ws;
    float* xim_g  = ws + 131072;
    float* xw     = ws + 262144;

    k_stage<<<1024, 256, 0, stream>>>(q, k, xtq, xtk);
    k_fft_c<<<512, 512, 0, stream>>>(xtq, xtk, amp2, qft, kft);
    k_red<<<160, 256, 0, stream>>>(amp2, tfq, ampsum);
    k_sel<<<64, 64, 0, stream>>>(ampsum, sel);
    k_attn<<<512, 256, 0, stream>>>(q, tfq, k, v, wfuse, sel, out);
    k_spec12<<<256, 256, 0, stream>>>(qft, kft, xre_g, xim_g);
    k_w1<<<256, 256, 0, stream>>>(xre_g, xim_g, w1re, w1im, xw);
    k_final<<<1024, 256, 0, stream>>>(xw, out);
  } else {
    // fallback (R9 layout, 4.2 MB)
    float* amp2  = ws;
    float* xre_g = ws;
    float* xim_g = ws + 131072;
    float* xw    = ws + 262144;
    float* qft   = ws + 524288;
    float* kft   = ws + 786432;
    int*   sel   = (int*)(ws + 1048576);

    k_fft_s<<<512, 256, 0, stream>>>(q, k, amp2, qft, kft);
    k_topk<<<64, 256, 0, stream>>>(amp2, tfq, sel);
    k_attn<<<512, 256, 0, stream>>>(q, tfq, k, v, wfuse, sel, out);
    k_spec12<<<256, 256, 0, stream>>>(qft, kft, xre_g, xim_g);
    k_w1<<<256, 256, 0, stream>>>(xre_g, xim_g, w1re, w1im, xw);
    k_final<<<1024, 256, 0, stream>>>(xw, out);
  }
}

// Round 13
// 114.031 us; speedup vs baseline: 6.8738x; 1.1752x over previous
//
#include <hip/hip_runtime.h>
#include <math.h>

#define B_ 4
#define H_ 8
#define L_ 1024
#define E_ 64
#define NTOP 35
#define SCALE_ 0.04419417382415922f  /* 1/sqrt(512) */

// ============================ device roles =================================

// ---- transpose staging x[b][t][h][e] -> xt[bh][e][t] (q and k) -------------
__device__ __forceinline__ void dev_stage(char* smem, int vbid,
                                          const float* __restrict__ q_g,
                                          const float* __restrict__ k_g,
                                          float* __restrict__ xtq,
                                          float* __restrict__ xtk) {
  float* tile = reinterpret_cast<float*>(smem);   // [64][65]
  const int tc = vbid & 15;
  const int src = (vbid >> 4) & 1;
  const int bh = vbid >> 5;
  const int b = bh >> 3, h = bh & 7;
  const int t0 = tc * 64;
  const int tid = threadIdx.x;
  const float* in = src ? k_g : q_g;
  float* out = src ? xtk : xtq;

  for (int idx = tid; idx < 1024; idx += 256) {
    int t = idx >> 4, e4 = idx & 15;
    float4 v = reinterpret_cast<const float4*>(
        in + ((size_t)(b * L_ + t0 + t) * H_ + h) * E_)[e4];
    tile[t * 65 + e4 * 4 + 0] = v.x; tile[t * 65 + e4 * 4 + 1] = v.y;
    tile[t * 65 + e4 * 4 + 2] = v.z; tile[t * 65 + e4 * 4 + 3] = v.w;
  }
  __syncthreads();
  for (int idx = tid; idx < 1024; idx += 256) {
    int e = idx >> 4, t4 = idx & 15;
    float4 v = make_float4(tile[(t4 * 4 + 0) * 65 + e], tile[(t4 * 4 + 1) * 65 + e],
                           tile[(t4 * 4 + 2) * 65 + e], tile[(t4 * 4 + 3) * 65 + e]);
    reinterpret_cast<float4*>(out + ((size_t)(bh * 64 + e)) * 1024 + t0)[t4] = v;
  }
}

// ---- tfq row-norms -> ampsum[bh*2+1][l] ------------------------------------
__device__ __forceinline__ void dev_tfqnorm(int vbid,
                                            const float* __restrict__ tfq,
                                            float* __restrict__ ampsum) {
  const int bh = vbid >> 2, qt = vbid & 3;
  const int b = bh >> 3, h = bh & 7;
  const int l = qt * 256 + threadIdx.x;
  const float4* p4 = reinterpret_cast<const float4*>(
      &tfq[((size_t)(b * L_ + l) * H_ + h) * E_]);
  float s = 0.f;
#pragma unroll
  for (int e4 = 0; e4 < 16; ++e4) {
    float4 v = p4[e4];
    s += v.x * v.x + v.y * v.y + v.z * v.z + v.w * v.w;
  }
  ampsum[(size_t)(bh * 2 + 1) * 1024 + l] = s;
}

// ---- FFT corr amplitude + 64-mode spectra (coalesced, 512 thr) -------------
__device__ __forceinline__ void dev_fft(char* smem, int vbid,
                                        const float* __restrict__ xtq,
                                        const float* __restrict__ xtk,
                                        float* __restrict__ amp2_part,
                                        float* __restrict__ qft,
                                        float* __restrict__ kft) {
  float* zre = reinterpret_cast<float*>(smem);     // [4][1024]
  float* zim = zre + 4096;
  float* ctab = zim + 4096;                        // [512]
  float* stab = ctab + 512;
  const int eg = vbid & 15;
  const int bh = vbid >> 4;
  const int tid = threadIdx.x;
  const float TWO_PI_N = 6.283185307179586f / 1024.0f;

  if (tid < 512) {
    float s, c;
    sincosf(TWO_PI_N * (float)tid, &s, &c);
    ctab[tid] = c; stab[tid] = s;     // W^j = c - i*s
  }
  for (int idx = tid; idx < 1024; idx += 512) {
    int ee = idx >> 8, t4 = idx & 255;
    size_t ro = ((size_t)(bh * 64 + eg * 4 + ee)) * 1024;
    float4 qv = reinterpret_cast<const float4*>(xtq + ro)[t4];
    float4 kv = reinterpret_cast<const float4*>(xtk + ro)[t4];
    *reinterpret_cast<float4*>(&zre[ee * 1024 + t4 * 4]) = qv;
    *reinterpret_cast<float4*>(&zim[ee * 1024 + t4 * 4]) = kv;
  }
  __syncthreads();

  // forward DIF
  for (int s = 0; s < 10; ++s) {
    const int half = 512 >> s;
#pragma unroll
    for (int it = 0; it < 4; ++it) {
      int idx = tid + it * 512;
      int ee = idx >> 9;
      int bf = idx & 511;
      int j = bf & (half - 1);
      int p0 = ((bf >> (9 - s)) << (10 - s)) + j;
      int p1 = p0 + half;
      float ur = zre[ee * 1024 + p0], ui = zim[ee * 1024 + p0];
      float vr = zre[ee * 1024 + p1], vi = zim[ee * 1024 + p1];
      float dr = ur - vr, di = ui - vi;
      zre[ee * 1024 + p0] = ur + vr; zim[ee * 1024 + p0] = ui + vi;
      int twi = j << s;
      float c = ctab[twi], sn = stab[twi];
      zre[ee * 1024 + p1] = fmaf(dr, c, di * sn);
      zim[ee * 1024 + p1] = fmaf(di, c, -dr * sn);
    }
    __syncthreads();
  }

  // Hermitian unpack + P = Fq*conj(Fk); dump modes 0..63
  float pr[8], pi_[8];
#pragma unroll
  for (int it = 0; it < 8; ++it) {
    int idx = tid + it * 512;
    int ee = idx >> 10;
    int p = idx & 1023;
    int m = __brev((unsigned)p) >> 22;
    int mp = (1024 - m) & 1023;
    int pp = __brev((unsigned)mp) >> 22;
    float ar = zre[ee * 1024 + p], ai = zim[ee * 1024 + p];
    float br = zre[ee * 1024 + pp], bi = zim[ee * 1024 + pp];
    float qr = 0.5f * (ar + br), qi = 0.5f * (ai - bi);
    float kr = 0.5f * (ai + bi), ki = -0.5f * (ar - br);
    pr[it]  = fmaf(qr, kr, qi * ki);
    pi_[it] = fmaf(qi, kr, -qr * ki);
    if (m < 64) {
      size_t o = ((size_t)(bh * 64 + eg * 4 + ee) * 64 + m) * 2;
      qft[o] = qr; qft[o + 1] = qi;
      kft[o] = kr; kft[o + 1] = ki;
    }
  }
  __syncthreads();
#pragma unroll
  for (int it = 0; it < 8; ++it) {
    int idx = tid + it * 512;
    int ee = idx >> 10;
    int p = idx & 1023;
    zre[ee * 1024 + p] = pr[it]; zim[ee * 1024 + p] = pi_[it];
  }
  __syncthreads();

  // pair-mix
  for (int idx = tid; idx < 2048; idx += 512) {
    int u = idx >> 10;
    int p = idx & 1023;
    int e0 = 2 * u, e1 = 2 * u + 1;
    float s_r = zre[e0 * 1024 + p] - zim[e1 * 1024 + p];
    float s_i = zim[e0 * 1024 + p] + zre[e1 * 1024 + p];
    zre[e0 * 1024 + p] = s_r; zim[e0 * 1024 + p] = s_i;
  }
  __syncthreads();

  // inverse DIT on slots 0,2
  for (int s = 9; s >= 0; --s) {
    const int half = 512 >> s;
#pragma unroll
    for (int it = 0; it < 2; ++it) {
      int idx = tid + it * 512;
      int ee = (idx >> 9) * 2;
      int bf = idx & 511;
      int j = bf & (half - 1);
      int p0 = ((bf >> (9 - s)) << (10 - s)) + j;
      int p1 = p0 + half;
      int twi = j << s;
      float c = ctab[twi], sn = stab[twi];
      float ur = zre[ee * 1024 + p0], ui = zim[ee * 1024 + p0];
      float wr = zre[ee * 1024 + p1], wi = zim[ee * 1024 + p1];
      float vr = fmaf(wr, c, -wi * sn);
      float vi = fmaf(wi, c, wr * sn);
      zre[ee * 1024 + p0] = ur + vr; zim[ee * 1024 + p0] = ui + vi;
      zre[ee * 1024 + p1] = ur - vr; zim[ee * 1024 + p1] = ui - vi;
    }
    __syncthreads();
  }

  for (int t = tid; t < 1024; t += 512) {
    float r0 = zre[t], i0 = zim[t];
    float r2 = zre[2 * 1024 + t], i2 = zim[2 * 1024 + t];
    amp2_part[(size_t)(bh * 16 + eg) * 1024 + t] =
        fmaf(r0, r0, fmaf(i0, i0, fmaf(r2, r2, i2 * i2)));
  }
}

// ---- reduction + wave top-35 selection for problem p = bh*2+src ------------
__device__ __forceinline__ void dev_sel(char* smem, int vbid,
                                        const float* __restrict__ amp2_part,
                                        const float* __restrict__ ampsum,
                                        int* __restrict__ sel_ws) {
  float* amp = reinterpret_cast<float*>(smem);    // [1024]
  const int p = vbid;
  const int tid = threadIdx.x;

  if ((p & 1) == 0) {
    const int bh = p >> 1;
    for (int t = tid; t < 1024; t += 256) {
      float s = 0.f;
#pragma unroll
      for (int c = 0; c < 16; ++c)
        s += amp2_part[(size_t)(bh * 16 + c) * 1024 + t];
      amp[t] = s;
    }
  } else {
    for (int t = tid; t < 1024; t += 256)
      amp[t] = ampsum[(size_t)p * 1024 + t];
  }
  __syncthreads();

  if (tid < 64) {
    const int lane = tid;
    float val[16];
#pragma unroll
    for (int j = 0; j < 16; ++j) val[j] = amp[j * 64 + lane];

    float bv = -1.f; int bi = lane;
#pragma unroll
    for (int j = 0; j < 16; ++j) {
      if (val[j] > bv) { bv = val[j]; bi = j * 64 + lane; }
    }
    for (int it = 0; it < NTOP; ++it) {
      float v = bv; int i = bi;
#pragma unroll
      for (int d = 1; d < 64; d <<= 1) {
        float ov = __shfl_xor(v, d);
        int oi = __shfl_xor(i, d);
        if (ov > v || (ov == v && oi < i)) { v = ov; i = oi; }
      }
      if (lane == 0) sel_ws[p * 64 + it] = i;
      if ((i & 63) == lane) {
        int jr = i >> 6;
#pragma unroll
        for (int j = 0; j < 16; ++j) if (j == jr) val[j] = -1.f;
        bv = -1.f; bi = lane;
#pragma unroll
        for (int j = 0; j < 16; ++j) {
          if (val[j] > bv) { bv = val[j]; bi = j * 64 + lane; }
        }
      }
    }
  }
}

// ---- sparse attention -------------------------------------------------------
__device__ __forceinline__ void dev_attn(char* smem, int vbid,
                                         const float* __restrict__ q_g,
                                         const float* __restrict__ tfq,
                                         const float* __restrict__ k_g,
                                         const float* __restrict__ v_g,
                                         const float* __restrict__ wfuse,
                                         const int* __restrict__ sel_ws,
                                         float* __restrict__ out) {
  float4* qs4 = reinterpret_cast<float4*>(smem);   // [2][35][16]
  float4* vs4 = qs4 + 2 * NTOP * 16;
  const int ac = vbid & 15;
  const int bh = vbid >> 4;
  const int b = bh >> 3, h = bh & 7;
  const int a0 = ac * 64;
  const int tid = threadIdx.x;

  for (int idx = tid; idx < 2 * NTOP * 16; idx += 256) {
    int src = idx / (NTOP * 16);
    int rem = idx - src * (NTOP * 16);
    int i = rem >> 4, e4 = rem & 15;
    int row = sel_ws[(bh * 2 + src) * 64 + i];
    size_t rb = ((size_t)(b * L_ + row) * H_ + h) * E_;
    const float* qbase = src ? tfq : q_g;
    qs4[(src * NTOP + i) * 16 + e4] = reinterpret_cast<const float4*>(qbase + rb)[e4];
    vs4[(src * NTOP + i) * 16 + e4] = reinterpret_cast<const float4*>(v_g + rb)[e4];
  }
  __syncthreads();

  const int qd = tid & 3, r = tid >> 2;
  const int a = a0 + r;
  const int eb = qd * 16;

  size_t krb = ((size_t)(b * L_ + a) * H_ + h) * E_;
  const float4* k4p = reinterpret_cast<const float4*>(k_g + krb);
  float4 kq[4];
#pragma unroll
  for (int j4 = 0; j4 < 4; ++j4) kq[j4] = k4p[qd * 4 + j4];

  float ct[NTOP], ctf[NTOP];
#pragma unroll
  for (int i = 0; i < NTOP; ++i) { ct[i] = 0.f; ctf[i] = 0.f; }

#pragma unroll
  for (int j4 = 0; j4 < 4; ++j4) {
    float4 kv = kq[j4];
#pragma unroll
    for (int i = 0; i < NTOP; ++i) {
      float4 q4 = qs4[(0 * NTOP + i) * 16 + qd * 4 + j4];
      ct[i] = fmaf(q4.x, kv.x, ct[i]); ct[i] = fmaf(q4.y, kv.y, ct[i]);
      ct[i] = fmaf(q4.z, kv.z, ct[i]); ct[i] = fmaf(q4.w, kv.w, ct[i]);
      float4 p4 = qs4[(1 * NTOP + i) * 16 + qd * 4 + j4];
      ctf[i] = fmaf(p4.x, kv.x, ctf[i]); ctf[i] = fmaf(p4.y, kv.y, ctf[i]);
      ctf[i] = fmaf(p4.z, kv.z, ctf[i]); ctf[i] = fmaf(p4.w, kv.w, ctf[i]);
    }
  }
#pragma unroll
  for (int i = 0; i < NTOP; ++i) {
    ct[i] += __shfl_xor(ct[i], 1);  ct[i] += __shfl_xor(ct[i], 2);
    ctf[i] += __shfl_xor(ctf[i], 1); ctf[i] += __shfl_xor(ctf[i], 2);
  }

  float wf0 = wfuse[(h * L_ + a) * 2 + 0];
  float wf1 = wfuse[(h * L_ + a) * 2 + 1];
  float wm = fmaxf(wf0, wf1);
  float ew0 = expf(wf0 - wm), ew1 = expf(wf1 - wm);
  float nw0 = ew0 / (ew0 + ew1), nw1 = ew1 / (ew0 + ew1);

  {
    float m = -1e30f;
#pragma unroll
    for (int i = 0; i < NTOP; ++i) { ct[i] *= SCALE_; m = fmaxf(m, ct[i]); }
    float sum = 0.f;
#pragma unroll
    for (int i = 0; i < NTOP; ++i) { ct[i] = expf(ct[i] - m); sum += ct[i]; }
    float c = 0.5f * nw0 / sum;
#pragma unroll
    for (int i = 0; i < NTOP; ++i) ct[i] *= c;
  }
  {
    float m = -1e30f;
#pragma unroll
    for (int i = 0; i < NTOP; ++i) { ctf[i] *= SCALE_; m = fmaxf(m, ctf[i]); }
    float sum = 0.f;
#pragma unroll
    for (int i = 0; i < NTOP; ++i) { ctf[i] = expf(ctf[i] - m); sum += ctf[i]; }
    float c = 0.5f * nw1 / sum;
#pragma unroll
    for (int i = 0; i < NTOP; ++i) ctf[i] *= c;
  }
#pragma unroll
  for (int j4 = 0; j4 < 4; ++j4) {
    float ax = 0.f, ay = 0.f, az = 0.f, aw = 0.f;
#pragma unroll
    for (int i = 0; i < NTOP; ++i) {
      float4 v4 = vs4[(0 * NTOP + i) * 16 + qd * 4 + j4];
      ax = fmaf(ct[i], v4.x, ax); ay = fmaf(ct[i], v4.y, ay);
      az = fmaf(ct[i], v4.z, az); aw = fmaf(ct[i], v4.w, aw);
    }
#pragma unroll
    for (int i = 0; i < NTOP; ++i) {
      float4 v4 = vs4[(1 * NTOP + i) * 16 + qd * 4 + j4];
      ax = fmaf(ctf[i], v4.x, ax); ay = fmaf(ctf[i], v4.y, ay);
      az = fmaf(ctf[i], v4.z, az); aw = fmaf(ctf[i], v4.w, aw);
    }
    int d = eb + j4 * 4;
    out[((size_t)(bh * 64 + d + 0)) * 1024 + a] = ax;
    out[((size_t)(bh * 64 + d + 1)) * 1024 + a] = ay;
    out[((size_t)(bh * 64 + d + 2)) * 1024 + a] = az;
    out[((size_t)(bh * 64 + d + 3)) * 1024 + a] = aw;
  }
}

// ---- spectral: xqk = ctanh(qft^T kft); xqkv = xqk @ kft^T -------------------
__device__ __forceinline__ void dev_spec12(char* smem, int vbid,
                                           const float* __restrict__ qft,
                                           const float* __restrict__ kft,
                                           float* __restrict__ xre_g,
                                           float* __restrict__ xim_g) {
  float* kre = reinterpret_cast<float*>(smem);    // [64][65]
  float* kim = kre + 4160;
  float* qre = kim + 4160;                        // [64][8]
  float* qim = qre + 512;
  float* tre = qim + 512;                         // [8][64]
  float* tim = tre + 512;
  const int xc = vbid & 7;
  const int bh = vbid >> 3;
  const int tid = threadIdx.x;

  for (int idx = tid; idx < 4096; idx += 256) {
    int e = idx >> 6, y = idx & 63;
    size_t o = ((size_t)(bh * 64 + e) * 64 + y) * 2;
    kre[e * 65 + y] = kft[o]; kim[e * 65 + y] = kft[o + 1];
  }
  for (int idx = tid; idx < 512; idx += 256) {
    int e = idx >> 3, xl = idx & 7;
    size_t o = ((size_t)(bh * 64 + e) * 64 + xc * 8 + xl) * 2;
    qre[e * 8 + xl] = qft[o]; qim[e * 8 + xl] = qft[o + 1];
  }
  __syncthreads();

  const int y = tid & 63, xg = tid >> 6;
#pragma unroll
  for (int xi = 0; xi < 2; ++xi) {
    int xl = xg + xi * 4;
    float ar = 0.f, ai = 0.f;
    for (int e = 0; e < 64; ++e) {
      float a = qre[e * 8 + xl], b = qim[e * 8 + xl];
      float c = kre[e * 65 + y], d = kim[e * 65 + y];
      ar = fmaf(a, c, fmaf(-b, d, ar));
      ai = fmaf(a, d, fmaf(b, c, ai));
    }
    float trv, tiv;
    float x2 = 2.f * ar, y2 = 2.f * ai;
    if (fabsf(x2) > 30.f) {
      trv = copysignf(1.f, ar); tiv = 0.f;
    } else {
      float sh = sinhf(x2), ch = coshf(x2);
      float sn = sinf(y2), cs = cosf(y2);
      float dd = ch + cs;
      trv = sh / dd; tiv = sn / dd;
    }
    tre[xl * 64 + y] = trv; tim[xl * 64 + y] = tiv;
  }
  __syncthreads();

  const int e2 = tid & 63, xg2 = tid >> 6;
#pragma unroll
  for (int xi = 0; xi < 2; ++xi) {
    int xl = xg2 + xi * 4;
    float ar = 0.f, ai = 0.f;
    for (int yy = 0; yy < 64; ++yy) {
      float a = tre[xl * 64 + yy], b = tim[xl * 64 + yy];
      float c = kre[e2 * 65 + yy], d = kim[e2 * 65 + yy];
      ar = fmaf(a, c, fmaf(-b, d, ar));
      ai = fmaf(a, d, fmaf(b, c, ai));
    }
    xre_g[(size_t)bh * 4096 + (xc * 8 + xl) * 64 + e2] = ar;
    xim_g[(size_t)bh * 4096 + (xc * 8 + xl) * 64 + e2] = ai;
  }
}

// ---- w1 einsum --------------------------------------------------------------
__device__ __forceinline__ void dev_w1(char* smem, int vbid,
                                       const float* __restrict__ xre_g,
                                       const float* __restrict__ xim_g,
                                       const float* __restrict__ w1re,
                                       const float* __restrict__ w1im,
                                       float* __restrict__ xw) {
  float* xre = reinterpret_cast<float*>(smem);    // [64][65]
  float* xim = xre + 4160;
  float* redr = xim + 4160;                       // [4][512]
  float* redi = redr + 2048;
  const int oc = vbid & 7;
  const int bh = vbid >> 3;
  const int h = bh & 7;
  const int tid = threadIdx.x;

  for (int idx = tid; idx < 4096; idx += 256) {
    int x = idx >> 6, e = idx & 63;
    xre[e * 65 + x] = xre_g[(size_t)bh * 4096 + idx];
    xim[e * 65 + x] = xim_g[(size_t)bh * 4096 + idx];
  }
  __syncthreads();

  const int x = tid & 63, g = tid >> 6;
  float accr[8], acci[8];
#pragma unroll
  for (int oo = 0; oo < 8; ++oo) { accr[oo] = 0.f; acci[oo] = 0.f; }

  for (int ee = 0; ee < 16; ++ee) {
    int e = g * 16 + ee;
    float a = xre[e * 65 + x], b = xim[e * 65 + x];
    size_t wbase = (((size_t)h * 64 + e) * 64 + oc * 8) * 64 + x;
#pragma unroll
    for (int oo = 0; oo < 8; ++oo) {
      float c = w1re[wbase + (size_t)oo * 64];
      float d = w1im[wbase + (size_t)oo * 64];
      accr[oo] = fmaf(a, c, fmaf(-b, d, accr[oo]));
      acci[oo] = fmaf(a, d, fmaf(b, c, acci[oo]));
    }
  }
#pragma unroll
  for (int oo = 0; oo < 8; ++oo) {
    redr[g * 512 + oo * 64 + x] = accr[oo];
    redi[g * 512 + oo * 64 + x] = acci[oo];
  }
  __syncthreads();

  const float INV = 1.0f / (512.0f * 512.0f);
  for (int idx = tid; idx < 512; idx += 256) {
    int oo = idx >> 6, x2 = idx & 63;
    float r = redr[idx] + redr[512 + idx] + redr[1024 + idx] + redr[1536 + idx];
    float i = redi[idx] + redi[512 + idx] + redi[1024 + idx] + redi[1536 + idx];
    size_t oidx = ((size_t)(bh * 64 + oc * 8 + oo) * 64 + x2) * 2;
    xw[oidx] = r * INV;
    xw[oidx + 1] = i * INV;
  }
}

// ---- final irfft add --------------------------------------------------------
__device__ __forceinline__ void dev_final(char* smem, int vbid,
                                          const float* __restrict__ xw,
                                          float* __restrict__ out) {
  float* Xre = reinterpret_cast<float*>(smem);    // [8][64], pre-scaled by 2
  float* Xim = Xre + 512;
  const int tc = vbid & 3;
  const int oc = (vbid >> 2) & 7;
  const int bh = vbid >> 5;
  const int o0 = oc * 8;
  const int tid = threadIdx.x;

  for (int idx = tid; idx < 512; idx += 256) {
    int o = idx >> 6, m = idx & 63;
    size_t s = ((size_t)(bh * 64 + o0 + o) * 64 + m) * 2;
    Xre[o * 64 + m] = 2.f * xw[s]; Xim[o * 64 + m] = 2.f * xw[s + 1];
  }
  __syncthreads();

  const int t = tc * 256 + tid;
  const float HALF_INVN = 0.5f / 1024.0f;
  const float TWO_PI = 6.283185307179586f;
  float th = TWO_PI * (float)t * (1.0f / 1024.0f);
  float s1, c1;
  __sincosf(th, &s1, &c1);
  float cm = c1, sm = s1;

  float acc[8];
#pragma unroll
  for (int o = 0; o < 8; ++o) acc[o] = 0.5f * Xre[o * 64];

  for (int m = 1; m < 64; ++m) {
#pragma unroll
    for (int o = 0; o < 8; ++o) {
      acc[o] = fmaf(Xre[o * 64 + m], cm, acc[o]);
      acc[o] = fmaf(-Xim[o * 64 + m], sm, acc[o]);
    }
    float cn = fmaf(cm, c1, -sm * s1);
    float sn = fmaf(sm, c1, cm * s1);
    cm = cn; sm = sn;
  }
#pragma unroll
  for (int o = 0; o < 8; ++o) {
    size_t oi = ((size_t)(bh * 64 + o0 + o)) * 1024 + t;
    out[oi] = fmaf(acc[o], HALF_INVN, out[oi]);
  }
}

// ============================ fat launches =================================

__global__ __launch_bounds__(256) void k_L1(const float* __restrict__ q,
                                            const float* __restrict__ k,
                                            const float* __restrict__ tfq,
                                            float* __restrict__ xtq,
                                            float* __restrict__ xtk,
                                            float* __restrict__ ampsum) {
  __shared__ __align__(16) char smem[16640];
  if (blockIdx.x < 1024) dev_stage(smem, blockIdx.x, q, k, xtq, xtk);
  else dev_tfqnorm(blockIdx.x - 1024, tfq, ampsum);
}

__global__ __launch_bounds__(512) void k_L2(const float* __restrict__ xtq,
                                            const float* __restrict__ xtk,
                                            float* __restrict__ amp2,
                                            float* __restrict__ qft,
                                            float* __restrict__ kft) {
  __shared__ __align__(16) char smem[36864];
  dev_fft(smem, blockIdx.x, xtq, xtk, amp2, qft, kft);
}

__global__ __launch_bounds__(256) void k_L3(const float* __restrict__ amp2,
                                            const float* __restrict__ ampsum,
                                            int* __restrict__ sel,
                                            const float* __restrict__ qft,
                                            const float* __restrict__ kft,
                                            float* __restrict__ xre_g,
                                            float* __restrict__ xim_g) {
  __shared__ __align__(16) char smem[41472];
  if (blockIdx.x < 64) dev_sel(smem, blockIdx.x, amp2, ampsum, sel);
  else dev_spec12(smem, blockIdx.x - 64, qft, kft, xre_g, xim_g);
}

__global__ __launch_bounds__(256) void k_L4(const float* __restrict__ q,
                                            const float* __restrict__ tfq,
                                            const float* __restrict__ k,
                                            const float* __restrict__ v,
                                            const float* __restrict__ wfuse,
                                            const int* __restrict__ sel,
                                            float* __restrict__ out,
                                            const float* __restrict__ xre_g,
                                            const float* __restrict__ xim_g,
                                            const float* __restrict__ w1re,
                                            const float* __restrict__ w1im,
                                            float* __restrict__ xw) {
  __shared__ __align__(16) char smem[49664];
  if (blockIdx.x < 512) dev_attn(smem, blockIdx.x, q, tfq, k, v, wfuse, sel, out);
  else dev_w1(smem, blockIdx.x - 512, xre_g, xim_g, w1re, w1im, xw);
}

__global__ __launch_bounds__(256) void k_L5(const float* __restrict__ xw,
                                            float* __restrict__ out) {
  __shared__ __align__(16) char smem[4096];
  dev_final(smem, blockIdx.x, xw, out);
}

// ============================ fallback kernels =============================
// (small-ws path: strided FFT + LDS top-k + standalone role wrappers)

__global__ __launch_bounds__(256) void k_fft_s(const float* __restrict__ q_g,
                                               const float* __restrict__ k_g,
                                               float* __restrict__ amp2_part,
                                               float* __restrict__ qft,
                                               float* __restrict__ kft) {
  __shared__ float zre[4][1024], zim[4][1024];
  __shared__ float ctab[512], stab[512];
  const int eg = blockIdx.x & 15;
  const int bh = blockIdx.x >> 4;
  const int b = bh >> 3, h = bh & 7;
  const int tid = threadIdx.x;
  const float TWO_PI_N = 6.283185307179586f / 1024.0f;

  for (int j = tid; j < 512; j += 256) {
    float s, c;
    sincosf(TWO_PI_N * (float)j, &s, &c);
    ctab[j] = c; stab[j] = s;
  }
  for (int t = tid; t < 1024; t += 256) {
    size_t g4 = ((size_t)(b * L_ + t) * H_ + h) * 16 + eg;
    float4 qv = reinterpret_cast<const float4*>(q_g)[g4];
    float4 kv = reinterpret_cast<const float4*>(k_g)[g4];
    zre[0][t] = qv.x; zre[1][t] = qv.y; zre[2][t] = qv.z; zre[3][t] = qv.w;
    zim[0][t] = kv.x; zim[1][t] = kv.y; zim[2][t] = kv.z; zim[3][t] = kv.w;
  }
  __syncthreads();

  for (int s = 0; s < 10; ++s) {
    const int half = 512 >> s;
#pragma unroll
    for (int it = 0; it < 8; ++it) {
      int idx = tid + it * 256;
      int ee = idx >> 9;
      int bf = idx & 511;
      int j = bf & (half - 1);
      int p0 = ((bf >> (9 - s)) << (10 - s)) + j;
      int p1 = p0 + half;
      float ur = zre[ee][p0], ui = zim[ee][p0];
      float vr = zre[ee][p1], vi = zim[ee][p1];
      float dr = ur - vr, di = ui - vi;
      zre[ee][p0] = ur + vr; zim[ee][p0] = ui + vi;
      int twi = j << s;
      float c = ctab[twi], sn = stab[twi];
      zre[ee][p1] = fmaf(dr, c, di * sn);
      zim[ee][p1] = fmaf(di, c, -dr * sn);
    }
    __syncthreads();
  }

  float pr[16], pi_[16];
#pragma unroll
  for (int it = 0; it < 16; ++it) {
    int idx = tid + it * 256;
    int ee = idx >> 10;
    int p = idx & 1023;
    int m = __brev((unsigned)p) >> 22;
    int mp = (1024 - m) & 1023;
    int pp = __brev((unsigned)mp) >> 22;
    float ar = zre[ee][p], ai = zim[ee][p];
    float br = zre[ee][pp], bi = zim[ee][pp];
    float qr = 0.5f * (ar + br), qi = 0.5f * (ai - bi);
    float kr = 0.5f * (ai + bi), ki = -0.5f * (ar - br);
    pr[it]  = fmaf(qr, kr, qi * ki);
    pi_[it] = fmaf(qi, kr, -qr * ki);
    if (m < 64) {
      size_t o = ((size_t)(bh * 64 + eg * 4 + ee) * 64 + m) * 2;
      qft[o] = qr; qft[o + 1] = qi;
      kft[o] = kr; kft[o + 1] = ki;
    }
  }
  __syncthreads();
#pragma unroll
  for (int it = 0; it < 16; ++it) {
    int idx = tid + it * 256;
    int ee = idx >> 10;
    int p = idx & 1023;
    zre[ee][p] = pr[it]; zim[ee][p] = pi_[it];
  }
  __syncthreads();

  for (int idx = tid; idx < 2048; idx += 256) {
    int u = idx >> 10;
    int p = idx & 1023;
    int e0 = 2 * u, e1 = 2 * u + 1;
    float s_r = zre[e0][p] - zim[e1][p];
    float s_i = zim[e0][p] + zre[e1][p];
    zre[e0][p] = s_r; zim[e0][p] = s_i;
  }
  __syncthreads();

  for (int s = 9; s >= 0; --s) {
    const int half = 512 >> s;
#pragma unroll
    for (int it = 0; it < 4; ++it) {
      int idx = tid + it * 256;
      int ee = (idx >> 9) * 2;
      int bf = idx & 511;
      int j = bf & (half - 1);
      int p0 = ((bf >> (9 - s)) << (10 - s)) + j;
      int p1 = p0 + half;
      int twi = j << s;
      float c = ctab[twi], sn = stab[twi];
      float ur = zre[ee][p0], ui = zim[ee][p0];
      float wr = zre[ee][p1], wi = zim[ee][p1];
      float vr = fmaf(wr, c, -wi * sn);
      float vi = fmaf(wi, c, wr * sn);
      zre[ee][p0] = ur + vr; zim[ee][p0] = ui + vi;
      zre[ee][p1] = ur - vr; zim[ee][p1] = ui - vi;
    }
    __syncthreads();
  }

  for (int t = tid; t < 1024; t += 256) {
    float r0 = zre[0][t], i0 = zim[0][t];
    float r2 = zre[2][t], i2 = zim[2][t];
    amp2_part[(size_t)(bh * 16 + eg) * 1024 + t] =
        fmaf(r0, r0, fmaf(i0, i0, fmaf(r2, r2, i2 * i2)));
  }
}

__global__ __launch_bounds__(256) void k_topk(const float* __restrict__ amp2_part,
                                              const float* __restrict__ tfq,
                                              int* __restrict__ sel_ws) {
  __shared__ float amp[1024];
  __shared__ float wv_s[4];
  __shared__ int wi_s[4];
  __shared__ int winner_s;
  const int src = blockIdx.x & 1;
  const int bh = blockIdx.x >> 1;
  const int b = bh >> 3, h = bh & 7;
  const int tid = threadIdx.x;

  if (src == 0) {
    for (int t = tid; t < 1024; t += 256) {
      float s = 0.f;
#pragma unroll
      for (int c = 0; c < 16; ++c) s += amp2_part[(size_t)(bh * 16 + c) * 1024 + t];
      amp[t] = s;
    }
  } else {
    for (int l = tid; l < 1024; l += 256) {
      const float4* p4 = reinterpret_cast<const float4*>(
          &tfq[((size_t)(b * L_ + l) * H_ + h) * E_]);
      float s = 0.f;
#pragma unroll
      for (int e4 = 0; e4 < 16; ++e4) {
        float4 v = p4[e4];
        s += v.x * v.x + v.y * v.y + v.z * v.z + v.w * v.w;
      }
      amp[l] = s;
    }
  }
  __syncthreads();

  float bv = -1.f; int bi = tid;
#pragma unroll
  for (int kk = 0; kk < 4; ++kk) {
    int t = tid + kk * 256;
    float v = amp[t];
    if (v > bv) { bv = v; bi = t; }
  }
  const int lane = tid & 63, w = tid >> 6;

  for (int it = 0; it < NTOP; ++it) {
    float v = bv; int i = bi;
#pragma unroll
    for (int d = 1; d < 64; d <<= 1) {
      float ov = __shfl_xor(v, d);
      int oi = __shfl_xor(i, d);
      if (ov > v || (ov == v && oi < i)) { v = ov; i = oi; }
    }
    if (lane == 0) { wv_s[w] = v; wi_s[w] = i; }
    __syncthreads();
    if (tid == 0) {
      float fv = wv_s[0]; int fi = wi_s[0];
#pragma unroll
      for (int j = 1; j < 4; ++j) {
        if (wv_s[j] > fv || (wv_s[j] == fv && wi_s[j] < fi)) { fv = wv_s[j]; fi = wi_s[j]; }
      }
      winner_s = fi;
      sel_ws[(bh * 2 + src) * 64 + it] = fi;
    }
    __syncthreads();
    int fi = winner_s;
    if ((fi & 255) == tid) {
      amp[fi] = -1.f;
      bv = -1.f; bi = tid;
#pragma unroll
      for (int kk = 0; kk < 4; ++kk) {
        int t = tid + kk * 256;
        float vv = amp[t];
        if (vv > bv) { bv = vv; bi = t; }
      }
    }
  }
}

__global__ __launch_bounds__(256) void k_attn_w(const float* __restrict__ q,
                                                const float* __restrict__ tfq,
                                                const float* __restrict__ k,
                                                const float* __restrict__ v,
                                                const float* __restrict__ wfuse,
                                                const int* __restrict__ sel,
                                                float* __restrict__ out) {
  __shared__ __align__(16) char smem[35840];
  dev_attn(smem, blockIdx.x, q, tfq, k, v, wfuse, sel, out);
}

__global__ __launch_bounds__(256) void k_spec12_w(const float* __restrict__ qft,
                                                  const float* __restrict__ kft,
                                                  float* __restrict__ xre_g,
                                                  float* __restrict__ xim_g) {
  __shared__ __align__(16) char smem[41472];
  dev_spec12(smem, blockIdx.x, qft, kft, xre_g, xim_g);
}

__global__ __launch_bounds__(256) void k_w1_w(const float* __restrict__ xre_g,
                                              const float* __restrict__ xim_g,
                                              const float* __restrict__ w1re,
                                              const float* __restrict__ w1im,
                                              float* __restrict__ xw) {
  __shared__ __align__(16) char smem[49664];
  dev_w1(smem, blockIdx.x, xre_g, xim_g, w1re, w1im, xw);
}

// ---------------------------------------------------------------------------
extern "C" void kernel_launch(void* const* d_in, const int* in_sizes, int n_in,
                              void* d_out, int out_size, void* d_ws, size_t ws_size,
                              hipStream_t stream) {
  const float* tfq   = (const float*)d_in[0];
  const float* q     = (const float*)d_in[1];
  const float* k     = (const float*)d_in[2];
  const float* v     = (const float*)d_in[3];
  const float* wfuse = (const float*)d_in[5];
  const float* w1re  = (const float*)d_in[6];
  const float* w1im  = (const float*)d_in[7];
  float* out = (float*)d_out;
  float* ws  = (float*)d_ws;

  const size_t STAGED_FLOATS = 5312512;   // ~21.25 MB
  if (ws_size >= STAGED_FLOATS * sizeof(float)) {
    // staged layout:
    //   xtq [0..2097152) | xtk [..4194304) | amp2 [..4718592)
    //   qft [..4980736) | kft [..5242880) | sel [..5246976) | ampsum [..5312512)
    //   xre_g/xim_g/xw alias xtq region (dead after k_L2).
    float* xtq    = ws;
    float* xtk    = ws + 2097152;
    float* amp2   = ws + 4194304;
    float* qft    = ws + 4718592;
    float* kft    = ws + 4980736;
    int*   sel    = (int*)(ws + 5242880);
    float* ampsum = ws + 5246976;
    float* xre_g  = ws;
    float* xim_g  = ws + 131072;
    float* xw     = ws + 262144;

    k_L1<<<1152, 256, 0, stream>>>(q, k, tfq, xtq, xtk, ampsum);
    k_L2<<<512, 512, 0, stream>>>(xtq, xtk, amp2, qft, kft);
    k_L3<<<320, 256, 0, stream>>>(amp2, ampsum, sel, qft, kft, xre_g, xim_g);
    k_L4<<<768, 256, 0, stream>>>(q, tfq, k, v, wfuse, sel, out,
                                  xre_g, xim_g, w1re, w1im, xw);
    k_L5<<<1024, 256, 0, stream>>>(xw, out);
  } else {
    // fallback (4.2 MB layout)
    float* amp2  = ws;
    float* xre_g = ws;
    float* xim_g = ws + 131072;
    float* xw    = ws + 262144;
    float* qft   = ws + 524288;
    float* kft   = ws + 786432;
    int*   sel   = (int*)(ws + 1048576);

    k_fft_s<<<512, 256, 0, stream>>>(q, k, amp2, qft, kft);
    k_topk<<<64, 256, 0, stream>>>(amp2, tfq, sel);
    k_attn_w<<<512, 256, 0, stream>>>(q, tfq, k, v, wfuse, sel, out);
    k_spec12_w<<<256, 256, 0, stream>>>(qft, kft, xre_g, xim_g);
    k_w1_w<<<256, 256, 0, stream>>>(xre_g, xim_g, w1re, w1im, xw);
    k_L5<<<1024, 256, 0, stream>>>(xw, out);
  }
}